// Round 1
// baseline (2532.253 us; speedup 1.0000x reference)
//
#include <hip/hip_runtime.h>

#define EPS 1e-5f

// ---------------- ws layout (float offsets) ----------------
#define WS_BN1SUM   0         // 256 (s1[128], s2[128])
#define WS_BN2SUM   256       // 256
#define WS_LOSS     512       // 1
#define WS_BN1SC    1024      // 128
#define WS_BN1SH    1152      // 128
#define WS_BN2SC    1280      // 128
#define WS_BN2SH    1408      // 128
#define WS_CC       1536      // 512 code norms
#define WS_IDX      2048      // 65536 ints
#define WS_WT3      67584     // 16384  pre_w^T  [ci][co]
#define WS_WT1      83968     // 294912 dec1_w^T [tap][ci][co]
#define WS_WT2      378880    // 294912 enc2_w^T [(ci*9+tap)][co]
#define WS_F        673792    // 131072 fused post table [k][co]
#define WS_A        1048576   // 33554432: h1raw, then z_pix (aliased), then h3raw
#define WS_B        34603008  // 16777216: h2, then d_pix
#define WS_Z        WS_A
// total = 51380224 floats = 205.5 MB

#define OUT_LOSS_E  3145728
#define OUT_LOSS_C  3145729
#define OUT_IDX     3145730

// ---------------- weight pre-transpose ----------------
__global__ __launch_bounds__(256) void k_wt(const float* __restrict__ dec1_w,
                                            const float* __restrict__ enc2_w,
                                            const float* __restrict__ pre_w,
                                            float* __restrict__ ws) {
    int g = blockIdx.x * 256 + threadIdx.x;
    if (g < 294912) {                       // wt1[tap*32768 + ci*128 + co] <- dec1_w[ci][co][tap]
        int co = g & 127, ci = (g >> 7) & 255, tap = g >> 15;
        ws[WS_WT1 + g] = dec1_w[ci * 1152 + co * 9 + tap];
    } else if (g < 2 * 294912) {            // wt2[(ci*9+tap)*256 + co] <- enc2_w[co][ci][tap]
        int h = g - 294912;
        int co = h & 255, q = h >> 8;
        int ci = q / 9, tap = q - ci * 9;
        ws[WS_WT2 + h] = enc2_w[co * 1152 + ci * 9 + tap];
    } else if (g < 2 * 294912 + 16384) {    // wt3[ci*64+co] <- pre_w[co][ci]
        int h = g - 2 * 294912;
        int co = h & 63, ci = h >> 6;
        ws[WS_WT3 + h] = pre_w[co * 256 + ci];
    }
}

// ---------------- fused post table F = codebook @ post_w^T + post_b; code norms ----------------
__global__ __launch_bounds__(256) void k_F(const float* __restrict__ codebook,
                                           const float* __restrict__ post_w,
                                           const float* __restrict__ post_b,
                                           float* __restrict__ ws) {
    __shared__ __align__(16) float cbr[64];
    int k = blockIdx.x, co = threadIdx.x;
    if (co < 64) cbr[co] = codebook[k * 64 + co];
    __syncthreads();
    float acc = post_b[co];
#pragma unroll
    for (int i = 0; i < 64; i += 4) {
        float4 w4 = *(const float4*)&post_w[co * 64 + i];
        acc = fmaf(cbr[i], w4.x, acc);
        acc = fmaf(cbr[i + 1], w4.y, acc);
        acc = fmaf(cbr[i + 2], w4.z, acc);
        acc = fmaf(cbr[i + 3], w4.w, acc);
    }
    ws[WS_F + k * 256 + co] = acc;
    if (co == 0) {
        float s = 0.f;
        for (int i = 0; i < 64; i++) s += cbr[i] * cbr[i];
        ws[WS_CC + k] = s;
    }
}

// ---------------- enc1: 3x3 s2 p1, 3->128, 128^2 -> 64^2, + BN partial sums ----------------
__global__ __launch_bounds__(256) void k_enc1(const float* __restrict__ x,
                                              const float* __restrict__ w,
                                              const float* __restrict__ bias,
                                              float* __restrict__ ws) {
    __shared__ __align__(16) float in_s[3 * 9 * 130];
    __shared__ __align__(16) float w_s[27 * 32];
    int n = blockIdx.y;
    int cog = blockIdx.x & 3, yt = blockIdx.x >> 2;
    int y0 = yt * 4, cobase = cog * 32;
    int tid = threadIdx.x;
    int xo = tid & 63, cg = tid >> 6;
    int co8 = cobase + cg * 8;

    for (int t = tid; t < 3 * 9 * 130; t += 256) {
        int c = t % 130, rest = t / 130;
        int row = rest % 9, ci = rest / 9;
        int iy = 2 * y0 - 1 + row, ix = c - 1;
        float v = 0.f;
        if ((unsigned)iy < 128u && (unsigned)ix < 128u)
            v = x[(n * 3 + ci) * 16384 + iy * 128 + ix];
        in_s[t] = v;
    }
    for (int t = tid; t < 864; t += 256) {
        int co = t & 31, q = t >> 5;
        w_s[q * 32 + co] = w[(cobase + co) * 27 + q];
    }
    __syncthreads();

    float acc[4][8];
#pragma unroll
    for (int r = 0; r < 4; r++)
#pragma unroll
        for (int j = 0; j < 8; j++) acc[r][j] = bias[co8 + j];

#pragma unroll
    for (int ci = 0; ci < 3; ci++)
#pragma unroll
        for (int ky = 0; ky < 3; ky++) {
            float v[4][3];
#pragma unroll
            for (int r = 0; r < 4; r++) {
                const float* bp = &in_s[ci * 1170 + (2 * r + ky) * 130 + 2 * xo];
                v[r][0] = bp[0]; v[r][1] = bp[1]; v[r][2] = bp[2];
            }
#pragma unroll
            for (int kx = 0; kx < 3; kx++) {
                const float* wp = &w_s[(ci * 9 + ky * 3 + kx) * 32 + cg * 8];
#pragma unroll
                for (int j = 0; j < 8; j++) {
                    float wv = wp[j];
#pragma unroll
                    for (int r = 0; r < 4; r++) acc[r][j] = fmaf(v[r][kx], wv, acc[r][j]);
                }
            }
        }

    float* h1 = ws + WS_A;
#pragma unroll
    for (int j = 0; j < 8; j++) {
        int co = co8 + j;
#pragma unroll
        for (int r = 0; r < 4; r++)
            h1[((n * 128 + co) * 64 + y0 + r) * 64 + xo] = acc[r][j];
        float s1 = acc[0][j] + acc[1][j] + acc[2][j] + acc[3][j];
        float s2 = acc[0][j] * acc[0][j] + acc[1][j] * acc[1][j]
                 + acc[2][j] * acc[2][j] + acc[3][j] * acc[3][j];
#pragma unroll
        for (int off = 32; off; off >>= 1) {
            s1 += __shfl_down(s1, off);
            s2 += __shfl_down(s2, off);
        }
        if ((tid & 63) == 0) {
            atomicAdd(&ws[WS_BN1SUM + co], s1);
            atomicAdd(&ws[WS_BN1SUM + 128 + co], s2);
        }
    }
}

// ---------------- BN finalize: scale/shift per channel ----------------
__global__ __launch_bounds__(128) void k_bnfin(const float* __restrict__ sums,
                                               const float* __restrict__ g,
                                               const float* __restrict__ b,
                                               float* __restrict__ scale,
                                               float* __restrict__ shift, float invN) {
    int c = threadIdx.x;
    float mean = sums[c] * invN;
    float var = sums[128 + c] * invN - mean * mean;
    float sc = g[c] * rsqrtf(var + EPS);
    scale[c] = sc;
    shift[c] = b[c] - mean * sc;
}

// ---------------- enc2: 3x3 s2 p1, 128->256, 64^2 -> 32^2 (BN1+ReLU applied on load) ----------------
__global__ __launch_bounds__(256) void k_enc2(const float* __restrict__ bias,
                                              float* __restrict__ ws) {
    __shared__ __align__(16) float in_s[8 * 9 * 66];
    __shared__ __align__(16) float w_s[72 * 64];
    int n = blockIdx.y;
    int cog = blockIdx.x & 3, yt = blockIdx.x >> 2;
    int y0 = yt * 4, cobase = cog * 64;
    int tid = threadIdx.x;
    int xo = tid & 31, cg = tid >> 5;
    int co8g = cobase + cg * 8;
    const float* h1 = ws + WS_A;
    const float* sc = ws + WS_BN1SC;
    const float* sh = ws + WS_BN1SH;
    const float* wt2 = ws + WS_WT2;

    float acc[4][8];
#pragma unroll
    for (int r = 0; r < 4; r++)
#pragma unroll
        for (int j = 0; j < 8; j++) acc[r][j] = bias[co8g + j];

    for (int c0 = 0; c0 < 128; c0 += 8) {
        __syncthreads();
        for (int t = tid; t < 8 * 9 * 66; t += 256) {
            int c = t % 66, rest = t / 66;
            int row = rest % 9, ci = rest / 9;
            int ciG = c0 + ci;
            int iy = 2 * y0 - 1 + row, ix = c - 1;
            float v = 0.f;
            if ((unsigned)iy < 64u && (unsigned)ix < 64u) {
                float raw = h1[((n * 128 + ciG) * 64 + iy) * 64 + ix];
                v = fmaxf(fmaf(raw, sc[ciG], sh[ciG]), 0.f);
            }
            in_s[t] = v;
        }
        for (int t = tid; t < 72 * 64; t += 256) {
            int co = t & 63, q = t >> 6;
            w_s[t] = wt2[(c0 * 9 + q) * 256 + cobase + co];
        }
        __syncthreads();
#pragma unroll
        for (int ci = 0; ci < 8; ci++) {
#pragma unroll
            for (int ky = 0; ky < 3; ky++) {
                float v[4][3];
#pragma unroll
                for (int r = 0; r < 4; r++) {
                    const float* bp = &in_s[ci * 594 + (2 * r + ky) * 66 + 2 * xo];
                    v[r][0] = bp[0]; v[r][1] = bp[1]; v[r][2] = bp[2];
                }
#pragma unroll
                for (int kx = 0; kx < 3; kx++) {
                    const float* wp = &w_s[(ci * 9 + ky * 3 + kx) * 64 + cg * 8];
#pragma unroll
                    for (int j = 0; j < 8; j++) {
                        float wv = wp[j];
#pragma unroll
                        for (int r = 0; r < 4; r++) acc[r][j] = fmaf(v[r][kx], wv, acc[r][j]);
                    }
                }
            }
        }
    }
    float* h2 = ws + WS_B;
#pragma unroll
    for (int j = 0; j < 8; j++) {
        int co = co8g + j;
#pragma unroll
        for (int r = 0; r < 4; r++)
            h2[((n * 256 + co) * 32 + y0 + r) * 32 + xo] = acc[r][j];
    }
}

// ---------------- pre: 1x1, 256->64, out NHWC z_pix[p][c] ----------------
__global__ __launch_bounds__(256) void k_pre(const float* __restrict__ bias,
                                             float* __restrict__ ws) {
    __shared__ __align__(16) float a_s[8 * 128];
    __shared__ __align__(16) float b_s[8 * 64];
    int p0 = blockIdx.x * 128;
    int n = p0 >> 10, sp0 = p0 & 1023;
    int tid = threadIdx.x;
    int px4 = tid & 31, cg = tid >> 5;
    int co8 = cg * 8;
    const float* h2 = ws + WS_B;
    const float* wt3 = ws + WS_WT3;

    float acc[4][8];
#pragma unroll
    for (int r = 0; r < 4; r++)
#pragma unroll
        for (int j = 0; j < 8; j++) acc[r][j] = bias[co8 + j];

    for (int c0 = 0; c0 < 256; c0 += 8) {
        __syncthreads();
#pragma unroll
        for (int it = 0; it < 4; it++) {
            int t = tid + it * 256;
            a_s[t] = h2[n * 262144 + (c0 + (t >> 7)) * 1024 + sp0 + (t & 127)];
        }
#pragma unroll
        for (int it = 0; it < 2; it++) {
            int t = tid + it * 256;
            b_s[t] = wt3[(c0 + (t >> 6)) * 64 + (t & 63)];
        }
        __syncthreads();
#pragma unroll
        for (int ci = 0; ci < 8; ci++) {
            float4 av = *(const float4*)&a_s[ci * 128 + px4 * 4];
            float4 w0 = *(const float4*)&b_s[ci * 64 + co8];
            float4 w1 = *(const float4*)&b_s[ci * 64 + co8 + 4];
            float wv[8] = {w0.x, w0.y, w0.z, w0.w, w1.x, w1.y, w1.z, w1.w};
            float a[4] = {av.x, av.y, av.z, av.w};
#pragma unroll
            for (int j = 0; j < 8; j++)
#pragma unroll
                for (int r = 0; r < 4; r++) acc[r][j] = fmaf(a[r], wv[j], acc[r][j]);
        }
    }
    float* z = ws + WS_Z;
#pragma unroll
    for (int r = 0; r < 4; r++) {
        int p = p0 + px4 * 4 + r;
        *(float4*)&z[p * 64 + co8] = make_float4(acc[r][0], acc[r][1], acc[r][2], acc[r][3]);
        *(float4*)&z[p * 64 + co8 + 4] = make_float4(acc[r][4], acc[r][5], acc[r][6], acc[r][7]);
    }
}

// ---------------- VQ: argmin over 512 codes, idx out, loss partial ----------------
__global__ __launch_bounds__(256) void k_vq(const float* __restrict__ codebook,
                                            float* __restrict__ out,
                                            float* __restrict__ ws) {
    __shared__ __align__(16) float cb_s[128 * 64];
    __shared__ __align__(16) float cc_s[128];
    int tid = threadIdx.x;
    int p = blockIdx.x * 256 + tid;
    const float* z = ws + WS_Z + p * 64;
    float4 z4[16];
#pragma unroll
    for (int i = 0; i < 16; i++) z4[i] = *(const float4*)&z[i * 4];
    float zz = 0.f;
#pragma unroll
    for (int i = 0; i < 16; i++)
        zz += z4[i].x * z4[i].x + z4[i].y * z4[i].y + z4[i].z * z4[i].z + z4[i].w * z4[i].w;

    float best = 3.4e38f;
    int bidx = 0;
    for (int k0 = 0; k0 < 512; k0 += 128) {
        __syncthreads();
#pragma unroll
        for (int it = 0; it < 32; it++) {
            int t = tid + it * 256;
            cb_s[t] = codebook[k0 * 64 + t];
        }
        if (tid < 128) cc_s[tid] = ws[WS_CC + k0 + tid];
        __syncthreads();
        for (int k = 0; k < 128; k++) {
            const float4* cp = (const float4*)&cb_s[k * 64];
            float dot = 0.f;
#pragma unroll
            for (int i = 0; i < 16; i++) {
                float4 c = cp[i];
                dot += z4[i].x * c.x + z4[i].y * c.y + z4[i].z * c.z + z4[i].w * c.w;
            }
            float d = fmaf(-2.f, dot, zz) + cc_s[k];
            if (d < best) { best = d; bidx = k0 + k; }
        }
    }
    out[OUT_IDX + p] = (float)bidx;
    ((int*)(ws + WS_IDX))[p] = bidx;

    float e = 0.f;
    const float4* q = (const float4*)&codebook[bidx * 64];
#pragma unroll
    for (int i = 0; i < 16; i++) {
        float4 qq = q[i];
        float d0 = z4[i].x - qq.x, d1 = z4[i].y - qq.y;
        float d2 = z4[i].z - qq.z, d3 = z4[i].w - qq.w;
        e += d0 * d0 + d1 * d1 + d2 * d2 + d3 * d3;
    }
#pragma unroll
    for (int off = 32; off; off >>= 1) e += __shfl_down(e, off);
    if ((tid & 63) == 0) atomicAdd(&ws[WS_LOSS], e);
}

__global__ void k_loss(float* __restrict__ out, const float* __restrict__ ws) {
    if (threadIdx.x == 0) {
        float v = ws[WS_LOSS] * (1.f / (65536.f * 64.f));
        out[OUT_LOSS_E] = v;
        out[OUT_LOSS_C] = v;
    }
}

// ---------------- gather fused-post rows: d_pix[p][:] = F[idx[p]][:] ----------------
__global__ __launch_bounds__(256) void k_gather(float* __restrict__ ws) {
    int tid = threadIdx.x;
    const int* idx = (const int*)(ws + WS_IDX);
    const float* F = ws + WS_F;
    float* dpx = ws + WS_B;
    int base = blockIdx.x * 64;
    for (int i = 0; i < 64; i++) {
        int row = idx[base + i];
        dpx[(base + i) * 256 + tid] = F[row * 256 + tid];
    }
}

// ---------------- dec1: conv_transpose 3x3 s2 p1 op1, 256->128, 32^2 -> 64^2, phases, +BN sums ----------------
__global__ __launch_bounds__(256) void k_dec1(const float* __restrict__ bias,
                                              float* __restrict__ ws) {
    __shared__ __align__(16) float in_s[8 * 5 * 34];
    __shared__ __align__(16) float w_s[8 * 4 * 64];
    int n = blockIdx.y;
    int bx = blockIdx.x;
    int cogrp = bx & 1, atile = (bx >> 1) & 7, phase = bx >> 4;
    int py = phase >> 1, px = phase & 1;
    int a0 = atile * 4, cobase = cogrp * 64;
    int tid = threadIdx.x;
    int b = tid & 31, cg = tid >> 5;
    int co8 = cobase + cg * 8;
    int ntsh = py + px;
    int ntap = 1 << ntsh;
    const float* dpx = ws + WS_B;
    const float* wt1 = ws + WS_WT1;

    float acc[4][8];
#pragma unroll
    for (int r = 0; r < 4; r++)
#pragma unroll
        for (int j = 0; j < 8; j++) acc[r][j] = bias[co8 + j];

    for (int c0 = 0; c0 < 256; c0 += 8) {
        __syncthreads();
        for (int t = tid; t < 8 * 5 * 34; t += 256) {
            int ci = t & 7, s = t >> 3;
            int cc2 = s % 34, row = s / 34;
            int iy = a0 + row;
            float v = 0.f;
            if (iy < 32 && cc2 < 32)
                v = dpx[(n * 1024 + iy * 32 + cc2) * 256 + c0 + ci];
            in_s[ci * 170 + row * 34 + cc2] = v;
        }
        int nw = (8 * 64) << ntsh;
        for (int t = tid; t < nw; t += 256) {
            int co = t & 63, s = t >> 6;
            int tt = s & (ntap - 1), ci = s >> ntsh;
            int ty = tt >> px, tx = tt & px;
            int ky = py ? 2 * ty : 1;
            int kx = px ? 2 * tx : 1;
            w_s[(ci * 4 + tt) * 64 + co] = wt1[(ky * 3 + kx) * 32768 + (c0 + ci) * 128 + cobase + co];
        }
        __syncthreads();
#pragma unroll
        for (int ci = 0; ci < 8; ci++) {
#pragma unroll
            for (int tt = 0; tt < 4; tt++) {
                if (tt >= ntap) break;
                int ty = tt >> px, tx = tt & px;
                int dyv = py ? 1 - ty : 0;
                int dxv = px ? 1 - tx : 0;
                const float* wp = &w_s[(ci * 4 + tt) * 64 + cg * 8];
                float wv[8];
#pragma unroll
                for (int j = 0; j < 8; j++) wv[j] = wp[j];
                const float* ip = &in_s[ci * 170 + dyv * 34 + b + dxv];
#pragma unroll
                for (int r = 0; r < 4; r++) {
                    float v = ip[r * 34];
#pragma unroll
                    for (int j = 0; j < 8; j++) acc[r][j] = fmaf(v, wv[j], acc[r][j]);
                }
            }
        }
    }
    float* h3 = ws + WS_A;
    int xcol = 2 * b + px;
#pragma unroll
    for (int j = 0; j < 8; j++) {
        int co = co8 + j;
#pragma unroll
        for (int r = 0; r < 4; r++) {
            int y = 2 * (a0 + r) + py;
            h3[((n * 128 + co) * 64 + y) * 64 + xcol] = acc[r][j];
        }
        float s1 = acc[0][j] + acc[1][j] + acc[2][j] + acc[3][j];
        float s2 = acc[0][j] * acc[0][j] + acc[1][j] * acc[1][j]
                 + acc[2][j] * acc[2][j] + acc[3][j] * acc[3][j];
#pragma unroll
        for (int off = 16; off; off >>= 1) {
            s1 += __shfl_xor(s1, off);
            s2 += __shfl_xor(s2, off);
        }
        if ((tid & 31) == 0) {
            atomicAdd(&ws[WS_BN2SUM + co], s1);
            atomicAdd(&ws[WS_BN2SUM + 128 + co], s2);
        }
    }
}

// ---------------- dec2: conv_transpose 3x3 s2 p1 op1, 128->3, 64^2 -> 128^2, BN2+ReLU on load, tanh ----------------
__global__ __launch_bounds__(256) void k_dec2(const float* __restrict__ w,
                                              const float* __restrict__ bias,
                                              float* __restrict__ out,
                                              float* __restrict__ ws) {
    __shared__ __align__(16) float in_s[8 * 5 * 66];
    __shared__ __align__(16) float w_s[8 * 4 * 3];
    int n = blockIdx.y;
    int bx = blockIdx.x;
    int atile = bx & 15, phase = bx >> 4;
    int py = phase >> 1, px = phase & 1;
    int a0 = atile * 4;
    int tid = threadIdx.x;
    int b = tid & 63, r4 = tid >> 6;
    int ntsh = py + px;
    int ntap = 1 << ntsh;
    const float* h3 = ws + WS_A;
    const float* sc = ws + WS_BN2SC;
    const float* sh = ws + WS_BN2SH;

    float acc[3] = {bias[0], bias[1], bias[2]};
    for (int c0 = 0; c0 < 128; c0 += 8) {
        __syncthreads();
        for (int t = tid; t < 8 * 5 * 66; t += 256) {
            int cL = t % 66, s = t / 66;
            int row = s % 5, ci = s / 5;
            int ciG = c0 + ci;
            int iy = a0 + row;
            float v = 0.f;
            if (iy < 64 && cL < 64) {
                float raw = h3[((n * 128 + ciG) * 64 + iy) * 64 + cL];
                v = fmaxf(fmaf(raw, sc[ciG], sh[ciG]), 0.f);
            }
            in_s[ci * 330 + row * 66 + cL] = v;
        }
        int nwt = 24 << ntsh;
        for (int t = tid; t < nwt; t += 256) {
            int co = t % 3, s = t / 3;
            int tt = s & (ntap - 1), ci = s >> ntsh;
            int ty = tt >> px, tx = tt & px;
            int ky = py ? 2 * ty : 1;
            int kx = px ? 2 * tx : 1;
            w_s[(ci * 4 + tt) * 3 + co] = w[(c0 + ci) * 27 + co * 9 + ky * 3 + kx];
        }
        __syncthreads();
#pragma unroll
        for (int ci = 0; ci < 8; ci++) {
#pragma unroll
            for (int tt = 0; tt < 4; tt++) {
                if (tt >= ntap) break;
                int ty = tt >> px, tx = tt & px;
                int dyv = py ? 1 - ty : 0;
                int dxv = px ? 1 - tx : 0;
                float v = in_s[ci * 330 + (r4 + dyv) * 66 + b + dxv];
                acc[0] = fmaf(v, w_s[(ci * 4 + tt) * 3 + 0], acc[0]);
                acc[1] = fmaf(v, w_s[(ci * 4 + tt) * 3 + 1], acc[1]);
                acc[2] = fmaf(v, w_s[(ci * 4 + tt) * 3 + 2], acc[2]);
            }
        }
    }
    int y = 2 * (a0 + r4) + py, xcol = 2 * b + px;
#pragma unroll
    for (int co = 0; co < 3; co++)
        out[(n * 3 + co) * 16384 + y * 128 + xcol] = tanhf(acc[co]);
}

// ---------------- launch ----------------
extern "C" void kernel_launch(void* const* d_in, const int* in_sizes, int n_in,
                              void* d_out, int out_size, void* d_ws, size_t ws_size,
                              hipStream_t stream) {
    const float* x       = (const float*)d_in[0];
    const float* enc1_w  = (const float*)d_in[1];
    const float* enc1_b  = (const float*)d_in[2];
    const float* bn1_g   = (const float*)d_in[3];
    const float* bn1_b   = (const float*)d_in[4];
    const float* enc2_w  = (const float*)d_in[5];
    const float* enc2_b  = (const float*)d_in[6];
    const float* pre_w   = (const float*)d_in[7];
    const float* pre_b   = (const float*)d_in[8];
    const float* codebook= (const float*)d_in[9];
    const float* post_w  = (const float*)d_in[10];
    const float* post_b  = (const float*)d_in[11];
    const float* dec1_w  = (const float*)d_in[12];
    const float* dec1_b  = (const float*)d_in[13];
    const float* dbn1_g  = (const float*)d_in[14];
    const float* dbn1_b  = (const float*)d_in[15];
    const float* dec2_w  = (const float*)d_in[16];
    const float* dec2_b  = (const float*)d_in[17];
    float* out = (float*)d_out;
    float* ws  = (float*)d_ws;

    hipMemsetAsync(ws, 0, 4096, stream);  // BN sums + loss accumulators

    k_wt<<<2368, 256, 0, stream>>>(dec1_w, enc2_w, pre_w, ws);
    k_F<<<512, 256, 0, stream>>>(codebook, post_w, post_b, ws);
    k_enc1<<<dim3(64, 64), 256, 0, stream>>>(x, enc1_w, enc1_b, ws);
    k_bnfin<<<1, 128, 0, stream>>>(ws + WS_BN1SUM, bn1_g, bn1_b,
                                   ws + WS_BN1SC, ws + WS_BN1SH, 1.f / 262144.f);
    k_enc2<<<dim3(32, 64), 256, 0, stream>>>(enc2_b, ws);
    k_pre<<<512, 256, 0, stream>>>(pre_b, ws);
    k_vq<<<256, 256, 0, stream>>>(codebook, out, ws);
    k_loss<<<1, 64, 0, stream>>>(out, ws);
    k_gather<<<1024, 256, 0, stream>>>(ws);
    k_dec1<<<dim3(64, 64), 256, 0, stream>>>(dec1_b, ws);
    k_bnfin<<<1, 128, 0, stream>>>(ws + WS_BN2SUM, dbn1_g, dbn1_b,
                                   ws + WS_BN2SC, ws + WS_BN2SH, 1.f / 262144.f);
    k_dec2<<<dim3(64, 64), 256, 0, stream>>>(dec2_w, dec2_b, out, ws);
}

// Round 2
// 2484.103 us; speedup vs baseline: 1.0194x; 1.0194x over previous
//
#include <hip/hip_runtime.h>

#define EPS 1e-5f

// ---------------- ws layout (float offsets) ----------------
#define WS_BN1SUM   0         // 256 (s1[128], s2[128])
#define WS_BN2SUM   256       // 256
#define WS_LOSS     512       // 1
#define WS_BN1SC    1024      // 128
#define WS_BN1SH    1152      // 128
#define WS_BN2SC    1280      // 128
#define WS_BN2SH    1408      // 128
#define WS_CC       1536      // 512 code norms
#define WS_IDX      2048      // 65536 ints
#define WS_WT3      67584     // 16384  pre_w^T  [ci][co]
#define WS_WT1      83968     // 294912 dec1_w^T [tap][ci][co]
#define WS_WT2      378880    // 294912 enc2_w^T [(ci*9+tap)][co]
#define WS_F        673792    // 131072 fused post table [k][co]
#define WS_A        1048576   // 33554432: h1raw, then z_pix (aliased), then h3raw
#define WS_B        34603008  // 16777216: h2, then d_pix
#define WS_Z        WS_A
// total = 51380224 floats = 205.5 MB

#define OUT_LOSS_E  3145728
#define OUT_LOSS_C  3145729
#define OUT_IDX     3145730

// ---------------- weight pre-transpose ----------------
__global__ __launch_bounds__(256) void k_wt(const float* __restrict__ dec1_w,
                                            const float* __restrict__ enc2_w,
                                            const float* __restrict__ pre_w,
                                            float* __restrict__ ws) {
    int g = blockIdx.x * 256 + threadIdx.x;
    if (g < 294912) {                       // wt1[tap*32768 + ci*128 + co] <- dec1_w[ci][co][tap]
        int co = g & 127, ci = (g >> 7) & 255, tap = g >> 15;
        ws[WS_WT1 + g] = dec1_w[ci * 1152 + co * 9 + tap];
    } else if (g < 2 * 294912) {            // wt2[(ci*9+tap)*256 + co] <- enc2_w[co][ci][tap]
        int h = g - 294912;
        int co = h & 255, q = h >> 8;
        int ci = q / 9, tap = q - ci * 9;
        ws[WS_WT2 + h] = enc2_w[co * 1152 + ci * 9 + tap];
    } else if (g < 2 * 294912 + 16384) {    // wt3[ci*64+co] <- pre_w[co][ci]
        int h = g - 2 * 294912;
        int co = h & 63, ci = h >> 6;
        ws[WS_WT3 + h] = pre_w[co * 256 + ci];
    }
}

// ---------------- fused post table F = codebook @ post_w^T + post_b; code norms ----------------
__global__ __launch_bounds__(256) void k_F(const float* __restrict__ codebook,
                                           const float* __restrict__ post_w,
                                           const float* __restrict__ post_b,
                                           float* __restrict__ ws) {
    __shared__ __align__(16) float cbr[64];
    int k = blockIdx.x, co = threadIdx.x;
    if (co < 64) cbr[co] = codebook[k * 64 + co];
    __syncthreads();
    float acc = post_b[co];
#pragma unroll
    for (int i = 0; i < 64; i += 4) {
        float4 w4 = *(const float4*)&post_w[co * 64 + i];
        acc = fmaf(cbr[i], w4.x, acc);
        acc = fmaf(cbr[i + 1], w4.y, acc);
        acc = fmaf(cbr[i + 2], w4.z, acc);
        acc = fmaf(cbr[i + 3], w4.w, acc);
    }
    ws[WS_F + k * 256 + co] = acc;
    if (co == 0) {
        float s = 0.f;
        for (int i = 0; i < 64; i++) s += cbr[i] * cbr[i];
        ws[WS_CC + k] = s;
    }
}

// ---------------- enc1: 3x3 s2 p1, 3->128, 128^2 -> 64^2, + BN partial sums ----------------
__global__ __launch_bounds__(256) void k_enc1(const float* __restrict__ x,
                                              const float* __restrict__ w,
                                              const float* __restrict__ bias,
                                              float* __restrict__ ws) {
    __shared__ __align__(16) float in_s[3 * 9 * 130];
    __shared__ __align__(16) float w_s[27 * 32];
    int n = blockIdx.y;
    int cog = blockIdx.x & 3, yt = blockIdx.x >> 2;
    int y0 = yt * 4, cobase = cog * 32;
    int tid = threadIdx.x;
    int xo = tid & 63, cg = tid >> 6;
    int co8 = cobase + cg * 8;

    for (int t = tid; t < 3 * 9 * 130; t += 256) {
        int c = t % 130, rest = t / 130;
        int row = rest % 9, ci = rest / 9;
        int iy = 2 * y0 - 1 + row, ix = c - 1;
        float v = 0.f;
        if ((unsigned)iy < 128u && (unsigned)ix < 128u)
            v = x[(n * 3 + ci) * 16384 + iy * 128 + ix];
        in_s[t] = v;
    }
    for (int t = tid; t < 864; t += 256) {
        int co = t & 31, q = t >> 5;
        w_s[q * 32 + co] = w[(cobase + co) * 27 + q];
    }
    __syncthreads();

    float acc[4][8];
#pragma unroll
    for (int r = 0; r < 4; r++)
#pragma unroll
        for (int j = 0; j < 8; j++) acc[r][j] = bias[co8 + j];

#pragma unroll
    for (int ci = 0; ci < 3; ci++)
#pragma unroll
        for (int ky = 0; ky < 3; ky++) {
            float v[4][3];
#pragma unroll
            for (int r = 0; r < 4; r++) {
                const float* bp = &in_s[ci * 1170 + (2 * r + ky) * 130 + 2 * xo];
                v[r][0] = bp[0]; v[r][1] = bp[1]; v[r][2] = bp[2];
            }
#pragma unroll
            for (int kx = 0; kx < 3; kx++) {
                const float* wp = &w_s[(ci * 9 + ky * 3 + kx) * 32 + cg * 8];
#pragma unroll
                for (int j = 0; j < 8; j++) {
                    float wv = wp[j];
#pragma unroll
                    for (int r = 0; r < 4; r++) acc[r][j] = fmaf(v[r][kx], wv, acc[r][j]);
                }
            }
        }

    float* h1 = ws + WS_A;
#pragma unroll
    for (int j = 0; j < 8; j++) {
        int co = co8 + j;
#pragma unroll
        for (int r = 0; r < 4; r++)
            h1[((n * 128 + co) * 64 + y0 + r) * 64 + xo] = acc[r][j];
        float s1 = acc[0][j] + acc[1][j] + acc[2][j] + acc[3][j];
        float s2 = acc[0][j] * acc[0][j] + acc[1][j] * acc[1][j]
                 + acc[2][j] * acc[2][j] + acc[3][j] * acc[3][j];
#pragma unroll
        for (int off = 32; off; off >>= 1) {
            s1 += __shfl_down(s1, off);
            s2 += __shfl_down(s2, off);
        }
        if ((tid & 63) == 0) {
            atomicAdd(&ws[WS_BN1SUM + co], s1);
            atomicAdd(&ws[WS_BN1SUM + 128 + co], s2);
        }
    }
}

// ---------------- BN finalize: scale/shift per channel ----------------
__global__ __launch_bounds__(128) void k_bnfin(const float* __restrict__ sums,
                                               const float* __restrict__ g,
                                               const float* __restrict__ b,
                                               float* __restrict__ scale,
                                               float* __restrict__ shift, float invN) {
    int c = threadIdx.x;
    float mean = sums[c] * invN;
    float var = sums[128 + c] * invN - mean * mean;
    float sc = g[c] * rsqrtf(var + EPS);
    scale[c] = sc;
    shift[c] = b[c] - mean * sc;
}

// ---------------- enc2: 3x3 s2 p1, 128->256, 64^2 -> 32^2 (BN1+ReLU applied on load) ----------------
__global__ __launch_bounds__(256) void k_enc2(const float* __restrict__ bias,
                                              float* __restrict__ ws) {
    __shared__ __align__(16) float in_s[8 * 9 * 66];
    __shared__ __align__(16) float w_s[72 * 64];
    int n = blockIdx.y;
    int cog = blockIdx.x & 3, yt = blockIdx.x >> 2;
    int y0 = yt * 4, cobase = cog * 64;
    int tid = threadIdx.x;
    int xo = tid & 31, cg = tid >> 5;
    int co8g = cobase + cg * 8;
    const float* h1 = ws + WS_A;
    const float* sc = ws + WS_BN1SC;
    const float* sh = ws + WS_BN1SH;
    const float* wt2 = ws + WS_WT2;

    float acc[4][8];
#pragma unroll
    for (int r = 0; r < 4; r++)
#pragma unroll
        for (int j = 0; j < 8; j++) acc[r][j] = bias[co8g + j];

    for (int c0 = 0; c0 < 128; c0 += 8) {
        __syncthreads();
        for (int t = tid; t < 8 * 9 * 66; t += 256) {
            int c = t % 66, rest = t / 66;
            int row = rest % 9, ci = rest / 9;
            int ciG = c0 + ci;
            int iy = 2 * y0 - 1 + row, ix = c - 1;
            float v = 0.f;
            if ((unsigned)iy < 64u && (unsigned)ix < 64u) {
                float raw = h1[((n * 128 + ciG) * 64 + iy) * 64 + ix];
                v = fmaxf(fmaf(raw, sc[ciG], sh[ciG]), 0.f);
            }
            in_s[t] = v;
        }
        for (int t = tid; t < 72 * 64; t += 256) {
            int co = t & 63, q = t >> 6;
            w_s[t] = wt2[(c0 * 9 + q) * 256 + cobase + co];
        }
        __syncthreads();
#pragma unroll
        for (int ci = 0; ci < 8; ci++) {
#pragma unroll
            for (int ky = 0; ky < 3; ky++) {
                float v[4][3];
#pragma unroll
                for (int r = 0; r < 4; r++) {
                    const float* bp = &in_s[ci * 594 + (2 * r + ky) * 66 + 2 * xo];
                    v[r][0] = bp[0]; v[r][1] = bp[1]; v[r][2] = bp[2];
                }
#pragma unroll
                for (int kx = 0; kx < 3; kx++) {
                    const float* wp = &w_s[(ci * 9 + ky * 3 + kx) * 64 + cg * 8];
#pragma unroll
                    for (int j = 0; j < 8; j++) {
                        float wv = wp[j];
#pragma unroll
                        for (int r = 0; r < 4; r++) acc[r][j] = fmaf(v[r][kx], wv, acc[r][j]);
                    }
                }
            }
        }
    }
    float* h2 = ws + WS_B;
#pragma unroll
    for (int j = 0; j < 8; j++) {
        int co = co8g + j;
#pragma unroll
        for (int r = 0; r < 4; r++)
            h2[((n * 256 + co) * 32 + y0 + r) * 32 + xo] = acc[r][j];
    }
}

// ---------------- pre: 1x1, 256->64, out NHWC z_pix[p][c] ----------------
__global__ __launch_bounds__(256) void k_pre(const float* __restrict__ bias,
                                             float* __restrict__ ws) {
    __shared__ __align__(16) float a_s[8 * 128];
    __shared__ __align__(16) float b_s[8 * 64];
    int p0 = blockIdx.x * 128;
    int n = p0 >> 10, sp0 = p0 & 1023;
    int tid = threadIdx.x;
    int px4 = tid & 31, cg = tid >> 5;
    int co8 = cg * 8;
    const float* h2 = ws + WS_B;
    const float* wt3 = ws + WS_WT3;

    float acc[4][8];
#pragma unroll
    for (int r = 0; r < 4; r++)
#pragma unroll
        for (int j = 0; j < 8; j++) acc[r][j] = bias[co8 + j];

    for (int c0 = 0; c0 < 256; c0 += 8) {
        __syncthreads();
#pragma unroll
        for (int it = 0; it < 4; it++) {
            int t = tid + it * 256;
            a_s[t] = h2[n * 262144 + (c0 + (t >> 7)) * 1024 + sp0 + (t & 127)];
        }
#pragma unroll
        for (int it = 0; it < 2; it++) {
            int t = tid + it * 256;
            b_s[t] = wt3[(c0 + (t >> 6)) * 64 + (t & 63)];
        }
        __syncthreads();
#pragma unroll
        for (int ci = 0; ci < 8; ci++) {
            float4 av = *(const float4*)&a_s[ci * 128 + px4 * 4];
            float4 w0 = *(const float4*)&b_s[ci * 64 + co8];
            float4 w1 = *(const float4*)&b_s[ci * 64 + co8 + 4];
            float wv[8] = {w0.x, w0.y, w0.z, w0.w, w1.x, w1.y, w1.z, w1.w};
            float a[4] = {av.x, av.y, av.z, av.w};
#pragma unroll
            for (int j = 0; j < 8; j++)
#pragma unroll
                for (int r = 0; r < 4; r++) acc[r][j] = fmaf(a[r], wv[j], acc[r][j]);
        }
    }
    float* z = ws + WS_Z;
#pragma unroll
    for (int r = 0; r < 4; r++) {
        int p = p0 + px4 * 4 + r;
        *(float4*)&z[p * 64 + co8] = make_float4(acc[r][0], acc[r][1], acc[r][2], acc[r][3]);
        *(float4*)&z[p * 64 + co8 + 4] = make_float4(acc[r][4], acc[r][5], acc[r][6], acc[r][7]);
    }
}

// ---------------- VQ: argmin over 512 codes, idx out, loss partial ----------------
// launch_bounds(256,2): cap VGPR at 256 so z4[16] (64 VGPRs) stays in registers.
// Round-1 failure: default VGPR target (64) spilled z4 to scratch -> 31 GB scratch traffic.
__global__ __launch_bounds__(256, 2) void k_vq(const float* __restrict__ codebook,
                                               float* __restrict__ out,
                                               float* __restrict__ ws) {
    __shared__ __align__(16) float cb_s[128 * 64];
    __shared__ __align__(16) float cc_s[128];
    int tid = threadIdx.x;
    int p = blockIdx.x * 256 + tid;
    const float* z = ws + WS_Z + p * 64;
    float4 z4[16];
#pragma unroll
    for (int i = 0; i < 16; i++) z4[i] = *(const float4*)&z[i * 4];
    float zz = 0.f;
#pragma unroll
    for (int i = 0; i < 16; i++)
        zz += z4[i].x * z4[i].x + z4[i].y * z4[i].y + z4[i].z * z4[i].z + z4[i].w * z4[i].w;

    float best = 3.4e38f;
    int bidx = 0;
    for (int k0 = 0; k0 < 512; k0 += 128) {
        __syncthreads();
#pragma unroll
        for (int it = 0; it < 32; it++) {
            int t = tid + it * 256;
            cb_s[t] = codebook[k0 * 64 + t];
        }
        if (tid < 128) cc_s[tid] = ws[WS_CC + k0 + tid];
        __syncthreads();
        for (int k = 0; k < 128; k++) {
            const float4* cp = (const float4*)&cb_s[k * 64];
            float d0 = 0.f, d1 = 0.f, d2 = 0.f, d3 = 0.f;
#pragma unroll
            for (int i = 0; i < 16; i += 4) {
                float4 c0v = cp[i], c1v = cp[i + 1], c2v = cp[i + 2], c3v = cp[i + 3];
                d0 += z4[i].x * c0v.x + z4[i].y * c0v.y + z4[i].z * c0v.z + z4[i].w * c0v.w;
                d1 += z4[i + 1].x * c1v.x + z4[i + 1].y * c1v.y + z4[i + 1].z * c1v.z + z4[i + 1].w * c1v.w;
                d2 += z4[i + 2].x * c2v.x + z4[i + 2].y * c2v.y + z4[i + 2].z * c2v.z + z4[i + 2].w * c2v.w;
                d3 += z4[i + 3].x * c3v.x + z4[i + 3].y * c3v.y + z4[i + 3].z * c3v.z + z4[i + 3].w * c3v.w;
            }
            float dot = (d0 + d1) + (d2 + d3);
            float d = fmaf(-2.f, dot, zz) + cc_s[k];
            if (d < best) { best = d; bidx = k0 + k; }
        }
    }
    out[OUT_IDX + p] = (float)bidx;
    ((int*)(ws + WS_IDX))[p] = bidx;

    float e = 0.f;
    const float4* q = (const float4*)&codebook[bidx * 64];
#pragma unroll
    for (int i = 0; i < 16; i++) {
        float4 qq = q[i];
        float d0 = z4[i].x - qq.x, d1 = z4[i].y - qq.y;
        float d2 = z4[i].z - qq.z, d3 = z4[i].w - qq.w;
        e += d0 * d0 + d1 * d1 + d2 * d2 + d3 * d3;
    }
#pragma unroll
    for (int off = 32; off; off >>= 1) e += __shfl_down(e, off);
    if ((tid & 63) == 0) atomicAdd(&ws[WS_LOSS], e);
}

__global__ void k_loss(float* __restrict__ out, const float* __restrict__ ws) {
    if (threadIdx.x == 0) {
        float v = ws[WS_LOSS] * (1.f / (65536.f * 64.f));
        out[OUT_LOSS_E] = v;
        out[OUT_LOSS_C] = v;
    }
}

// ---------------- gather fused-post rows: d_pix[p][:] = F[idx[p]][:] ----------------
__global__ __launch_bounds__(256) void k_gather(float* __restrict__ ws) {
    int tid = threadIdx.x;
    const int* idx = (const int*)(ws + WS_IDX);
    const float* F = ws + WS_F;
    float* dpx = ws + WS_B;
    int base = blockIdx.x * 64;
    for (int i = 0; i < 64; i++) {
        int row = idx[base + i];
        dpx[(base + i) * 256 + tid] = F[row * 256 + tid];
    }
}

// ---------------- dec1: conv_transpose 3x3 s2 p1 op1, 256->128, 32^2 -> 64^2 ----------------
// All 4 parity phases merged into one 1024-thread block: input tile staged ONCE
// (was 4x redundant across phase-blocks), all 9 weight taps staged, barriers
// amortized over 4x the compute. Phase = tid>>8 (wave-uniform).
__global__ __launch_bounds__(1024, 2) void k_dec1(const float* __restrict__ bias,
                                                  float* __restrict__ ws) {
    __shared__ __align__(16) float in_s[8 * 5 * 34];      // 5.4 KB
    __shared__ __align__(16) float w_s[8 * 9 * 64];       // 18.4 KB
    int n = blockIdx.y;
    int bx = blockIdx.x;
    int cogrp = bx & 1, atile = bx >> 1;
    int a0 = atile * 4, cobase = cogrp * 64;
    int tid = threadIdx.x;
    int phase = tid >> 8;
    int py = phase >> 1, px = phase & 1;
    int tidl = tid & 255;
    int b = tidl & 31, cg = tidl >> 5;
    int co8 = cobase + cg * 8;
    int ntsh = py + px;
    int ntap = 1 << ntsh;
    const float* dpx = ws + WS_B;
    const float* wt1 = ws + WS_WT1;

    float acc[4][8];
#pragma unroll
    for (int r = 0; r < 4; r++)
#pragma unroll
        for (int j = 0; j < 8; j++) acc[r][j] = bias[co8 + j];

    for (int c0 = 0; c0 < 256; c0 += 8) {
        __syncthreads();
        for (int t = tid; t < 8 * 5 * 34; t += 1024) {
            int ci = t & 7, s = t >> 3;
            int cc2 = s % 34, row = s / 34;
            int iy = a0 + row;
            float v = 0.f;
            if (iy < 32 && cc2 < 32)
                v = dpx[(n * 1024 + iy * 32 + cc2) * 256 + c0 + ci];
            in_s[ci * 170 + row * 34 + cc2] = v;
        }
        for (int t = tid; t < 8 * 9 * 64; t += 1024) {
            int co = t & 63, q = t >> 6;     // q = ci*9 + tap
            int ci = q / 9, tap = q - ci * 9;
            w_s[t] = wt1[tap * 32768 + (c0 + ci) * 128 + cobase + co];
        }
        __syncthreads();
#pragma unroll
        for (int ci = 0; ci < 8; ci++) {
#pragma unroll
            for (int tt = 0; tt < 4; tt++) {
                if (tt >= ntap) break;
                int ty = tt >> px, tx = tt & px;
                int ky = py ? 2 * ty : 1;
                int kx = px ? 2 * tx : 1;
                int dyv = py ? 1 - ty : 0;
                int dxv = px ? 1 - tx : 0;
                const float* wp = &w_s[(ci * 9 + ky * 3 + kx) * 64 + cg * 8];
                float wv[8];
#pragma unroll
                for (int j = 0; j < 8; j++) wv[j] = wp[j];
                const float* ip = &in_s[ci * 170 + dyv * 34 + b + dxv];
#pragma unroll
                for (int r = 0; r < 4; r++) {
                    float v = ip[r * 34];
#pragma unroll
                    for (int j = 0; j < 8; j++) acc[r][j] = fmaf(v, wv[j], acc[r][j]);
                }
            }
        }
    }
    float* h3 = ws + WS_A;
    int xcol = 2 * b + px;
#pragma unroll
    for (int j = 0; j < 8; j++) {
        int co = co8 + j;
#pragma unroll
        for (int r = 0; r < 4; r++) {
            int y = 2 * (a0 + r) + py;
            h3[((n * 128 + co) * 64 + y) * 64 + xcol] = acc[r][j];
        }
        float s1 = acc[0][j] + acc[1][j] + acc[2][j] + acc[3][j];
        float s2 = acc[0][j] * acc[0][j] + acc[1][j] * acc[1][j]
                 + acc[2][j] * acc[2][j] + acc[3][j] * acc[3][j];
#pragma unroll
        for (int off = 16; off; off >>= 1) {
            s1 += __shfl_xor(s1, off);
            s2 += __shfl_xor(s2, off);
        }
        if ((tid & 31) == 0) {
            atomicAdd(&ws[WS_BN2SUM + co], s1);
            atomicAdd(&ws[WS_BN2SUM + 128 + co], s2);
        }
    }
}

// ---------------- dec2: conv_transpose 3x3 s2 p1 op1, 128->3, BN2+ReLU on load, tanh ----------------
// Phases merged like dec1: 1024 threads, input staged once, all 9 taps staged.
__global__ __launch_bounds__(1024, 2) void k_dec2(const float* __restrict__ w,
                                                  const float* __restrict__ bias,
                                                  float* __restrict__ out,
                                                  float* __restrict__ ws) {
    __shared__ __align__(16) float in_s[8 * 5 * 66];      // 10.6 KB
    __shared__ __align__(16) float w_s[8 * 9 * 3];
    int n = blockIdx.y;
    int atile = blockIdx.x;
    int a0 = atile * 4;
    int tid = threadIdx.x;
    int phase = tid >> 8;
    int py = phase >> 1, px = phase & 1;
    int tidl = tid & 255;
    int b = tidl & 63, r4 = tidl >> 6;
    int ntsh = py + px;
    int ntap = 1 << ntsh;
    const float* h3 = ws + WS_A;
    const float* sc = ws + WS_BN2SC;
    const float* sh = ws + WS_BN2SH;

    float acc[3] = {bias[0], bias[1], bias[2]};
    for (int c0 = 0; c0 < 128; c0 += 8) {
        __syncthreads();
        for (int t = tid; t < 8 * 5 * 66; t += 1024) {
            int cL = t % 66, s = t / 66;
            int row = s % 5, ci = s / 5;
            int ciG = c0 + ci;
            int iy = a0 + row;
            float v = 0.f;
            if (iy < 64 && cL < 64) {
                float raw = h3[((n * 128 + ciG) * 64 + iy) * 64 + cL];
                v = fmaxf(fmaf(raw, sc[ciG], sh[ciG]), 0.f);
            }
            in_s[ci * 330 + row * 66 + cL] = v;
        }
        if (tid < 8 * 9 * 3) {
            int co = tid % 3, q = tid / 3;   // q = ci*9 + tap
            int ci = q / 9, tap = q - ci * 9;
            w_s[q * 3 + co] = w[(c0 + ci) * 27 + co * 9 + tap];
        }
        __syncthreads();
#pragma unroll
        for (int ci = 0; ci < 8; ci++) {
#pragma unroll
            for (int tt = 0; tt < 4; tt++) {
                if (tt >= ntap) break;
                int ty = tt >> px, tx = tt & px;
                int ky = py ? 2 * ty : 1;
                int kx = px ? 2 * tx : 1;
                int dyv = py ? 1 - ty : 0;
                int dxv = px ? 1 - tx : 0;
                float v = in_s[ci * 330 + (r4 + dyv) * 66 + b + dxv];
                const float* wp = &w_s[(ci * 9 + ky * 3 + kx) * 3];
                acc[0] = fmaf(v, wp[0], acc[0]);
                acc[1] = fmaf(v, wp[1], acc[1]);
                acc[2] = fmaf(v, wp[2], acc[2]);
            }
        }
    }
    int y = 2 * (a0 + r4) + py, xcol = 2 * b + px;
#pragma unroll
    for (int co = 0; co < 3; co++)
        out[(n * 3 + co) * 16384 + y * 128 + xcol] = tanhf(acc[co]);
}

// ---------------- launch ----------------
extern "C" void kernel_launch(void* const* d_in, const int* in_sizes, int n_in,
                              void* d_out, int out_size, void* d_ws, size_t ws_size,
                              hipStream_t stream) {
    const float* x       = (const float*)d_in[0];
    const float* enc1_w  = (const float*)d_in[1];
    const float* enc1_b  = (const float*)d_in[2];
    const float* bn1_g   = (const float*)d_in[3];
    const float* bn1_b   = (const float*)d_in[4];
    const float* enc2_w  = (const float*)d_in[5];
    const float* enc2_b  = (const float*)d_in[6];
    const float* pre_w   = (const float*)d_in[7];
    const float* pre_b   = (const float*)d_in[8];
    const float* codebook= (const float*)d_in[9];
    const float* post_w  = (const float*)d_in[10];
    const float* post_b  = (const float*)d_in[11];
    const float* dec1_w  = (const float*)d_in[12];
    const float* dec1_b  = (const float*)d_in[13];
    const float* dbn1_g  = (const float*)d_in[14];
    const float* dbn1_b  = (const float*)d_in[15];
    const float* dec2_w  = (const float*)d_in[16];
    const float* dec2_b  = (const float*)d_in[17];
    float* out = (float*)d_out;
    float* ws  = (float*)d_ws;

    hipMemsetAsync(ws, 0, 4096, stream);  // BN sums + loss accumulators

    k_wt<<<2368, 256, 0, stream>>>(dec1_w, enc2_w, pre_w, ws);
    k_F<<<512, 256, 0, stream>>>(codebook, post_w, post_b, ws);
    k_enc1<<<dim3(64, 64), 256, 0, stream>>>(x, enc1_w, enc1_b, ws);
    k_bnfin<<<1, 128, 0, stream>>>(ws + WS_BN1SUM, bn1_g, bn1_b,
                                   ws + WS_BN1SC, ws + WS_BN1SH, 1.f / 262144.f);
    k_enc2<<<dim3(32, 64), 256, 0, stream>>>(enc2_b, ws);
    k_pre<<<512, 256, 0, stream>>>(pre_b, ws);
    k_vq<<<256, 256, 0, stream>>>(codebook, out, ws);
    k_loss<<<1, 64, 0, stream>>>(out, ws);
    k_gather<<<1024, 256, 0, stream>>>(ws);
    k_dec1<<<dim3(16, 64), 1024, 0, stream>>>(dec1_b, ws);
    k_bnfin<<<1, 128, 0, stream>>>(ws + WS_BN2SUM, dbn1_g, dbn1_b,
                                   ws + WS_BN2SC, ws + WS_BN2SH, 1.f / 262144.f);
    k_dec2<<<dim3(16, 64), 1024, 0, stream>>>(dec2_w, dec2_b, out, ws);
}

// Round 3
// 1703.589 us; speedup vs baseline: 1.4864x; 1.4582x over previous
//
#include <hip/hip_runtime.h>

#define EPS 1e-5f

typedef __attribute__((ext_vector_type(8))) short short8;
typedef __attribute__((ext_vector_type(4))) float f32x4;

__device__ inline ushort f2bf(float f) {
    uint u = __float_as_uint(f);
    u += 0x7FFFu + ((u >> 16) & 1u);
    return (ushort)(u >> 16);
}
__device__ inline float bf2f(ushort h) { return __uint_as_float(((uint)h) << 16); }

// ---------------- ws layout (float offsets) ----------------
#define WS_BN1SUM   0         // 256 (s1[128], s2[128])
#define WS_LOSS     512       // 1
#define WS_BN1SC    1024      // 128
#define WS_BN1SH    1152      // 128
#define WS_BN2SC    1280      // 128
#define WS_BN2SH    1408      // 128
#define WS_CC       1536      // 512 code norms
#define WS_IDX      2048      // 65536 ints
#define WS_WT3      67584     // 16384  pre_w^T  [ci][co]
#define WS_WT1      83968     // 294912 floats = 589824 ushorts: dec1_w split-bf16 [tap][co][ci] hi then lo
#define WS_WT2      378880    // 294912 enc2_w^T [(ci*9+tap)][co]
#define WS_F        673792    // 131072 fused post table [k][co]
#define WS_BN2S8    804864    // 8 shadow copies x 256 (s1[128], s2[128])
#define WS_A        1048576   // 33554432: h1raw -> z_pix (aliased) -> h3 (NHWC)
#define WS_B        34603008  // 16777216: h2 -> d_pix [p][256] fp32
#define WS_Z        WS_A

#define OUT_LOSS_E  3145728
#define OUT_LOSS_C  3145729
#define OUT_IDX     3145730

// ---------------- weight pre-transpose / split ----------------
__global__ __launch_bounds__(256) void k_wt(const float* __restrict__ dec1_w,
                                            const float* __restrict__ enc2_w,
                                            const float* __restrict__ pre_w,
                                            float* __restrict__ ws) {
    int g = blockIdx.x * 256 + threadIdx.x;
    if (g < 294912) {
        // wB[(tap*128+co)*256+ci] split hi/lo bf16 <- dec1_w[ci][co][tap]
        int ci = g & 255, co = (g >> 8) & 127, tap = g >> 15;
        float v = dec1_w[ci * 1152 + co * 9 + tap];
        ushort hi = f2bf(v);
        ushort lo = f2bf(v - bf2f(hi));
        ushort* u16 = (ushort*)(ws + WS_WT1);
        u16[g] = hi;
        u16[294912 + g] = lo;
    } else if (g < 2 * 294912) {            // wt2[(ci*9+tap)*256 + co] <- enc2_w[co][ci][tap]
        int h = g - 294912;
        int co = h & 255, q = h >> 8;
        int ci = q / 9, tap = q - ci * 9;
        ws[WS_WT2 + h] = enc2_w[co * 1152 + ci * 9 + tap];
    } else if (g < 2 * 294912 + 16384) {    // wt3[ci*64+co] <- pre_w[co][ci]
        int h = g - 2 * 294912;
        int co = h & 63, ci = h >> 6;
        ws[WS_WT3 + h] = pre_w[co * 256 + ci];
    }
}

// ---------------- fused post table F = codebook @ post_w^T + post_b; code norms ----------------
__global__ __launch_bounds__(256) void k_F(const float* __restrict__ codebook,
                                           const float* __restrict__ post_w,
                                           const float* __restrict__ post_b,
                                           float* __restrict__ ws) {
    __shared__ __align__(16) float cbr[64];
    int k = blockIdx.x, co = threadIdx.x;
    if (co < 64) cbr[co] = codebook[k * 64 + co];
    __syncthreads();
    float acc = post_b[co];
#pragma unroll
    for (int i = 0; i < 64; i += 4) {
        float4 w4 = *(const float4*)&post_w[co * 64 + i];
        acc = fmaf(cbr[i], w4.x, acc);
        acc = fmaf(cbr[i + 1], w4.y, acc);
        acc = fmaf(cbr[i + 2], w4.z, acc);
        acc = fmaf(cbr[i + 3], w4.w, acc);
    }
    ws[WS_F + k * 256 + co] = acc;
    if (co == 0) {
        float s = 0.f;
        for (int i = 0; i < 64; i++) s += cbr[i] * cbr[i];
        ws[WS_CC + k] = s;
    }
}

// ---------------- enc1: 3x3 s2 p1, 3->128, 128^2 -> 64^2, + BN partial sums ----------------
__global__ __launch_bounds__(256) void k_enc1(const float* __restrict__ x,
                                              const float* __restrict__ w,
                                              const float* __restrict__ bias,
                                              float* __restrict__ ws) {
    __shared__ __align__(16) float in_s[3 * 9 * 130];
    __shared__ __align__(16) float w_s[27 * 32];
    int n = blockIdx.y;
    int cog = blockIdx.x & 3, yt = blockIdx.x >> 2;
    int y0 = yt * 4, cobase = cog * 32;
    int tid = threadIdx.x;
    int xo = tid & 63, cg = tid >> 6;
    int co8 = cobase + cg * 8;

    for (int t = tid; t < 3 * 9 * 130; t += 256) {
        int c = t % 130, rest = t / 130;
        int row = rest % 9, ci = rest / 9;
        int iy = 2 * y0 - 1 + row, ix = c - 1;
        float v = 0.f;
        if ((unsigned)iy < 128u && (unsigned)ix < 128u)
            v = x[(n * 3 + ci) * 16384 + iy * 128 + ix];
        in_s[t] = v;
    }
    for (int t = tid; t < 864; t += 256) {
        int co = t & 31, q = t >> 5;
        w_s[q * 32 + co] = w[(cobase + co) * 27 + q];
    }
    __syncthreads();

    float acc[4][8];
#pragma unroll
    for (int r = 0; r < 4; r++)
#pragma unroll
        for (int j = 0; j < 8; j++) acc[r][j] = bias[co8 + j];

#pragma unroll
    for (int ci = 0; ci < 3; ci++)
#pragma unroll
        for (int ky = 0; ky < 3; ky++) {
            float v[4][3];
#pragma unroll
            for (int r = 0; r < 4; r++) {
                const float* bp = &in_s[ci * 1170 + (2 * r + ky) * 130 + 2 * xo];
                v[r][0] = bp[0]; v[r][1] = bp[1]; v[r][2] = bp[2];
            }
#pragma unroll
            for (int kx = 0; kx < 3; kx++) {
                const float* wp = &w_s[(ci * 9 + ky * 3 + kx) * 32 + cg * 8];
#pragma unroll
                for (int j = 0; j < 8; j++) {
                    float wv = wp[j];
#pragma unroll
                    for (int r = 0; r < 4; r++) acc[r][j] = fmaf(v[r][kx], wv, acc[r][j]);
                }
            }
        }

    float* h1 = ws + WS_A;
#pragma unroll
    for (int j = 0; j < 8; j++) {
        int co = co8 + j;
#pragma unroll
        for (int r = 0; r < 4; r++)
            h1[((n * 128 + co) * 64 + y0 + r) * 64 + xo] = acc[r][j];
        float s1 = acc[0][j] + acc[1][j] + acc[2][j] + acc[3][j];
        float s2 = acc[0][j] * acc[0][j] + acc[1][j] * acc[1][j]
                 + acc[2][j] * acc[2][j] + acc[3][j] * acc[3][j];
#pragma unroll
        for (int off = 32; off; off >>= 1) {
            s1 += __shfl_down(s1, off);
            s2 += __shfl_down(s2, off);
        }
        if ((tid & 63) == 0) {
            atomicAdd(&ws[WS_BN1SUM + co], s1);
            atomicAdd(&ws[WS_BN1SUM + 128 + co], s2);
        }
    }
}

// ---------------- BN finalize (single accumulator copy) ----------------
__global__ __launch_bounds__(128) void k_bnfin(const float* __restrict__ sums,
                                               const float* __restrict__ g,
                                               const float* __restrict__ b,
                                               float* __restrict__ scale,
                                               float* __restrict__ shift, float invN) {
    int c = threadIdx.x;
    float mean = sums[c] * invN;
    float var = sums[128 + c] * invN - mean * mean;
    float sc = g[c] * rsqrtf(var + EPS);
    scale[c] = sc;
    shift[c] = b[c] - mean * sc;
}

// BN finalize summing the 8 shadow copies written by k_dec1
__global__ __launch_bounds__(128) void k_bnfin2(const float* __restrict__ g,
                                                const float* __restrict__ b,
                                                float* __restrict__ ws) {
    int c = threadIdx.x;
    float s1 = 0.f, s2 = 0.f;
    for (int k = 0; k < 8; k++) {
        s1 += ws[WS_BN2S8 + k * 256 + c];
        s2 += ws[WS_BN2S8 + k * 256 + 128 + c];
    }
    float mean = s1 * (1.f / 262144.f);
    float var = s2 * (1.f / 262144.f) - mean * mean;
    float sc = g[c] * rsqrtf(var + EPS);
    ws[WS_BN2SC + c] = sc;
    ws[WS_BN2SH + c] = b[c] - mean * sc;
}

// ---------------- enc2: 3x3 s2 p1, 128->256, 64^2 -> 32^2 (BN1+ReLU applied on load) ----------------
__global__ __launch_bounds__(256) void k_enc2(const float* __restrict__ bias,
                                              float* __restrict__ ws) {
    __shared__ __align__(16) float in_s[8 * 9 * 66];
    __shared__ __align__(16) float w_s[72 * 64];
    int n = blockIdx.y;
    int cog = blockIdx.x & 3, yt = blockIdx.x >> 2;
    int y0 = yt * 4, cobase = cog * 64;
    int tid = threadIdx.x;
    int xo = tid & 31, cg = tid >> 5;
    int co8g = cobase + cg * 8;
    const float* h1 = ws + WS_A;
    const float* sc = ws + WS_BN1SC;
    const float* sh = ws + WS_BN1SH;
    const float* wt2 = ws + WS_WT2;

    float acc[4][8];
#pragma unroll
    for (int r = 0; r < 4; r++)
#pragma unroll
        for (int j = 0; j < 8; j++) acc[r][j] = bias[co8g + j];

    for (int c0 = 0; c0 < 128; c0 += 8) {
        __syncthreads();
        for (int t = tid; t < 8 * 9 * 66; t += 256) {
            int c = t % 66, rest = t / 66;
            int row = rest % 9, ci = rest / 9;
            int ciG = c0 + ci;
            int iy = 2 * y0 - 1 + row, ix = c - 1;
            float v = 0.f;
            if ((unsigned)iy < 64u && (unsigned)ix < 64u) {
                float raw = h1[((n * 128 + ciG) * 64 + iy) * 64 + ix];
                v = fmaxf(fmaf(raw, sc[ciG], sh[ciG]), 0.f);
            }
            in_s[t] = v;
        }
        for (int t = tid; t < 72 * 64; t += 256) {
            int co = t & 63, q = t >> 6;
            w_s[t] = wt2[(c0 * 9 + q) * 256 + cobase + co];
        }
        __syncthreads();
#pragma unroll
        for (int ci = 0; ci < 8; ci++) {
#pragma unroll
            for (int ky = 0; ky < 3; ky++) {
                float v[4][3];
#pragma unroll
                for (int r = 0; r < 4; r++) {
                    const float* bp = &in_s[ci * 594 + (2 * r + ky) * 66 + 2 * xo];
                    v[r][0] = bp[0]; v[r][1] = bp[1]; v[r][2] = bp[2];
                }
#pragma unroll
                for (int kx = 0; kx < 3; kx++) {
                    const float* wp = &w_s[(ci * 9 + ky * 3 + kx) * 64 + cg * 8];
#pragma unroll
                    for (int j = 0; j < 8; j++) {
                        float wv = wp[j];
#pragma unroll
                        for (int r = 0; r < 4; r++) acc[r][j] = fmaf(v[r][kx], wv, acc[r][j]);
                    }
                }
            }
        }
    }
    float* h2 = ws + WS_B;
#pragma unroll
    for (int j = 0; j < 8; j++) {
        int co = co8g + j;
#pragma unroll
        for (int r = 0; r < 4; r++)
            h2[((n * 256 + co) * 32 + y0 + r) * 32 + xo] = acc[r][j];
    }
}

// ---------------- pre: 1x1, 256->64, out NHWC z_pix[p][c] ----------------
__global__ __launch_bounds__(256) void k_pre(const float* __restrict__ bias,
                                             float* __restrict__ ws) {
    __shared__ __align__(16) float a_s[8 * 128];
    __shared__ __align__(16) float b_s[8 * 64];
    int p0 = blockIdx.x * 128;
    int n = p0 >> 10, sp0 = p0 & 1023;
    int tid = threadIdx.x;
    int px4 = tid & 31, cg = tid >> 5;
    int co8 = cg * 8;
    const float* h2 = ws + WS_B;
    const float* wt3 = ws + WS_WT3;

    float acc[4][8];
#pragma unroll
    for (int r = 0; r < 4; r++)
#pragma unroll
        for (int j = 0; j < 8; j++) acc[r][j] = bias[co8 + j];

    for (int c0 = 0; c0 < 256; c0 += 8) {
        __syncthreads();
#pragma unroll
        for (int it = 0; it < 4; it++) {
            int t = tid + it * 256;
            a_s[t] = h2[n * 262144 + (c0 + (t >> 7)) * 1024 + sp0 + (t & 127)];
        }
#pragma unroll
        for (int it = 0; it < 2; it++) {
            int t = tid + it * 256;
            b_s[t] = wt3[(c0 + (t >> 6)) * 64 + (t & 63)];
        }
        __syncthreads();
#pragma unroll
        for (int ci = 0; ci < 8; ci++) {
            float4 av = *(const float4*)&a_s[ci * 128 + px4 * 4];
            float4 w0 = *(const float4*)&b_s[ci * 64 + co8];
            float4 w1 = *(const float4*)&b_s[ci * 64 + co8 + 4];
            float wv[8] = {w0.x, w0.y, w0.z, w0.w, w1.x, w1.y, w1.z, w1.w};
            float a[4] = {av.x, av.y, av.z, av.w};
#pragma unroll
            for (int j = 0; j < 8; j++)
#pragma unroll
                for (int r = 0; r < 4; r++) acc[r][j] = fmaf(a[r], wv[j], acc[r][j]);
        }
    }
    float* z = ws + WS_Z;
#pragma unroll
    for (int r = 0; r < 4; r++) {
        int p = p0 + px4 * 4 + r;
        *(float4*)&z[p * 64 + co8] = make_float4(acc[r][0], acc[r][1], acc[r][2], acc[r][3]);
        *(float4*)&z[p * 64 + co8 + 4] = make_float4(acc[r][4], acc[r][5], acc[r][6], acc[r][7]);
    }
}

// ---------------- VQ: argmin over 512 codes, idx out, loss partial ----------------
__global__ __launch_bounds__(256, 2) void k_vq(const float* __restrict__ codebook,
                                               float* __restrict__ out,
                                               float* __restrict__ ws) {
    __shared__ __align__(16) float cb_s[128 * 64];
    __shared__ __align__(16) float cc_s[128];
    int tid = threadIdx.x;
    int p = blockIdx.x * 256 + tid;
    const float* z = ws + WS_Z + p * 64;
    float4 z4[16];
#pragma unroll
    for (int i = 0; i < 16; i++) z4[i] = *(const float4*)&z[i * 4];
    float zz = 0.f;
#pragma unroll
    for (int i = 0; i < 16; i++)
        zz += z4[i].x * z4[i].x + z4[i].y * z4[i].y + z4[i].z * z4[i].z + z4[i].w * z4[i].w;

    float best = 3.4e38f;
    int bidx = 0;
    for (int k0 = 0; k0 < 512; k0 += 128) {
        __syncthreads();
#pragma unroll
        for (int it = 0; it < 32; it++) {
            int t = tid + it * 256;
            cb_s[t] = codebook[k0 * 64 + t];
        }
        if (tid < 128) cc_s[tid] = ws[WS_CC + k0 + tid];
        __syncthreads();
        for (int k = 0; k < 128; k++) {
            const float4* cp = (const float4*)&cb_s[k * 64];
            float d0 = 0.f, d1 = 0.f, d2 = 0.f, d3 = 0.f;
#pragma unroll
            for (int i = 0; i < 16; i += 4) {
                float4 c0v = cp[i], c1v = cp[i + 1], c2v = cp[i + 2], c3v = cp[i + 3];
                d0 += z4[i].x * c0v.x + z4[i].y * c0v.y + z4[i].z * c0v.z + z4[i].w * c0v.w;
                d1 += z4[i + 1].x * c1v.x + z4[i + 1].y * c1v.y + z4[i + 1].z * c1v.z + z4[i + 1].w * c1v.w;
                d2 += z4[i + 2].x * c2v.x + z4[i + 2].y * c2v.y + z4[i + 2].z * c2v.z + z4[i + 2].w * c2v.w;
                d3 += z4[i + 3].x * c3v.x + z4[i + 3].y * c3v.y + z4[i + 3].z * c3v.z + z4[i + 3].w * c3v.w;
            }
            float dot = (d0 + d1) + (d2 + d3);
            float d = fmaf(-2.f, dot, zz) + cc_s[k];
            if (d < best) { best = d; bidx = k0 + k; }
        }
    }
    out[OUT_IDX + p] = (float)bidx;
    ((int*)(ws + WS_IDX))[p] = bidx;

    float e = 0.f;
    const float4* q = (const float4*)&codebook[bidx * 64];
#pragma unroll
    for (int i = 0; i < 16; i++) {
        float4 qq = q[i];
        float d0 = z4[i].x - qq.x, d1 = z4[i].y - qq.y;
        float d2 = z4[i].z - qq.z, d3 = z4[i].w - qq.w;
        e += d0 * d0 + d1 * d1 + d2 * d2 + d3 * d3;
    }
#pragma unroll
    for (int off = 32; off; off >>= 1) e += __shfl_down(e, off);
    if ((tid & 63) == 0) atomicAdd(&ws[WS_LOSS], e);
}

__global__ void k_loss(float* __restrict__ out, const float* __restrict__ ws) {
    if (threadIdx.x == 0) {
        float v = ws[WS_LOSS] * (1.f / (65536.f * 64.f));
        out[OUT_LOSS_E] = v;
        out[OUT_LOSS_C] = v;
    }
}

// ---------------- gather fused-post rows: d_pix[p][:] = F[idx[p]][:] ----------------
__global__ __launch_bounds__(256) void k_gather(float* __restrict__ ws) {
    int tid = threadIdx.x;
    const int* idx = (const int*)(ws + WS_IDX);
    const float* F = ws + WS_F;
    float* dpx = ws + WS_B;
    int base = blockIdx.x * 64;
    for (int i = 0; i < 64; i++) {
        int row = idx[base + i];
        dpx[(base + i) * 256 + tid] = F[row * 256 + tid];
    }
}

// ---------------- dec1: conv_transpose 3x3 s2 p1 op1, 256->128 via split-bf16 MFMA ----------------
// Per phase (output parity py,px): implicit GEMM, M=65536 px, N=128 co, K=256*ntap.
// fp32 = bf16_hi + bf16_lo; D = Ah*Bh + Ah*Bl + Al*Bh (al*bl ~2^-18, dropped).
// Block: 256 thr (4 waves as 2x2), tile M=128 x N=128, 16x16x32 MFMA.
// A staged once per 32-ci chunk covering the 5x33 input-px union of all taps.
// Output stored NHWC so D-fragment stores (16 consecutive couts/quad) coalesce.
__global__ __launch_bounds__(256, 2) void k_dec1(const float* __restrict__ bias,
                                                 float* __restrict__ ws) {
    __shared__ __align__(16) short As_h[5280], As_l[5280];   // [5 row][33 col][32 ci]
    __shared__ __align__(16) short Bs_h[4096], Bs_l[4096];   // [128 co][32 ci]
    int bx = blockIdx.x;
    int tile = bx & 511, phase = bx >> 9;
    int py = phase >> 1, px = phase & 1;
    int n_img = tile >> 3, a0 = (tile & 7) * 4;
    int tid = threadIdx.x, lane = tid & 63, wid = tid >> 6;
    int wy = wid >> 1, wx = wid & 1;
    int l15 = lane & 15, quad = lane >> 4;

    int ntY = py + 1, ntX = px + 1, ntap = ntY * ntX;
    int tap_off[4], tap_w[4];
    {
        int ti = 0;
        for (int ty = 0; ty < ntY; ty++)
            for (int tx = 0; tx < ntX; tx++) {
                int dy = py ? 1 - ty : 0, ky = py ? 2 * ty : 1;
                int dx = px ? 1 - tx : 0, kx = px ? 2 * tx : 1;
                tap_off[ti] = (dy * 33 + dx) * 32;
                tap_w[ti] = ky * 3 + kx;
                ti++;
            }
    }

    int Aoff[4];
#pragma unroll
    for (int mt = 0; mt < 4; mt++) {
        int m_loc = wy * 64 + mt * 16 + l15;
        Aoff[mt] = ((m_loc >> 5) * 33 + (m_loc & 31)) * 32 + quad * 8;
    }
    int Boff[4];
#pragma unroll
    for (int nt = 0; nt < 4; nt++)
        Boff[nt] = (wx * 64 + nt * 16 + l15) * 32 + quad * 8;

    f32x4 acc[4][4];
#pragma unroll
    for (int nt = 0; nt < 4; nt++) {
        float bv = bias[wx * 64 + nt * 16 + l15];
#pragma unroll
        for (int mt = 0; mt < 4; mt++) acc[mt][nt] = (f32x4){bv, bv, bv, bv};
    }

    const float* dpx = ws + WS_B;
    const ushort* wbh = (const ushort*)(ws + WS_WT1);
    const ushort* wbl = wbh + 294912;

    for (int c0 = 0; c0 < 256; c0 += 32) {
        __syncthreads();
        // stage A union (165 px x 32 ci), fp32 -> split bf16
        for (int i = tid; i < 1320; i += 256) {
            int p5 = i >> 3, q = i & 7;
            int rr = p5 / 33, cc = p5 - rr * 33;
            int a_in = a0 + rr;
            float4 v = make_float4(0.f, 0.f, 0.f, 0.f);
            if (a_in < 32 && cc < 32)
                v = *(const float4*)&dpx[(n_img * 1024 + a_in * 32 + cc) * 256 + c0 + q * 4];
            ushort h0 = f2bf(v.x), h1 = f2bf(v.y), h2 = f2bf(v.z), h3v = f2bf(v.w);
            ushort l0 = f2bf(v.x - bf2f(h0)), l1 = f2bf(v.y - bf2f(h1));
            ushort l2 = f2bf(v.z - bf2f(h2)), l3 = f2bf(v.w - bf2f(h3v));
            int d = p5 * 32 + q * 4;
            *(uint*)&As_h[d]     = (uint)h0 | ((uint)h1 << 16);
            *(uint*)&As_h[d + 2] = (uint)h2 | ((uint)h3v << 16);
            *(uint*)&As_l[d]     = (uint)l0 | ((uint)l1 << 16);
            *(uint*)&As_l[d + 2] = (uint)l2 | ((uint)l3 << 16);
        }
        for (int t = 0; t < ntap; t++) {
            if (t) __syncthreads();
            int tw = tap_w[t];
            for (int i = tid; i < 512; i += 256) {
                int co = i >> 2, q = i & 3;
                int src = (tw * 128 + co) * 256 + c0 + q * 8;
                *(uint4*)&Bs_h[co * 32 + q * 8] = *(const uint4*)&wbh[src];
                *(uint4*)&Bs_l[co * 32 + q * 8] = *(const uint4*)&wbl[src];
            }
            __syncthreads();
            int ao = tap_off[t];
            short8 Ah[4], Al[4];
#pragma unroll
            for (int mt = 0; mt < 4; mt++) {
                Ah[mt] = *(const short8*)&As_h[Aoff[mt] + ao];
                Al[mt] = *(const short8*)&As_l[Aoff[mt] + ao];
            }
#pragma unroll
            for (int nt = 0; nt < 4; nt++) {
                short8 Bh = *(const short8*)&Bs_h[Boff[nt]];
                short8 Bl = *(const short8*)&Bs_l[Boff[nt]];
#pragma unroll
                for (int mt = 0; mt < 4; mt++) {
                    acc[mt][nt] = __builtin_amdgcn_mfma_f32_16x16x32_bf16(Ah[mt], Bh, acc[mt][nt], 0, 0, 0);
                    acc[mt][nt] = __builtin_amdgcn_mfma_f32_16x16x32_bf16(Ah[mt], Bl, acc[mt][nt], 0, 0, 0);
                    acc[mt][nt] = __builtin_amdgcn_mfma_f32_16x16x32_bf16(Al[mt], Bh, acc[mt][nt], 0, 0, 0);
                }
            }
        }
    }

    // epilogue: NHWC store + BN partial sums into 8 shadow copies
    float* h3n = ws + WS_A;
#pragma unroll
    for (int mt = 0; mt < 4; mt++) {
#pragma unroll
        for (int r = 0; r < 4; r++) {
            int m_glob = tile * 128 + wy * 64 + mt * 16 + quad * 4 + r;
            int a = (m_glob >> 5) & 31, bb = m_glob & 31;
            int y = 2 * a + py, x = 2 * bb + px;
            float* rowp = &h3n[(((m_glob >> 10) * 64 + y) * 64 + x) * 128 + wx * 64];
#pragma unroll
            for (int nt = 0; nt < 4; nt++) rowp[nt * 16 + l15] = acc[mt][nt][r];
        }
    }
    int shadow = (bx & 7) * 256;
#pragma unroll
    for (int nt = 0; nt < 4; nt++) {
        float s1 = 0.f, s2 = 0.f;
#pragma unroll
        for (int mt = 0; mt < 4; mt++)
#pragma unroll
            for (int r = 0; r < 4; r++) {
                float v = acc[mt][nt][r];
                s1 += v; s2 += v * v;
            }
        s1 += __shfl_xor(s1, 16); s1 += __shfl_xor(s1, 32);
        s2 += __shfl_xor(s2, 16); s2 += __shfl_xor(s2, 32);
        if (quad == 0) {
            int co = wx * 64 + nt * 16 + l15;
            atomicAdd(&ws[WS_BN2S8 + shadow + co], s1);
            atomicAdd(&ws[WS_BN2S8 + shadow + 128 + co], s2);
        }
    }
}

// ---------------- dec2: conv_transpose 3x3 s2 p1 op1, 128->3, BN2+ReLU on load, tanh ----------------
// h3 is now NHWC: [n][y 64][x 64][co 128]
__global__ __launch_bounds__(1024, 2) void k_dec2(const float* __restrict__ w,
                                                  const float* __restrict__ bias,
                                                  float* __restrict__ out,
                                                  float* __restrict__ ws) {
    __shared__ __align__(16) float in_s[8 * 5 * 66];
    __shared__ __align__(16) float w_s[8 * 9 * 3];
    __shared__ float scs[128], shs[128];
    int n = blockIdx.y;
    int atile = blockIdx.x;
    int a0 = atile * 4;
    int tid = threadIdx.x;
    int phase = tid >> 8;
    int py = phase >> 1, px = phase & 1;
    int tidl = tid & 255;
    int b = tidl & 63, r4 = tidl >> 6;
    int ntsh = py + px;
    int ntap = 1 << ntsh;
    const float* h3n = ws + WS_A;

    if (tid < 128) { scs[tid] = ws[WS_BN2SC + tid]; shs[tid] = ws[WS_BN2SH + tid]; }

    float acc[3] = {bias[0], bias[1], bias[2]};
    for (int c0 = 0; c0 < 128; c0 += 8) {
        __syncthreads();
        if (tid < 660) {
            int ciq = tid & 1, s = tid >> 1;
            int cL = s % 66, row = s / 66;
            int iy = a0 + row;
            float4 v = make_float4(0.f, 0.f, 0.f, 0.f);
            if (iy < 64 && cL < 64)
                v = *(const float4*)&h3n[((n * 64 + iy) * 64 + cL) * 128 + c0 + ciq * 4];
            int cb = c0 + ciq * 4;
            float r0 = fmaxf(fmaf(v.x, scs[cb], shs[cb]), 0.f);
            float r1 = fmaxf(fmaf(v.y, scs[cb + 1], shs[cb + 1]), 0.f);
            float r2 = fmaxf(fmaf(v.z, scs[cb + 2], shs[cb + 2]), 0.f);
            float r3 = fmaxf(fmaf(v.w, scs[cb + 3], shs[cb + 3]), 0.f);
            int ci0 = ciq * 4;
            in_s[(ci0 + 0) * 330 + row * 66 + cL] = r0;
            in_s[(ci0 + 1) * 330 + row * 66 + cL] = r1;
            in_s[(ci0 + 2) * 330 + row * 66 + cL] = r2;
            in_s[(ci0 + 3) * 330 + row * 66 + cL] = r3;
        }
        if (tid < 8 * 9 * 3) {
            int co = tid % 3, q = tid / 3;   // q = ci*9 + tap
            int ci = q / 9, tap = q - ci * 9;
            w_s[q * 3 + co] = w[(c0 + ci) * 27 + co * 9 + tap];
        }
        __syncthreads();
#pragma unroll
        for (int ci = 0; ci < 8; ci++) {
#pragma unroll
            for (int tt = 0; tt < 4; tt++) {
                if (tt >= ntap) break;
                int ty = tt >> px, tx = tt & px;
                int ky = py ? 2 * ty : 1;
                int kx = px ? 2 * tx : 1;
                int dyv = py ? 1 - ty : 0;
                int dxv = px ? 1 - tx : 0;
                float v = in_s[ci * 330 + (r4 + dyv) * 66 + b + dxv];
                const float* wp = &w_s[(ci * 9 + ky * 3 + kx) * 3];
                acc[0] = fmaf(v, wp[0], acc[0]);
                acc[1] = fmaf(v, wp[1], acc[1]);
                acc[2] = fmaf(v, wp[2], acc[2]);
            }
        }
    }
    int y = 2 * (a0 + r4) + py, xcol = 2 * b + px;
#pragma unroll
    for (int co = 0; co < 3; co++)
        out[(n * 3 + co) * 16384 + y * 128 + xcol] = tanhf(acc[co]);
}

// ---------------- launch ----------------
extern "C" void kernel_launch(void* const* d_in, const int* in_sizes, int n_in,
                              void* d_out, int out_size, void* d_ws, size_t ws_size,
                              hipStream_t stream) {
    const float* x       = (const float*)d_in[0];
    const float* enc1_w  = (const float*)d_in[1];
    const float* enc1_b  = (const float*)d_in[2];
    const float* bn1_g   = (const float*)d_in[3];
    const float* bn1_b   = (const float*)d_in[4];
    const float* enc2_w  = (const float*)d_in[5];
    const float* enc2_b  = (const float*)d_in[6];
    const float* pre_w   = (const float*)d_in[7];
    const float* pre_b   = (const float*)d_in[8];
    const float* codebook= (const float*)d_in[9];
    const float* post_w  = (const float*)d_in[10];
    const float* post_b  = (const float*)d_in[11];
    const float* dec1_w  = (const float*)d_in[12];
    const float* dec1_b  = (const float*)d_in[13];
    const float* dbn1_g  = (const float*)d_in[14];
    const float* dbn1_b  = (const float*)d_in[15];
    const float* dec2_w  = (const float*)d_in[16];
    const float* dec2_b  = (const float*)d_in[17];
    float* out = (float*)d_out;
    float* ws  = (float*)d_ws;

    hipMemsetAsync(ws, 0, 4096, stream);                      // BN1 sums + loss
    hipMemsetAsync(ws + WS_BN2S8, 0, 8 * 256 * 4, stream);    // BN2 shadow sums

    k_wt<<<2368, 256, 0, stream>>>(dec1_w, enc2_w, pre_w, ws);
    k_F<<<512, 256, 0, stream>>>(codebook, post_w, post_b, ws);
    k_enc1<<<dim3(64, 64), 256, 0, stream>>>(x, enc1_w, enc1_b, ws);
    k_bnfin<<<1, 128, 0, stream>>>(ws + WS_BN1SUM, bn1_g, bn1_b,
                                   ws + WS_BN1SC, ws + WS_BN1SH, 1.f / 262144.f);
    k_enc2<<<dim3(32, 64), 256, 0, stream>>>(enc2_b, ws);
    k_pre<<<512, 256, 0, stream>>>(pre_b, ws);
    k_vq<<<256, 256, 0, stream>>>(codebook, out, ws);
    k_loss<<<1, 64, 0, stream>>>(out, ws);
    k_gather<<<1024, 256, 0, stream>>>(ws);
    k_dec1<<<2048, 256, 0, stream>>>(dec1_b, ws);
    k_bnfin2<<<1, 128, 0, stream>>>(dbn1_g, dbn1_b, ws);
    k_dec2<<<dim3(16, 64), 1024, 0, stream>>>(dec2_w, dec2_b, out, ws);
}

// Round 5
// 1260.826 us; speedup vs baseline: 2.0084x; 1.3512x over previous
//
#include <hip/hip_runtime.h>

#define EPS 1e-5f

typedef __attribute__((ext_vector_type(8))) short short8;
typedef __attribute__((ext_vector_type(4))) float f32x4;
typedef _Float16 half8v __attribute__((ext_vector_type(8)));

__device__ inline ushort f2bf(float f) {
    uint u = __float_as_uint(f);
    u += 0x7FFFu + ((u >> 16) & 1u);
    return (ushort)(u >> 16);
}
__device__ inline float bf2f(ushort h) { return __uint_as_float(((uint)h) << 16); }
__device__ inline ushort hbits(_Float16 h) { return __builtin_bit_cast(ushort, h); }

// ---------------- ws layout (float offsets) ----------------
#define WS_BN1SUM   0         // 256 (s1[128], s2[128])
#define WS_LOSS     512       // 1
#define WS_BN1SC    1024      // 128
#define WS_BN1SH    1152      // 128
#define WS_BN2SC    1280      // 128
#define WS_BN2SH    1408      // 128
#define WS_CC       1536      // 512 code norms
#define WS_IDX      2048      // 65536 ints
#define WS_WT3      67584     // 16384  pre_w^T  [ci][co]
#define WS_WT1      83968     // 294912 floats = 589824 ushorts: dec1_w split-bf16 [tap][co][ci] hi|lo
#define WS_WT2      378880    // 294912 floats = 589824 ushorts: enc2_w split-fp16 [(tap*256+co)*128+ci] hi|lo(x2048)
#define WS_F        673792    // 131072 fused post table [k][co]
#define WS_BN2S8    804864    // 8 shadow copies x 256 (s1[128], s2[128])
#define WS_A        1048576   // 33554432: h1raw -> z_pix (aliased) -> h3 (NHWC)
#define WS_B        34603008  // 16777216: h2 -> d_pix [p][256] fp32
#define WS_Z        WS_A

#define OUT_LOSS_E  3145728
#define OUT_LOSS_C  3145729
#define OUT_IDX     3145730

// ---------------- weight pre-transpose / split ----------------
__global__ __launch_bounds__(256) void k_wt(const float* __restrict__ dec1_w,
                                            const float* __restrict__ enc2_w,
                                            const float* __restrict__ pre_w,
                                            float* __restrict__ ws) {
    int g = blockIdx.x * 256 + threadIdx.x;
    if (g < 294912) {
        // dec1: wB[(tap*128+co)*256+ci] split hi/lo bf16 <- dec1_w[ci][co][tap]
        int ci = g & 255, co = (g >> 8) & 127, tap = g >> 15;
        float v = dec1_w[ci * 1152 + co * 9 + tap];
        ushort hi = f2bf(v);
        ushort lo = f2bf(v - bf2f(hi));
        ushort* u16 = (ushort*)(ws + WS_WT1);
        u16[g] = hi;
        u16[294912 + g] = lo;
    } else if (g < 2 * 294912) {
        // enc2: wt2s[(tap*256+co)*128+ci] split hi/lo fp16, lo scaled x2048 to stay
        // in fp16 normal range (denormal-flush safety) <- enc2_w[co][ci][tap]
        int h = g - 294912;
        int ci = h & 127, rest = h >> 7;
        int co = rest & 255, tap = rest >> 8;
        float v = enc2_w[co * 1152 + ci * 9 + tap];
        _Float16 hi = (_Float16)v;
        _Float16 lo = (_Float16)((v - (float)hi) * 2048.0f);
        ushort* u16 = (ushort*)(ws + WS_WT2);
        u16[h] = hbits(hi);
        u16[294912 + h] = hbits(lo);
    } else if (g < 2 * 294912 + 16384) {    // wt3[ci*64+co] <- pre_w[co][ci]
        int h = g - 2 * 294912;
        int co = h & 63, ci = h >> 6;
        ws[WS_WT3 + h] = pre_w[co * 256 + ci];
    }
}

// ---------------- fused post table F = codebook @ post_w^T + post_b; code norms ----------------
__global__ __launch_bounds__(256) void k_F(const float* __restrict__ codebook,
                                           const float* __restrict__ post_w,
                                           const float* __restrict__ post_b,
                                           float* __restrict__ ws) {
    __shared__ __align__(16) float cbr[64];
    int k = blockIdx.x, co = threadIdx.x;
    if (co < 64) cbr[co] = codebook[k * 64 + co];
    __syncthreads();
    float acc = post_b[co];
#pragma unroll
    for (int i = 0; i < 64; i += 4) {
        float4 w4 = *(const float4*)&post_w[co * 64 + i];
        acc = fmaf(cbr[i], w4.x, acc);
        acc = fmaf(cbr[i + 1], w4.y, acc);
        acc = fmaf(cbr[i + 2], w4.z, acc);
        acc = fmaf(cbr[i + 3], w4.w, acc);
    }
    ws[WS_F + k * 256 + co] = acc;
    if (co == 0) {
        float s = 0.f;
        for (int i = 0; i < 64; i++) s += cbr[i] * cbr[i];
        ws[WS_CC + k] = s;
    }
}

// ---------------- enc1: 3x3 s2 p1, 3->128, 128^2 -> 64^2, + BN partial sums ----------------
__global__ __launch_bounds__(256) void k_enc1(const float* __restrict__ x,
                                              const float* __restrict__ w,
                                              const float* __restrict__ bias,
                                              float* __restrict__ ws) {
    __shared__ __align__(16) float in_s[3 * 9 * 130];
    __shared__ __align__(16) float w_s[27 * 32];
    int n = blockIdx.y;
    int cog = blockIdx.x & 3, yt = blockIdx.x >> 2;
    int y0 = yt * 4, cobase = cog * 32;
    int tid = threadIdx.x;
    int xo = tid & 63, cg = tid >> 6;
    int co8 = cobase + cg * 8;

    for (int t = tid; t < 3 * 9 * 130; t += 256) {
        int c = t % 130, rest = t / 130;
        int row = rest % 9, ci = rest / 9;
        int iy = 2 * y0 - 1 + row, ix = c - 1;
        float v = 0.f;
        if ((unsigned)iy < 128u && (unsigned)ix < 128u)
            v = x[(n * 3 + ci) * 16384 + iy * 128 + ix];
        in_s[t] = v;
    }
    for (int t = tid; t < 864; t += 256) {
        int co = t & 31, q = t >> 5;
        w_s[q * 32 + co] = w[(cobase + co) * 27 + q];
    }
    __syncthreads();

    float acc[4][8];
#pragma unroll
    for (int r = 0; r < 4; r++)
#pragma unroll
        for (int j = 0; j < 8; j++) acc[r][j] = bias[co8 + j];

#pragma unroll
    for (int ci = 0; ci < 3; ci++)
#pragma unroll
        for (int ky = 0; ky < 3; ky++) {
            float v[4][3];
#pragma unroll
            for (int r = 0; r < 4; r++) {
                const float* bp = &in_s[ci * 1170 + (2 * r + ky) * 130 + 2 * xo];
                v[r][0] = bp[0]; v[r][1] = bp[1]; v[r][2] = bp[2];
            }
#pragma unroll
            for (int kx = 0; kx < 3; kx++) {
                const float* wp = &w_s[(ci * 9 + ky * 3 + kx) * 32 + cg * 8];
#pragma unroll
                for (int j = 0; j < 8; j++) {
                    float wv = wp[j];
#pragma unroll
                    for (int r = 0; r < 4; r++) acc[r][j] = fmaf(v[r][kx], wv, acc[r][j]);
                }
            }
        }

    float* h1 = ws + WS_A;
#pragma unroll
    for (int j = 0; j < 8; j++) {
        int co = co8 + j;
#pragma unroll
        for (int r = 0; r < 4; r++)
            h1[((n * 128 + co) * 64 + y0 + r) * 64 + xo] = acc[r][j];
        float s1 = acc[0][j] + acc[1][j] + acc[2][j] + acc[3][j];
        float s2 = acc[0][j] * acc[0][j] + acc[1][j] * acc[1][j]
                 + acc[2][j] * acc[2][j] + acc[3][j] * acc[3][j];
#pragma unroll
        for (int off = 32; off; off >>= 1) {
            s1 += __shfl_down(s1, off);
            s2 += __shfl_down(s2, off);
        }
        if ((tid & 63) == 0) {
            atomicAdd(&ws[WS_BN1SUM + co], s1);
            atomicAdd(&ws[WS_BN1SUM + 128 + co], s2);
        }
    }
}

// ---------------- BN finalize (single accumulator copy) ----------------
__global__ __launch_bounds__(128) void k_bnfin(const float* __restrict__ sums,
                                               const float* __restrict__ g,
                                               const float* __restrict__ b,
                                               float* __restrict__ scale,
                                               float* __restrict__ shift, float invN) {
    int c = threadIdx.x;
    float mean = sums[c] * invN;
    float var = sums[128 + c] * invN - mean * mean;
    float sc = g[c] * rsqrtf(var + EPS);
    scale[c] = sc;
    shift[c] = b[c] - mean * sc;
}

// BN finalize summing the 8 shadow copies written by k_dec1
__global__ __launch_bounds__(128) void k_bnfin2(const float* __restrict__ g,
                                                const float* __restrict__ b,
                                                float* __restrict__ ws) {
    int c = threadIdx.x;
    float s1 = 0.f, s2 = 0.f;
    for (int k = 0; k < 8; k++) {
        s1 += ws[WS_BN2S8 + k * 256 + c];
        s2 += ws[WS_BN2S8 + k * 256 + 128 + c];
    }
    float mean = s1 * (1.f / 262144.f);
    float var = s2 * (1.f / 262144.f) - mean * mean;
    float sc = g[c] * rsqrtf(var + EPS);
    ws[WS_BN2SC + c] = sc;
    ws[WS_BN2SH + c] = b[c] - mean * sc;
}

// ---------------- enc2: 3x3 s2 p1, 128->256 via split-fp16 MFMA ----------------
// Implicit GEMM: M=64 px (2 out rows x 32 cols), N=256 co, K=128ci x 9 taps.
// fp32 = fp16_hi + fp16_lo; lo terms SCALED x2048 (fp16-normal range, no
// denormal flush) and accumulated separately: out = acc1 + acc2/2048.
// PADDING FIX (round-4 bug): BN+ReLU applied ONLY in-bounds; pad rows = 0.
__global__ __launch_bounds__(256, 2) void k_enc2(const float* __restrict__ bias,
                                                 float* __restrict__ ws) {
    __shared__ __align__(16) uint As_h[6500], As_l[6500];   // [5 row][65 col][32 ci], 52 KB
    __shared__ float scs[128], shs[128];
    int b = blockIdx.x;
    int n = b >> 4, y0 = (b & 15) * 2;
    int tid = threadIdx.x, lane = tid & 63, wid = tid >> 6;
    int l15 = lane & 15, quad = lane >> 4;
    int co0 = wid * 64;
    const float* h1 = ws + WS_A;
    const ushort* w2h = (const ushort*)(ws + WS_WT2);
    const ushort* w2l = w2h + 294912;

    if (tid < 128) { scs[tid] = ws[WS_BN1SC + tid]; shs[tid] = ws[WS_BN1SH + tid]; }

    int Abase[4];
#pragma unroll
    for (int mt = 0; mt < 4; mt++) {
        int m = mt * 16 + l15;
        Abase[mt] = (2 * (m >> 5)) * 2600 + (2 * (m & 31)) * 40 + quad * 8;  // ushort units
    }

    f32x4 acc1[4][4], acc2[4][4];
#pragma unroll
    for (int nt = 0; nt < 4; nt++) {
        float bv = bias[co0 + nt * 16 + l15];
#pragma unroll
        for (int mt = 0; mt < 4; mt++) {
            acc1[mt][nt] = (f32x4){bv, bv, bv, bv};
            acc2[mt][nt] = (f32x4){0.f, 0.f, 0.f, 0.f};
        }
    }

    for (int c0 = 0; c0 < 128; c0 += 32) {
        __syncthreads();
        if (tid < 80) {                       // zero col 0 (in_x = -1 pad)
            int p = tid & 15, row = tid >> 4;
            As_h[row * 1300 + p] = 0;
            As_l[row * 1300 + p] = 0;
        }
        for (int i = tid; i < 1280; i += 256) {
            int p = i & 15, g = i >> 4;       // p = ci-pair, g -> (row, colgroup)
            int row = g >> 4, colg = g & 15;
            int in_y = 2 * y0 - 1 + row;
            int ci0 = c0 + 2 * p;
            float av[4] = {0.f, 0.f, 0.f, 0.f}, bv[4] = {0.f, 0.f, 0.f, 0.f};
            if ((unsigned)in_y < 64u) {       // pad rows stay EXACTLY zero (no BN of 0!)
                const float* bp = h1 + (n * 128 + ci0) * 4096 + in_y * 64 + colg * 4;
                float4 va = *(const float4*)bp;
                float4 vb = *(const float4*)(bp + 4096);
                float sa = scs[ci0], ta = shs[ci0];
                float sb = scs[ci0 + 1], tb = shs[ci0 + 1];
                av[0] = fmaxf(fmaf(va.x, sa, ta), 0.f); av[1] = fmaxf(fmaf(va.y, sa, ta), 0.f);
                av[2] = fmaxf(fmaf(va.z, sa, ta), 0.f); av[3] = fmaxf(fmaf(va.w, sa, ta), 0.f);
                bv[0] = fmaxf(fmaf(vb.x, sb, tb), 0.f); bv[1] = fmaxf(fmaf(vb.y, sb, tb), 0.f);
                bv[2] = fmaxf(fmaf(vb.z, sb, tb), 0.f); bv[3] = fmaxf(fmaf(vb.w, sb, tb), 0.f);
            }
            int wbase = row * 1300 + (colg * 4 + 1) * 20 + p;
#pragma unroll
            for (int j = 0; j < 4; j++) {
                _Float16 ah = (_Float16)av[j], bh = (_Float16)bv[j];
                _Float16 al = (_Float16)((av[j] - (float)ah) * 2048.f);
                _Float16 bl = (_Float16)((bv[j] - (float)bh) * 2048.f);
                As_h[wbase + j * 20] = (uint)hbits(ah) | ((uint)hbits(bh) << 16);
                As_l[wbase + j * 20] = (uint)hbits(al) | ((uint)hbits(bl) << 16);
            }
        }
        __syncthreads();
        const ushort* ah16 = (const ushort*)As_h;
        const ushort* al16 = (const ushort*)As_l;
#pragma unroll
        for (int tap = 0; tap < 9; tap++) {
            int ky = tap / 3, kx = tap - ky * 3;
            int toff = ky * 2600 + kx * 40;
            half8v Bh[4], Bl[4];
#pragma unroll
            for (int nt = 0; nt < 4; nt++) {
                int src = (tap * 256 + co0 + nt * 16 + l15) * 128 + c0 + quad * 8;
                Bh[nt] = *(const half8v*)&w2h[src];
                Bl[nt] = *(const half8v*)&w2l[src];
            }
            half8v Ah[4], Al[4];
#pragma unroll
            for (int mt = 0; mt < 4; mt++) {
                Ah[mt] = *(const half8v*)&ah16[Abase[mt] + toff];
                Al[mt] = *(const half8v*)&al16[Abase[mt] + toff];
            }
#pragma unroll
            for (int nt = 0; nt < 4; nt++)
#pragma unroll
                for (int mt = 0; mt < 4; mt++) {
                    acc2[mt][nt] = __builtin_amdgcn_mfma_f32_16x16x32_f16(Ah[mt], Bl[nt], acc2[mt][nt], 0, 0, 0);
                    acc2[mt][nt] = __builtin_amdgcn_mfma_f32_16x16x32_f16(Al[mt], Bh[nt], acc2[mt][nt], 0, 0, 0);
                    acc1[mt][nt] = __builtin_amdgcn_mfma_f32_16x16x32_f16(Ah[mt], Bh[nt], acc1[mt][nt], 0, 0, 0);
                }
        }
    }

    // epilogue: combine hi + lo/2048, NCHW float4 stores (D rows r are x-consecutive)
    float* h2 = ws + WS_B;
    const float ls = 1.f / 2048.f;
#pragma unroll
    for (int mt = 0; mt < 4; mt++) {
        int mloc = mt * 16 + quad * 4;
        int y = y0 + (mloc >> 5), x = mloc & 31;
#pragma unroll
        for (int nt = 0; nt < 4; nt++) {
            int co = co0 + nt * 16 + l15;
            *(float4*)&h2[(n * 256 + co) * 1024 + y * 32 + x] =
                make_float4(fmaf(acc2[mt][nt][0], ls, acc1[mt][nt][0]),
                            fmaf(acc2[mt][nt][1], ls, acc1[mt][nt][1]),
                            fmaf(acc2[mt][nt][2], ls, acc1[mt][nt][2]),
                            fmaf(acc2[mt][nt][3], ls, acc1[mt][nt][3]));
        }
    }
}

// ---------------- pre: 1x1, 256->64, out NHWC z_pix[p][c] ----------------
__global__ __launch_bounds__(256) void k_pre(const float* __restrict__ bias,
                                             float* __restrict__ ws) {
    __shared__ __align__(16) float a_s[8 * 128];
    __shared__ __align__(16) float b_s[8 * 64];
    int p0 = blockIdx.x * 128;
    int n = p0 >> 10, sp0 = p0 & 1023;
    int tid = threadIdx.x;
    int px4 = tid & 31, cg = tid >> 5;
    int co8 = cg * 8;
    const float* h2 = ws + WS_B;
    const float* wt3 = ws + WS_WT3;

    float acc[4][8];
#pragma unroll
    for (int r = 0; r < 4; r++)
#pragma unroll
        for (int j = 0; j < 8; j++) acc[r][j] = bias[co8 + j];

    for (int c0 = 0; c0 < 256; c0 += 8) {
        __syncthreads();
#pragma unroll
        for (int it = 0; it < 4; it++) {
            int t = tid + it * 256;
            a_s[t] = h2[n * 262144 + (c0 + (t >> 7)) * 1024 + sp0 + (t & 127)];
        }
#pragma unroll
        for (int it = 0; it < 2; it++) {
            int t = tid + it * 256;
            b_s[t] = wt3[(c0 + (t >> 6)) * 64 + (t & 63)];
        }
        __syncthreads();
#pragma unroll
        for (int ci = 0; ci < 8; ci++) {
            float4 av = *(const float4*)&a_s[ci * 128 + px4 * 4];
            float4 w0 = *(const float4*)&b_s[ci * 64 + co8];
            float4 w1 = *(const float4*)&b_s[ci * 64 + co8 + 4];
            float wv[8] = {w0.x, w0.y, w0.z, w0.w, w1.x, w1.y, w1.z, w1.w};
            float a[4] = {av.x, av.y, av.z, av.w};
#pragma unroll
            for (int j = 0; j < 8; j++)
#pragma unroll
                for (int r = 0; r < 4; r++) acc[r][j] = fmaf(a[r], wv[j], acc[r][j]);
        }
    }
    float* z = ws + WS_Z;
#pragma unroll
    for (int r = 0; r < 4; r++) {
        int p = p0 + px4 * 4 + r;
        *(float4*)&z[p * 64 + co8] = make_float4(acc[r][0], acc[r][1], acc[r][2], acc[r][3]);
        *(float4*)&z[p * 64 + co8 + 4] = make_float4(acc[r][4], acc[r][5], acc[r][6], acc[r][7]);
    }
}

// ---------------- VQ: argmin over 512 codes, idx out, loss partial ----------------
__global__ __launch_bounds__(256, 2) void k_vq(const float* __restrict__ codebook,
                                               float* __restrict__ out,
                                               float* __restrict__ ws) {
    __shared__ __align__(16) float cb_s[128 * 64];
    __shared__ __align__(16) float cc_s[128];
    int tid = threadIdx.x;
    int p = blockIdx.x * 256 + tid;
    const float* z = ws + WS_Z + p * 64;
    float4 z4[16];
#pragma unroll
    for (int i = 0; i < 16; i++) z4[i] = *(const float4*)&z[i * 4];
    float zz = 0.f;
#pragma unroll
    for (int i = 0; i < 16; i++)
        zz += z4[i].x * z4[i].x + z4[i].y * z4[i].y + z4[i].z * z4[i].z + z4[i].w * z4[i].w;

    float best = 3.4e38f;
    int bidx = 0;
    for (int k0 = 0; k0 < 512; k0 += 128) {
        __syncthreads();
#pragma unroll
        for (int it = 0; it < 32; it++) {
            int t = tid + it * 256;
            cb_s[t] = codebook[k0 * 64 + t];
        }
        if (tid < 128) cc_s[tid] = ws[WS_CC + k0 + tid];
        __syncthreads();
        for (int k = 0; k < 128; k++) {
            const float4* cp = (const float4*)&cb_s[k * 64];
            float d0 = 0.f, d1 = 0.f, d2 = 0.f, d3 = 0.f;
#pragma unroll
            for (int i = 0; i < 16; i += 4) {
                float4 c0v = cp[i], c1v = cp[i + 1], c2v = cp[i + 2], c3v = cp[i + 3];
                d0 += z4[i].x * c0v.x + z4[i].y * c0v.y + z4[i].z * c0v.z + z4[i].w * c0v.w;
                d1 += z4[i + 1].x * c1v.x + z4[i + 1].y * c1v.y + z4[i + 1].z * c1v.z + z4[i + 1].w * c1v.w;
                d2 += z4[i + 2].x * c2v.x + z4[i + 2].y * c2v.y + z4[i + 2].z * c2v.z + z4[i + 2].w * c2v.w;
                d3 += z4[i + 3].x * c3v.x + z4[i + 3].y * c3v.y + z4[i + 3].z * c3v.z + z4[i + 3].w * c3v.w;
            }
            float dot = (d0 + d1) + (d2 + d3);
            float d = fmaf(-2.f, dot, zz) + cc_s[k];
            if (d < best) { best = d; bidx = k0 + k; }
        }
    }
    out[OUT_IDX + p] = (float)bidx;
    ((int*)(ws + WS_IDX))[p] = bidx;

    float e = 0.f;
    const float4* q = (const float4*)&codebook[bidx * 64];
#pragma unroll
    for (int i = 0; i < 16; i++) {
        float4 qq = q[i];
        float d0 = z4[i].x - qq.x, d1 = z4[i].y - qq.y;
        float d2 = z4[i].z - qq.z, d3 = z4[i].w - qq.w;
        e += d0 * d0 + d1 * d1 + d2 * d2 + d3 * d3;
    }
#pragma unroll
    for (int off = 32; off; off >>= 1) e += __shfl_down(e, off);
    if ((tid & 63) == 0) atomicAdd(&ws[WS_LOSS], e);
}

__global__ void k_loss(float* __restrict__ out, const float* __restrict__ ws) {
    if (threadIdx.x == 0) {
        float v = ws[WS_LOSS] * (1.f / (65536.f * 64.f));
        out[OUT_LOSS_E] = v;
        out[OUT_LOSS_C] = v;
    }
}

// ---------------- gather fused-post rows: d_pix[p][:] = F[idx[p]][:] ----------------
__global__ __launch_bounds__(256) void k_gather(float* __restrict__ ws) {
    int tid = threadIdx.x;
    const int* idx = (const int*)(ws + WS_IDX);
    const float* F = ws + WS_F;
    float* dpx = ws + WS_B;
    int base = blockIdx.x * 64;
    for (int i = 0; i < 64; i++) {
        int row = idx[base + i];
        dpx[(base + i) * 256 + tid] = F[row * 256 + tid];
    }
}

// ---------------- dec1: conv_transpose 3x3 s2 p1 op1, 256->128 via split-bf16 MFMA ----------------
__global__ __launch_bounds__(256, 2) void k_dec1(const float* __restrict__ bias,
                                                 float* __restrict__ ws) {
    __shared__ __align__(16) short As_h[5280], As_l[5280];   // [5 row][33 col][32 ci]
    __shared__ __align__(16) short Bs_h[4096], Bs_l[4096];   // [128 co][32 ci]
    int bx = blockIdx.x;
    int tile = bx & 511, phase = bx >> 9;
    int py = phase >> 1, px = phase & 1;
    int n_img = tile >> 3, a0 = (tile & 7) * 4;
    int tid = threadIdx.x, lane = tid & 63, wid = tid >> 6;
    int wy = wid >> 1, wx = wid & 1;
    int l15 = lane & 15, quad = lane >> 4;

    int ntY = py + 1, ntX = px + 1, ntap = ntY * ntX;
    int tap_off[4], tap_w[4];
    {
        int ti = 0;
        for (int ty = 0; ty < ntY; ty++)
            for (int tx = 0; tx < ntX; tx++) {
                int dy = py ? 1 - ty : 0, ky = py ? 2 * ty : 1;
                int dx = px ? 1 - tx : 0, kx = px ? 2 * tx : 1;
                tap_off[ti] = (dy * 33 + dx) * 32;
                tap_w[ti] = ky * 3 + kx;
                ti++;
            }
    }

    int Aoff[4];
#pragma unroll
    for (int mt = 0; mt < 4; mt++) {
        int m_loc = wy * 64 + mt * 16 + l15;
        Aoff[mt] = ((m_loc >> 5) * 33 + (m_loc & 31)) * 32 + quad * 8;
    }
    int Boff[4];
#pragma unroll
    for (int nt = 0; nt < 4; nt++)
        Boff[nt] = (wx * 64 + nt * 16 + l15) * 32 + quad * 8;

    f32x4 acc[4][4];
#pragma unroll
    for (int nt = 0; nt < 4; nt++) {
        float bv = bias[wx * 64 + nt * 16 + l15];
#pragma unroll
        for (int mt = 0; mt < 4; mt++) acc[mt][nt] = (f32x4){bv, bv, bv, bv};
    }

    const float* dpx = ws + WS_B;
    const ushort* wbh = (const ushort*)(ws + WS_WT1);
    const ushort* wbl = wbh + 294912;

    for (int c0 = 0; c0 < 256; c0 += 32) {
        __syncthreads();
        for (int i = tid; i < 1320; i += 256) {
            int p5 = i >> 3, q = i & 7;
            int rr = p5 / 33, cc = p5 - rr * 33;
            int a_in = a0 + rr;
            float4 v = make_float4(0.f, 0.f, 0.f, 0.f);
            if (a_in < 32 && cc < 32)
                v = *(const float4*)&dpx[(n_img * 1024 + a_in * 32 + cc) * 256 + c0 + q * 4];
            ushort h0 = f2bf(v.x), h1 = f2bf(v.y), h2 = f2bf(v.z), h3v = f2bf(v.w);
            ushort l0 = f2bf(v.x - bf2f(h0)), l1 = f2bf(v.y - bf2f(h1));
            ushort l2 = f2bf(v.z - bf2f(h2)), l3 = f2bf(v.w - bf2f(h3v));
            int d = p5 * 32 + q * 4;
            *(uint*)&As_h[d]     = (uint)h0 | ((uint)h1 << 16);
            *(uint*)&As_h[d + 2] = (uint)h2 | ((uint)h3v << 16);
            *(uint*)&As_l[d]     = (uint)l0 | ((uint)l1 << 16);
            *(uint*)&As_l[d + 2] = (uint)l2 | ((uint)l3 << 16);
        }
        for (int t = 0; t < ntap; t++) {
            if (t) __syncthreads();
            int tw = tap_w[t];
            for (int i = tid; i < 512; i += 256) {
                int co = i >> 2, q = i & 3;
                int src = (tw * 128 + co) * 256 + c0 + q * 8;
                *(uint4*)&Bs_h[co * 32 + q * 8] = *(const uint4*)&wbh[src];
                *(uint4*)&Bs_l[co * 32 + q * 8] = *(const uint4*)&wbl[src];
            }
            __syncthreads();
            int ao = tap_off[t];
            short8 Ah[4], Al[4];
#pragma unroll
            for (int mt = 0; mt < 4; mt++) {
                Ah[mt] = *(const short8*)&As_h[Aoff[mt] + ao];
                Al[mt] = *(const short8*)&As_l[Aoff[mt] + ao];
            }
#pragma unroll
            for (int nt = 0; nt < 4; nt++) {
                short8 Bh = *(const short8*)&Bs_h[Boff[nt]];
                short8 Bl = *(const short8*)&Bs_l[Boff[nt]];
#pragma unroll
                for (int mt = 0; mt < 4; mt++) {
                    acc[mt][nt] = __builtin_amdgcn_mfma_f32_16x16x32_bf16(Ah[mt], Bh, acc[mt][nt], 0, 0, 0);
                    acc[mt][nt] = __builtin_amdgcn_mfma_f32_16x16x32_bf16(Ah[mt], Bl, acc[mt][nt], 0, 0, 0);
                    acc[mt][nt] = __builtin_amdgcn_mfma_f32_16x16x32_bf16(Al[mt], Bh, acc[mt][nt], 0, 0, 0);
                }
            }
        }
    }

    float* h3n = ws + WS_A;
#pragma unroll
    for (int mt = 0; mt < 4; mt++) {
#pragma unroll
        for (int r = 0; r < 4; r++) {
            int m_glob = tile * 128 + wy * 64 + mt * 16 + quad * 4 + r;
            int a = (m_glob >> 5) & 31, bb = m_glob & 31;
            int y = 2 * a + py, x = 2 * bb + px;
            float* rowp = &h3n[(((m_glob >> 10) * 64 + y) * 64 + x) * 128 + wx * 64];
#pragma unroll
            for (int nt = 0; nt < 4; nt++) rowp[nt * 16 + l15] = acc[mt][nt][r];
        }
    }
    int shadow = (bx & 7) * 256;
#pragma unroll
    for (int nt = 0; nt < 4; nt++) {
        float s1 = 0.f, s2 = 0.f;
#pragma unroll
        for (int mt = 0; mt < 4; mt++)
#pragma unroll
            for (int r = 0; r < 4; r++) {
                float v = acc[mt][nt][r];
                s1 += v; s2 += v * v;
            }
        s1 += __shfl_xor(s1, 16); s1 += __shfl_xor(s1, 32);
        s2 += __shfl_xor(s2, 16); s2 += __shfl_xor(s2, 32);
        if (quad == 0) {
            int co = wx * 64 + nt * 16 + l15;
            atomicAdd(&ws[WS_BN2S8 + shadow + co], s1);
            atomicAdd(&ws[WS_BN2S8 + shadow + 128 + co], s2);
        }
    }
}

// ---------------- dec2: conv_transpose 3x3 s2 p1 op1, 128->3, BN2+ReLU on load, tanh ----------------
// PADDING FIX (round-4 bug): BN+ReLU applied ONLY in-bounds; pad entries = 0.
__global__ __launch_bounds__(1024, 2) void k_dec2(const float* __restrict__ w,
                                                  const float* __restrict__ bias,
                                                  float* __restrict__ out,
                                                  float* __restrict__ ws) {
    __shared__ __align__(16) float in_s[8 * 5 * 66];
    __shared__ __align__(16) float w_s[8 * 9 * 3];
    __shared__ float scs[128], shs[128];
    int n = blockIdx.y;
    int atile = blockIdx.x;
    int a0 = atile * 4;
    int tid = threadIdx.x;
    int phase = tid >> 8;
    int py = phase >> 1, px = phase & 1;
    int tidl = tid & 255;
    int b = tidl & 63, r4 = tidl >> 6;
    int ntsh = py + px;
    int ntap = 1 << ntsh;
    const float* h3n = ws + WS_A;

    if (tid < 128) { scs[tid] = ws[WS_BN2SC + tid]; shs[tid] = ws[WS_BN2SH + tid]; }

    float acc[3] = {bias[0], bias[1], bias[2]};
    for (int c0 = 0; c0 < 128; c0 += 8) {
        __syncthreads();
        if (tid < 660) {
            int ciq = tid & 1, s = tid >> 1;
            int cL = s % 66, row = s / 66;
            int iy = a0 + row;
            float r0 = 0.f, r1 = 0.f, r2 = 0.f, r3 = 0.f;
            if (iy < 64 && cL < 64) {          // pad entries stay EXACTLY zero
                float4 v = *(const float4*)&h3n[((n * 64 + iy) * 64 + cL) * 128 + c0 + ciq * 4];
                int cb = c0 + ciq * 4;
                r0 = fmaxf(fmaf(v.x, scs[cb], shs[cb]), 0.f);
                r1 = fmaxf(fmaf(v.y, scs[cb + 1], shs[cb + 1]), 0.f);
                r2 = fmaxf(fmaf(v.z, scs[cb + 2], shs[cb + 2]), 0.f);
                r3 = fmaxf(fmaf(v.w, scs[cb + 3], shs[cb + 3]), 0.f);
            }
            int ci0 = ciq * 4;
            in_s[(ci0 + 0) * 330 + row * 66 + cL] = r0;
            in_s[(ci0 + 1) * 330 + row * 66 + cL] = r1;
            in_s[(ci0 + 2) * 330 + row * 66 + cL] = r2;
            in_s[(ci0 + 3) * 330 + row * 66 + cL] = r3;
        }
        if (tid < 8 * 9 * 3) {
            int co = tid % 3, q = tid / 3;   // q = ci*9 + tap
            int ci = q / 9, tap = q - ci * 9;
            w_s[q * 3 + co] = w[(c0 + ci) * 27 + co * 9 + tap];
        }
        __syncthreads();
#pragma unroll
        for (int ci = 0; ci < 8; ci++) {
#pragma unroll
            for (int tt = 0; tt < 4; tt++) {
                if (tt >= ntap) break;
                int ty = tt >> px, tx = tt & px;
                int ky = py ? 2 * ty : 1;
                int kx = px ? 2 * tx : 1;
                int dyv = py ? 1 - ty : 0;
                int dxv = px ? 1 - tx : 0;
                float v = in_s[ci * 330 + (r4 + dyv) * 66 + b + dxv];
                const float* wp = &w_s[(ci * 9 + ky * 3 + kx) * 3];
                acc[0] = fmaf(v, wp[0], acc[0]);
                acc[1] = fmaf(v, wp[1], acc[1]);
                acc[2] = fmaf(v, wp[2], acc[2]);
            }
        }
    }
    int y = 2 * (a0 + r4) + py, xcol = 2 * b + px;
#pragma unroll
    for (int co = 0; co < 3; co++)
        out[(n * 3 + co) * 16384 + y * 128 + xcol] = tanhf(acc[co]);
}

// ---------------- launch ----------------
extern "C" void kernel_launch(void* const* d_in, const int* in_sizes, int n_in,
                              void* d_out, int out_size, void* d_ws, size_t ws_size,
                              hipStream_t stream) {
    const float* x       = (const float*)d_in[0];
    const float* enc1_w  = (const float*)d_in[1];
    const float* enc1_b  = (const float*)d_in[2];
    const float* bn1_g   = (const float*)d_in[3];
    const float* bn1_b   = (const float*)d_in[4];
    const float* enc2_w  = (const float*)d_in[5];
    const float* enc2_b  = (const float*)d_in[6];
    const float* pre_w   = (const float*)d_in[7];
    const float* pre_b   = (const float*)d_in[8];
    const float* codebook= (const float*)d_in[9];
    const float* post_w  = (const float*)d_in[10];
    const float* post_b  = (const float*)d_in[11];
    const float* dec1_w  = (const float*)d_in[12];
    const float* dec1_b  = (const float*)d_in[13];
    const float* dbn1_g  = (const float*)d_in[14];
    const float* dbn1_b  = (const float*)d_in[15];
    const float* dec2_w  = (const float*)d_in[16];
    const float* dec2_b  = (const float*)d_in[17];
    float* out = (float*)d_out;
    float* ws  = (float*)d_ws;

    hipMemsetAsync(ws, 0, 4096, stream);                      // BN1 sums + loss
    hipMemsetAsync(ws + WS_BN2S8, 0, 8 * 256 * 4, stream);    // BN2 shadow sums

    k_wt<<<2368, 256, 0, stream>>>(dec1_w, enc2_w, pre_w, ws);
    k_F<<<512, 256, 0, stream>>>(codebook, post_w, post_b, ws);
    k_enc1<<<dim3(64, 64), 256, 0, stream>>>(x, enc1_w, enc1_b, ws);
    k_bnfin<<<1, 128, 0, stream>>>(ws + WS_BN1SUM, bn1_g, bn1_b,
                                   ws + WS_BN1SC, ws + WS_BN1SH, 1.f / 262144.f);
    k_enc2<<<1024, 256, 0, stream>>>(enc2_b, ws);
    k_pre<<<512, 256, 0, stream>>>(pre_b, ws);
    k_vq<<<256, 256, 0, stream>>>(codebook, out, ws);
    k_loss<<<1, 64, 0, stream>>>(out, ws);
    k_gather<<<1024, 256, 0, stream>>>(ws);
    k_dec1<<<2048, 256, 0, stream>>>(dec1_b, ws);
    k_bnfin2<<<1, 128, 0, stream>>>(dbn1_g, dbn1_b, ws);
    k_dec2<<<dim3(16, 64), 1024, 0, stream>>>(dec2_w, dec2_b, out, ws);
}

// Round 6
// 856.684 us; speedup vs baseline: 2.9559x; 1.4718x over previous
//
#include <hip/hip_runtime.h>

#define EPS 1e-5f

typedef __attribute__((ext_vector_type(8))) short short8;
typedef __attribute__((ext_vector_type(4))) float f32x4;
typedef _Float16 half8v __attribute__((ext_vector_type(8)));

__device__ inline ushort f2bf(float f) {
    uint u = __float_as_uint(f);
    u += 0x7FFFu + ((u >> 16) & 1u);
    return (ushort)(u >> 16);
}
__device__ inline float bf2f(ushort h) { return __uint_as_float(((uint)h) << 16); }
__device__ inline ushort hbits(_Float16 h) { return __builtin_bit_cast(ushort, h); }

// ---------------- ws layout (float offsets) ----------------
#define WS_BN1SUM   0         // (legacy, unused by new enc1)
#define WS_LOSS     512       // 1
#define WS_BN1SC    1024      // 128
#define WS_BN1SH    1152      // 128
#define WS_BN2SC    1280      // 128
#define WS_BN2SH    1408      // 128
#define WS_CC       1536      // 512 code norms
#define WS_IDX      2048      // 65536 ints
#define WS_WT3      67584     // 16384  pre_w^T  [ci][co]
#define WS_WT1      83968     // 294912 floats = 589824 ushorts: dec1_w split-bf16 [tap][co][ci] hi|lo
#define WS_WT2      378880    // 294912 floats = 589824 ushorts: enc2_w split-fp16 [(tap*256+co)*128+ci] hi|lo(x2048)
#define WS_F        673792    // 131072 fused post table [k][co]
#define WS_BN2S8    804864    // 8 shadow copies x 256 (s1[128], s2[128])
#define WS_BN1S8    806912    // 8 shadow copies x 256 (enc1 BN sums)
#define WS_WTE1     808960    // 1024 floats = 8192 ushorts: enc1_w split-fp16 [co][32] hi then lo(x2048)
#define WS_A        1048576   // 33554432: h1raw -> z_pix (aliased) -> h3 (NHWC)
#define WS_B        34603008  // 16777216: h2 -> d_pix [p][256] fp32
#define WS_Z        WS_A

#define OUT_LOSS_E  3145728
#define OUT_LOSS_C  3145729
#define OUT_IDX     3145730

// ---------------- weight pre-transpose / split ----------------
__global__ __launch_bounds__(256) void k_wt(const float* __restrict__ dec1_w,
                                            const float* __restrict__ enc2_w,
                                            const float* __restrict__ pre_w,
                                            const float* __restrict__ enc1_w,
                                            float* __restrict__ ws) {
    int g = blockIdx.x * 256 + threadIdx.x;
    if (g < 294912) {
        // dec1: wB[(tap*128+co)*256+ci] split hi/lo bf16 <- dec1_w[ci][co][tap]
        int ci = g & 255, co = (g >> 8) & 127, tap = g >> 15;
        float v = dec1_w[ci * 1152 + co * 9 + tap];
        ushort hi = f2bf(v);
        ushort lo = f2bf(v - bf2f(hi));
        ushort* u16 = (ushort*)(ws + WS_WT1);
        u16[g] = hi;
        u16[294912 + g] = lo;
    } else if (g < 2 * 294912) {
        // enc2: wt2s[(tap*256+co)*128+ci] split hi/lo fp16, lo scaled x2048
        int h = g - 294912;
        int ci = h & 127, rest = h >> 7;
        int co = rest & 255, tap = rest >> 8;
        float v = enc2_w[co * 1152 + ci * 9 + tap];
        _Float16 hi = (_Float16)v;
        _Float16 lo = (_Float16)((v - (float)hi) * 2048.0f);
        ushort* u16 = (ushort*)(ws + WS_WT2);
        u16[h] = hbits(hi);
        u16[294912 + h] = hbits(lo);
    } else if (g < 2 * 294912 + 16384) {    // wt3[ci*64+co] <- pre_w[co][ci]
        int h = g - 2 * 294912;
        int co = h & 63, ci = h >> 6;
        ws[WS_WT3 + h] = pre_w[co * 256 + ci];
    } else if (g < 2 * 294912 + 16384 + 4096) {
        // enc1: we1[co][k] split hi/lo fp16 (lo x2048); k = ci*9+ky*3+kx matches
        // enc1_w's natural [co][ci][ky][kx] order; k>=27 zero-padded.
        int h = g - (2 * 294912 + 16384);
        int k = h & 31, co = h >> 5;
        float v = (k < 27) ? enc1_w[co * 27 + k] : 0.f;
        _Float16 hi = (_Float16)v;
        _Float16 lo = (_Float16)((v - (float)hi) * 2048.0f);
        ushort* u16 = (ushort*)(ws + WS_WTE1);
        u16[h] = hbits(hi);
        u16[4096 + h] = hbits(lo);
    }
}

// ---------------- fused post table F = codebook @ post_w^T + post_b; code norms ----------------
__global__ __launch_bounds__(256) void k_F(const float* __restrict__ codebook,
                                           const float* __restrict__ post_w,
                                           const float* __restrict__ post_b,
                                           float* __restrict__ ws) {
    __shared__ __align__(16) float cbr[64];
    int k = blockIdx.x, co = threadIdx.x;
    if (co < 64) cbr[co] = codebook[k * 64 + co];
    __syncthreads();
    float acc = post_b[co];
#pragma unroll
    for (int i = 0; i < 64; i += 4) {
        float4 w4 = *(const float4*)&post_w[co * 64 + i];
        acc = fmaf(cbr[i], w4.x, acc);
        acc = fmaf(cbr[i + 1], w4.y, acc);
        acc = fmaf(cbr[i + 2], w4.z, acc);
        acc = fmaf(cbr[i + 3], w4.w, acc);
    }
    ws[WS_F + k * 256 + co] = acc;
    if (co == 0) {
        float s = 0.f;
        for (int i = 0; i < 64; i++) s += cbr[i] * cbr[i];
        ws[WS_CC + k] = s;
    }
}

// ---------------- enc1: 3x3 s2 p1, 3->128 via split-fp16 MFMA ----------------
// Implicit GEMM: M=128 px (2 out rows x 64 cols), N=128 co, K=27 (3ci x 9taps)
// padded to 32 -> a SINGLE 16x16x32 K-chunk (48 MFMAs/block, 2 barriers).
// Round-5 post-mortem: old fp32-VALU version ran 447us at 9% VALUBusy / 8%
// occupancy — latency-bound + 262K atomics on ONE BN accumulator copy.
// Fix: MFMA + register-direct B + 8-shadow BN atomics (dec1-style).
__global__ __launch_bounds__(256, 2) void k_enc1(const float* __restrict__ x,
                                                 const float* __restrict__ bias,
                                                 float* __restrict__ ws) {
    __shared__ __align__(16) float raw_s[1950];              // [3 ci][5 rr][130 c]
    __shared__ __align__(16) ushort As_h[5120], As_l[5120];  // [128 m][40] (k in 0..31)
    int b = blockIdx.x;
    int n = b >> 5, oy0 = (b & 31) * 2;
    int tid = threadIdx.x, lane = tid & 63, wid = tid >> 6;
    int wy = wid >> 1, wx = wid & 1;
    int l15 = lane & 15, quad = lane >> 4;
    int co0 = wx * 64;
    const ushort* we1h = (const ushort*)(ws + WS_WTE1);
    const ushort* we1l = we1h + 4096;

    // B frags register-direct from L2 (16 KB table)
    half8v Bh[4], Bl[4];
#pragma unroll
    for (int nt = 0; nt < 4; nt++) {
        int src = (co0 + nt * 16 + l15) * 32 + quad * 8;
        Bh[nt] = *(const half8v*)&we1h[src];
        Bl[nt] = *(const half8v*)&we1l[src];
    }

    // stage raw input rows: iy = 2*oy0-1+rr (rr 0..4), ix = c-1 (c 0..129)
    for (int i = tid; i < 1950; i += 256) {
        int c = i % 130, rest = i / 130;
        int rr = rest % 5, ci = rest / 5;
        int iy = 2 * oy0 - 1 + rr, ix = c - 1;
        float v = 0.f;
        if ((unsigned)iy < 128u && (unsigned)ix < 128u)
            v = x[(n * 3 + ci) * 16384 + iy * 128 + ix];
        raw_s[i] = v;
    }
    __syncthreads();

    // im2col + split: A[m][k], m = r*64+xx, k = ci*9+ky*3+kx (27..31 -> 0)
    for (int i = tid; i < 4096; i += 256) {
        int m = i >> 5, k = i & 31;
        float v = 0.f;
        if (k < 27) {
            int ci = k / 9, t9 = k - ci * 9;
            int ky = t9 / 3, kx = t9 - ky * 3;
            int r = m >> 6, xx = m & 63;
            v = raw_s[(ci * 5 + 2 * r + ky) * 130 + 2 * xx + kx];
        }
        _Float16 hi = (_Float16)v;
        _Float16 lo = (_Float16)((v - (float)hi) * 2048.f);
        As_h[m * 40 + k] = hbits(hi);
        As_l[m * 40 + k] = hbits(lo);
    }
    __syncthreads();

    f32x4 acc1[4][4], acc2[4][4];
#pragma unroll
    for (int nt = 0; nt < 4; nt++) {
        float bv = bias[co0 + nt * 16 + l15];
#pragma unroll
        for (int mt = 0; mt < 4; mt++) {
            acc1[mt][nt] = (f32x4){bv, bv, bv, bv};
            acc2[mt][nt] = (f32x4){0.f, 0.f, 0.f, 0.f};
        }
    }

    half8v Ah[4], Al[4];
#pragma unroll
    for (int mt = 0; mt < 4; mt++) {
        int aoff = (wy * 64 + mt * 16 + l15) * 40 + quad * 8;
        Ah[mt] = *(const half8v*)&As_h[aoff];
        Al[mt] = *(const half8v*)&As_l[aoff];
    }
#pragma unroll
    for (int nt = 0; nt < 4; nt++)
#pragma unroll
        for (int mt = 0; mt < 4; mt++) {
            acc2[mt][nt] = __builtin_amdgcn_mfma_f32_16x16x32_f16(Ah[mt], Bl[nt], acc2[mt][nt], 0, 0, 0);
            acc2[mt][nt] = __builtin_amdgcn_mfma_f32_16x16x32_f16(Al[mt], Bh[nt], acc2[mt][nt], 0, 0, 0);
            acc1[mt][nt] = __builtin_amdgcn_mfma_f32_16x16x32_f16(Ah[mt], Bh[nt], acc1[mt][nt], 0, 0, 0);
        }

    // epilogue: h1 NCHW float4 stores; oy = oy0 + wy, x0 = mt*16+quad*4
    float* h1 = ws + WS_A;
    const float ls = 1.f / 2048.f;
    int oy = oy0 + wy;
#pragma unroll
    for (int mt = 0; mt < 4; mt++) {
        int x0 = mt * 16 + quad * 4;
#pragma unroll
        for (int nt = 0; nt < 4; nt++) {
            int co = co0 + nt * 16 + l15;
            *(float4*)&h1[((n * 128 + co) * 64 + oy) * 64 + x0] =
                make_float4(fmaf(acc2[mt][nt][0], ls, acc1[mt][nt][0]),
                            fmaf(acc2[mt][nt][1], ls, acc1[mt][nt][1]),
                            fmaf(acc2[mt][nt][2], ls, acc1[mt][nt][2]),
                            fmaf(acc2[mt][nt][3], ls, acc1[mt][nt][3]));
        }
    }
    // BN1 partial sums -> 8 shadow copies
    int shadow = (b & 7) * 256;
#pragma unroll
    for (int nt = 0; nt < 4; nt++) {
        float s1 = 0.f, s2 = 0.f;
#pragma unroll
        for (int mt = 0; mt < 4; mt++)
#pragma unroll
            for (int r = 0; r < 4; r++) {
                float v = fmaf(acc2[mt][nt][r], ls, acc1[mt][nt][r]);
                s1 += v; s2 += v * v;
            }
        s1 += __shfl_xor(s1, 16); s1 += __shfl_xor(s1, 32);
        s2 += __shfl_xor(s2, 16); s2 += __shfl_xor(s2, 32);
        if (quad == 0) {
            int co = co0 + nt * 16 + l15;
            atomicAdd(&ws[WS_BN1S8 + shadow + co], s1);
            atomicAdd(&ws[WS_BN1S8 + shadow + 128 + co], s2);
        }
    }
}

// ---------------- BN finalize from 8 shadow copies ----------------
__global__ __launch_bounds__(128) void k_bnfin8(const float* __restrict__ sums8,
                                                const float* __restrict__ g,
                                                const float* __restrict__ b,
                                                float* __restrict__ scale,
                                                float* __restrict__ shift) {
    int c = threadIdx.x;
    float s1 = 0.f, s2 = 0.f;
    for (int k = 0; k < 8; k++) {
        s1 += sums8[k * 256 + c];
        s2 += sums8[k * 256 + 128 + c];
    }
    float mean = s1 * (1.f / 262144.f);
    float var = s2 * (1.f / 262144.f) - mean * mean;
    float sc = g[c] * rsqrtf(var + EPS);
    scale[c] = sc;
    shift[c] = b[c] - mean * sc;
}

// ---------------- enc2: 3x3 s2 p1, 128->256 via split-fp16 MFMA ----------------
__global__ __launch_bounds__(256, 2) void k_enc2(const float* __restrict__ bias,
                                                 float* __restrict__ ws) {
    __shared__ __align__(16) uint As_h[6500], As_l[6500];   // [5 row][65 col][32 ci], 52 KB
    __shared__ float scs[128], shs[128];
    int b = blockIdx.x;
    int n = b >> 4, y0 = (b & 15) * 2;
    int tid = threadIdx.x, lane = tid & 63, wid = tid >> 6;
    int l15 = lane & 15, quad = lane >> 4;
    int co0 = wid * 64;
    const float* h1 = ws + WS_A;
    const ushort* w2h = (const ushort*)(ws + WS_WT2);
    const ushort* w2l = w2h + 294912;

    if (tid < 128) { scs[tid] = ws[WS_BN1SC + tid]; shs[tid] = ws[WS_BN1SH + tid]; }

    int Abase[4];
#pragma unroll
    for (int mt = 0; mt < 4; mt++) {
        int m = mt * 16 + l15;
        Abase[mt] = (2 * (m >> 5)) * 2600 + (2 * (m & 31)) * 40 + quad * 8;  // ushort units
    }

    f32x4 acc1[4][4], acc2[4][4];
#pragma unroll
    for (int nt = 0; nt < 4; nt++) {
        float bv = bias[co0 + nt * 16 + l15];
#pragma unroll
        for (int mt = 0; mt < 4; mt++) {
            acc1[mt][nt] = (f32x4){bv, bv, bv, bv};
            acc2[mt][nt] = (f32x4){0.f, 0.f, 0.f, 0.f};
        }
    }

    for (int c0 = 0; c0 < 128; c0 += 32) {
        __syncthreads();
        if (tid < 80) {                       // zero col 0 (in_x = -1 pad)
            int p = tid & 15, row = tid >> 4;
            As_h[row * 1300 + p] = 0;
            As_l[row * 1300 + p] = 0;
        }
        for (int i = tid; i < 1280; i += 256) {
            int p = i & 15, g = i >> 4;       // p = ci-pair, g -> (row, colgroup)
            int row = g >> 4, colg = g & 15;
            int in_y = 2 * y0 - 1 + row;
            int ci0 = c0 + 2 * p;
            float av[4] = {0.f, 0.f, 0.f, 0.f}, bv[4] = {0.f, 0.f, 0.f, 0.f};
            if ((unsigned)in_y < 64u) {       // pad rows stay EXACTLY zero
                const float* bp = h1 + (n * 128 + ci0) * 4096 + in_y * 64 + colg * 4;
                float4 va = *(const float4*)bp;
                float4 vb = *(const float4*)(bp + 4096);
                float sa = scs[ci0], ta = shs[ci0];
                float sb = scs[ci0 + 1], tb = shs[ci0 + 1];
                av[0] = fmaxf(fmaf(va.x, sa, ta), 0.f); av[1] = fmaxf(fmaf(va.y, sa, ta), 0.f);
                av[2] = fmaxf(fmaf(va.z, sa, ta), 0.f); av[3] = fmaxf(fmaf(va.w, sa, ta), 0.f);
                bv[0] = fmaxf(fmaf(vb.x, sb, tb), 0.f); bv[1] = fmaxf(fmaf(vb.y, sb, tb), 0.f);
                bv[2] = fmaxf(fmaf(vb.z, sb, tb), 0.f); bv[3] = fmaxf(fmaf(vb.w, sb, tb), 0.f);
            }
            int wbase = row * 1300 + (colg * 4 + 1) * 20 + p;
#pragma unroll
            for (int j = 0; j < 4; j++) {
                _Float16 ah = (_Float16)av[j], bh = (_Float16)bv[j];
                _Float16 al = (_Float16)((av[j] - (float)ah) * 2048.f);
                _Float16 bl = (_Float16)((bv[j] - (float)bh) * 2048.f);
                As_h[wbase + j * 20] = (uint)hbits(ah) | ((uint)hbits(bh) << 16);
                As_l[wbase + j * 20] = (uint)hbits(al) | ((uint)hbits(bl) << 16);
            }
        }
        __syncthreads();
        const ushort* ah16 = (const ushort*)As_h;
        const ushort* al16 = (const ushort*)As_l;
#pragma unroll
        for (int tap = 0; tap < 9; tap++) {
            int ky = tap / 3, kx = tap - ky * 3;
            int toff = ky * 2600 + kx * 40;
            half8v Bh[4], Bl[4];
#pragma unroll
            for (int nt = 0; nt < 4; nt++) {
                int src = (tap * 256 + co0 + nt * 16 + l15) * 128 + c0 + quad * 8;
                Bh[nt] = *(const half8v*)&w2h[src];
                Bl[nt] = *(const half8v*)&w2l[src];
            }
            half8v Ah[4], Al[4];
#pragma unroll
            for (int mt = 0; mt < 4; mt++) {
                Ah[mt] = *(const half8v*)&ah16[Abase[mt] + toff];
                Al[mt] = *(const half8v*)&al16[Abase[mt] + toff];
            }
#pragma unroll
            for (int nt = 0; nt < 4; nt++)
#pragma unroll
                for (int mt = 0; mt < 4; mt++) {
                    acc2[mt][nt] = __builtin_amdgcn_mfma_f32_16x16x32_f16(Ah[mt], Bl[nt], acc2[mt][nt], 0, 0, 0);
                    acc2[mt][nt] = __builtin_amdgcn_mfma_f32_16x16x32_f16(Al[mt], Bh[nt], acc2[mt][nt], 0, 0, 0);
                    acc1[mt][nt] = __builtin_amdgcn_mfma_f32_16x16x32_f16(Ah[mt], Bh[nt], acc1[mt][nt], 0, 0, 0);
                }
        }
    }

    // epilogue: combine hi + lo/2048, NCHW float4 stores
    float* h2 = ws + WS_B;
    const float ls = 1.f / 2048.f;
#pragma unroll
    for (int mt = 0; mt < 4; mt++) {
        int mloc = mt * 16 + quad * 4;
        int y = y0 + (mloc >> 5), x = mloc & 31;
#pragma unroll
        for (int nt = 0; nt < 4; nt++) {
            int co = co0 + nt * 16 + l15;
            *(float4*)&h2[(n * 256 + co) * 1024 + y * 32 + x] =
                make_float4(fmaf(acc2[mt][nt][0], ls, acc1[mt][nt][0]),
                            fmaf(acc2[mt][nt][1], ls, acc1[mt][nt][1]),
                            fmaf(acc2[mt][nt][2], ls, acc1[mt][nt][2]),
                            fmaf(acc2[mt][nt][3], ls, acc1[mt][nt][3]));
        }
    }
}

// ---------------- pre: 1x1, 256->64, out NHWC z_pix[p][c] ----------------
__global__ __launch_bounds__(256) void k_pre(const float* __restrict__ bias,
                                             float* __restrict__ ws) {
    __shared__ __align__(16) float a_s[8 * 128];
    __shared__ __align__(16) float b_s[8 * 64];
    int p0 = blockIdx.x * 128;
    int n = p0 >> 10, sp0 = p0 & 1023;
    int tid = threadIdx.x;
    int px4 = tid & 31, cg = tid >> 5;
    int co8 = cg * 8;
    const float* h2 = ws + WS_B;
    const float* wt3 = ws + WS_WT3;

    float acc[4][8];
#pragma unroll
    for (int r = 0; r < 4; r++)
#pragma unroll
        for (int j = 0; j < 8; j++) acc[r][j] = bias[co8 + j];

    for (int c0 = 0; c0 < 256; c0 += 8) {
        __syncthreads();
#pragma unroll
        for (int it = 0; it < 4; it++) {
            int t = tid + it * 256;
            a_s[t] = h2[n * 262144 + (c0 + (t >> 7)) * 1024 + sp0 + (t & 127)];
        }
#pragma unroll
        for (int it = 0; it < 2; it++) {
            int t = tid + it * 256;
            b_s[t] = wt3[(c0 + (t >> 6)) * 64 + (t & 63)];
        }
        __syncthreads();
#pragma unroll
        for (int ci = 0; ci < 8; ci++) {
            float4 av = *(const float4*)&a_s[ci * 128 + px4 * 4];
            float4 w0 = *(const float4*)&b_s[ci * 64 + co8];
            float4 w1 = *(const float4*)&b_s[ci * 64 + co8 + 4];
            float wv[8] = {w0.x, w0.y, w0.z, w0.w, w1.x, w1.y, w1.z, w1.w};
            float a[4] = {av.x, av.y, av.z, av.w};
#pragma unroll
            for (int j = 0; j < 8; j++)
#pragma unroll
                for (int r = 0; r < 4; r++) acc[r][j] = fmaf(a[r], wv[j], acc[r][j]);
        }
    }
    float* z = ws + WS_Z;
#pragma unroll
    for (int r = 0; r < 4; r++) {
        int p = p0 + px4 * 4 + r;
        *(float4*)&z[p * 64 + co8] = make_float4(acc[r][0], acc[r][1], acc[r][2], acc[r][3]);
        *(float4*)&z[p * 64 + co8 + 4] = make_float4(acc[r][4], acc[r][5], acc[r][6], acc[r][7]);
    }
}

// ---------------- VQ: argmin over 512 codes, idx out, loss partial ----------------
__global__ __launch_bounds__(256, 2) void k_vq(const float* __restrict__ codebook,
                                               float* __restrict__ out,
                                               float* __restrict__ ws) {
    __shared__ __align__(16) float cb_s[128 * 64];
    __shared__ __align__(16) float cc_s[128];
    int tid = threadIdx.x;
    int p = blockIdx.x * 256 + tid;
    const float* z = ws + WS_Z + p * 64;
    float4 z4[16];
#pragma unroll
    for (int i = 0; i < 16; i++) z4[i] = *(const float4*)&z[i * 4];
    float zz = 0.f;
#pragma unroll
    for (int i = 0; i < 16; i++)
        zz += z4[i].x * z4[i].x + z4[i].y * z4[i].y + z4[i].z * z4[i].z + z4[i].w * z4[i].w;

    float best = 3.4e38f;
    int bidx = 0;
    for (int k0 = 0; k0 < 512; k0 += 128) {
        __syncthreads();
#pragma unroll
        for (int it = 0; it < 32; it++) {
            int t = tid + it * 256;
            cb_s[t] = codebook[k0 * 64 + t];
        }
        if (tid < 128) cc_s[tid] = ws[WS_CC + k0 + tid];
        __syncthreads();
        for (int k = 0; k < 128; k++) {
            const float4* cp = (const float4*)&cb_s[k * 64];
            float d0 = 0.f, d1 = 0.f, d2 = 0.f, d3 = 0.f;
#pragma unroll
            for (int i = 0; i < 16; i += 4) {
                float4 c0v = cp[i], c1v = cp[i + 1], c2v = cp[i + 2], c3v = cp[i + 3];
                d0 += z4[i].x * c0v.x + z4[i].y * c0v.y + z4[i].z * c0v.z + z4[i].w * c0v.w;
                d1 += z4[i + 1].x * c1v.x + z4[i + 1].y * c1v.y + z4[i + 1].z * c1v.z + z4[i + 1].w * c1v.w;
                d2 += z4[i + 2].x * c2v.x + z4[i + 2].y * c2v.y + z4[i + 2].z * c2v.z + z4[i + 2].w * c2v.w;
                d3 += z4[i + 3].x * c3v.x + z4[i + 3].y * c3v.y + z4[i + 3].z * c3v.z + z4[i + 3].w * c3v.w;
            }
            float dot = (d0 + d1) + (d2 + d3);
            float d = fmaf(-2.f, dot, zz) + cc_s[k];
            if (d < best) { best = d; bidx = k0 + k; }
        }
    }
    out[OUT_IDX + p] = (float)bidx;
    ((int*)(ws + WS_IDX))[p] = bidx;

    float e = 0.f;
    const float4* q = (const float4*)&codebook[bidx * 64];
#pragma unroll
    for (int i = 0; i < 16; i++) {
        float4 qq = q[i];
        float d0 = z4[i].x - qq.x, d1 = z4[i].y - qq.y;
        float d2 = z4[i].z - qq.z, d3 = z4[i].w - qq.w;
        e += d0 * d0 + d1 * d1 + d2 * d2 + d3 * d3;
    }
#pragma unroll
    for (int off = 32; off; off >>= 1) e += __shfl_down(e, off);
    if ((tid & 63) == 0) atomicAdd(&ws[WS_LOSS], e);
}

__global__ void k_loss(float* __restrict__ out, const float* __restrict__ ws) {
    if (threadIdx.x == 0) {
        float v = ws[WS_LOSS] * (1.f / (65536.f * 64.f));
        out[OUT_LOSS_E] = v;
        out[OUT_LOSS_C] = v;
    }
}

// ---------------- gather fused-post rows: d_pix[p][:] = F[idx[p]][:] ----------------
__global__ __launch_bounds__(256) void k_gather(float* __restrict__ ws) {
    int tid = threadIdx.x;
    const int* idx = (const int*)(ws + WS_IDX);
    const float* F = ws + WS_F;
    float* dpx = ws + WS_B;
    int base = blockIdx.x * 64;
    for (int i = 0; i < 64; i++) {
        int row = idx[base + i];
        dpx[(base + i) * 256 + tid] = F[row * 256 + tid];
    }
}

// ---------------- dec1: conv_transpose 3x3 s2 p1 op1, 256->128 via split-bf16 MFMA ----------------
__global__ __launch_bounds__(256, 2) void k_dec1(const float* __restrict__ bias,
                                                 float* __restrict__ ws) {
    __shared__ __align__(16) short As_h[5280], As_l[5280];   // [5 row][33 col][32 ci]
    __shared__ __align__(16) short Bs_h[4096], Bs_l[4096];   // [128 co][32 ci]
    int bx = blockIdx.x;
    int tile = bx & 511, phase = bx >> 9;
    int py = phase >> 1, px = phase & 1;
    int n_img = tile >> 3, a0 = (tile & 7) * 4;
    int tid = threadIdx.x, lane = tid & 63, wid = tid >> 6;
    int wy = wid >> 1, wx = wid & 1;
    int l15 = lane & 15, quad = lane >> 4;

    int ntY = py + 1, ntX = px + 1, ntap = ntY * ntX;
    int tap_off[4], tap_w[4];
    {
        int ti = 0;
        for (int ty = 0; ty < ntY; ty++)
            for (int tx = 0; tx < ntX; tx++) {
                int dy = py ? 1 - ty : 0, ky = py ? 2 * ty : 1;
                int dx = px ? 1 - tx : 0, kx = px ? 2 * tx : 1;
                tap_off[ti] = (dy * 33 + dx) * 32;
                tap_w[ti] = ky * 3 + kx;
                ti++;
            }
    }

    int Aoff[4];
#pragma unroll
    for (int mt = 0; mt < 4; mt++) {
        int m_loc = wy * 64 + mt * 16 + l15;
        Aoff[mt] = ((m_loc >> 5) * 33 + (m_loc & 31)) * 32 + quad * 8;
    }
    int Boff[4];
#pragma unroll
    for (int nt = 0; nt < 4; nt++)
        Boff[nt] = (wx * 64 + nt * 16 + l15) * 32 + quad * 8;

    f32x4 acc[4][4];
#pragma unroll
    for (int nt = 0; nt < 4; nt++) {
        float bv = bias[wx * 64 + nt * 16 + l15];
#pragma unroll
        for (int mt = 0; mt < 4; mt++) acc[mt][nt] = (f32x4){bv, bv, bv, bv};
    }

    const float* dpx = ws + WS_B;
    const ushort* wbh = (const ushort*)(ws + WS_WT1);
    const ushort* wbl = wbh + 294912;

    for (int c0 = 0; c0 < 256; c0 += 32) {
        __syncthreads();
        for (int i = tid; i < 1320; i += 256) {
            int p5 = i >> 3, q = i & 7;
            int rr = p5 / 33, cc = p5 - rr * 33;
            int a_in = a0 + rr;
            float4 v = make_float4(0.f, 0.f, 0.f, 0.f);
            if (a_in < 32 && cc < 32)
                v = *(const float4*)&dpx[(n_img * 1024 + a_in * 32 + cc) * 256 + c0 + q * 4];
            ushort h0 = f2bf(v.x), h1 = f2bf(v.y), h2 = f2bf(v.z), h3v = f2bf(v.w);
            ushort l0 = f2bf(v.x - bf2f(h0)), l1 = f2bf(v.y - bf2f(h1));
            ushort l2 = f2bf(v.z - bf2f(h2)), l3 = f2bf(v.w - bf2f(h3v));
            int d = p5 * 32 + q * 4;
            *(uint*)&As_h[d]     = (uint)h0 | ((uint)h1 << 16);
            *(uint*)&As_h[d + 2] = (uint)h2 | ((uint)h3v << 16);
            *(uint*)&As_l[d]     = (uint)l0 | ((uint)l1 << 16);
            *(uint*)&As_l[d + 2] = (uint)l2 | ((uint)l3 << 16);
        }
        for (int t = 0; t < ntap; t++) {
            if (t) __syncthreads();
            int tw = tap_w[t];
            for (int i = tid; i < 512; i += 256) {
                int co = i >> 2, q = i & 3;
                int src = (tw * 128 + co) * 256 + c0 + q * 8;
                *(uint4*)&Bs_h[co * 32 + q * 8] = *(const uint4*)&wbh[src];
                *(uint4*)&Bs_l[co * 32 + q * 8] = *(const uint4*)&wbl[src];
            }
            __syncthreads();
            int ao = tap_off[t];
            short8 Ah[4], Al[4];
#pragma unroll
            for (int mt = 0; mt < 4; mt++) {
                Ah[mt] = *(const short8*)&As_h[Aoff[mt] + ao];
                Al[mt] = *(const short8*)&As_l[Aoff[mt] + ao];
            }
#pragma unroll
            for (int nt = 0; nt < 4; nt++) {
                short8 Bh = *(const short8*)&Bs_h[Boff[nt]];
                short8 Bl = *(const short8*)&Bs_l[Boff[nt]];
#pragma unroll
                for (int mt = 0; mt < 4; mt++) {
                    acc[mt][nt] = __builtin_amdgcn_mfma_f32_16x16x32_bf16(Ah[mt], Bh, acc[mt][nt], 0, 0, 0);
                    acc[mt][nt] = __builtin_amdgcn_mfma_f32_16x16x32_bf16(Ah[mt], Bl, acc[mt][nt], 0, 0, 0);
                    acc[mt][nt] = __builtin_amdgcn_mfma_f32_16x16x32_bf16(Al[mt], Bh, acc[mt][nt], 0, 0, 0);
                }
            }
        }
    }

    float* h3n = ws + WS_A;
#pragma unroll
    for (int mt = 0; mt < 4; mt++) {
#pragma unroll
        for (int r = 0; r < 4; r++) {
            int m_glob = tile * 128 + wy * 64 + mt * 16 + quad * 4 + r;
            int a = (m_glob >> 5) & 31, bb = m_glob & 31;
            int y = 2 * a + py, x = 2 * bb + px;
            float* rowp = &h3n[(((m_glob >> 10) * 64 + y) * 64 + x) * 128 + wx * 64];
#pragma unroll
            for (int nt = 0; nt < 4; nt++) rowp[nt * 16 + l15] = acc[mt][nt][r];
        }
    }
    int shadow = (bx & 7) * 256;
#pragma unroll
    for (int nt = 0; nt < 4; nt++) {
        float s1 = 0.f, s2 = 0.f;
#pragma unroll
        for (int mt = 0; mt < 4; mt++)
#pragma unroll
            for (int r = 0; r < 4; r++) {
                float v = acc[mt][nt][r];
                s1 += v; s2 += v * v;
            }
        s1 += __shfl_xor(s1, 16); s1 += __shfl_xor(s1, 32);
        s2 += __shfl_xor(s2, 16); s2 += __shfl_xor(s2, 32);
        if (quad == 0) {
            int co = wx * 64 + nt * 16 + l15;
            atomicAdd(&ws[WS_BN2S8 + shadow + co], s1);
            atomicAdd(&ws[WS_BN2S8 + shadow + 128 + co], s2);
        }
    }
}

// ---------------- dec2: conv_transpose 3x3 s2 p1 op1, 128->3, BN2+ReLU on load, tanh ----------------
__global__ __launch_bounds__(1024, 2) void k_dec2(const float* __restrict__ w,
                                                  const float* __restrict__ bias,
                                                  float* __restrict__ out,
                                                  float* __restrict__ ws) {
    __shared__ __align__(16) float in_s[8 * 5 * 66];
    __shared__ __align__(16) float w_s[8 * 9 * 3];
    __shared__ float scs[128], shs[128];
    int n = blockIdx.y;
    int atile = blockIdx.x;
    int a0 = atile * 4;
    int tid = threadIdx.x;
    int phase = tid >> 8;
    int py = phase >> 1, px = phase & 1;
    int tidl = tid & 255;
    int b = tidl & 63, r4 = tidl >> 6;
    int ntsh = py + px;
    int ntap = 1 << ntsh;
    const float* h3n = ws + WS_A;

    if (tid < 128) { scs[tid] = ws[WS_BN2SC + tid]; shs[tid] = ws[WS_BN2SH + tid]; }

    float acc[3] = {bias[0], bias[1], bias[2]};
    for (int c0 = 0; c0 < 128; c0 += 8) {
        __syncthreads();
        if (tid < 660) {
            int ciq = tid & 1, s = tid >> 1;
            int cL = s % 66, row = s / 66;
            int iy = a0 + row;
            float r0 = 0.f, r1 = 0.f, r2 = 0.f, r3 = 0.f;
            if (iy < 64 && cL < 64) {          // pad entries stay EXACTLY zero
                float4 v = *(const float4*)&h3n[((n * 64 + iy) * 64 + cL) * 128 + c0 + ciq * 4];
                int cb = c0 + ciq * 4;
                r0 = fmaxf(fmaf(v.x, scs[cb], shs[cb]), 0.f);
                r1 = fmaxf(fmaf(v.y, scs[cb + 1], shs[cb + 1]), 0.f);
                r2 = fmaxf(fmaf(v.z, scs[cb + 2], shs[cb + 2]), 0.f);
                r3 = fmaxf(fmaf(v.w, scs[cb + 3], shs[cb + 3]), 0.f);
            }
            int ci0 = ciq * 4;
            in_s[(ci0 + 0) * 330 + row * 66 + cL] = r0;
            in_s[(ci0 + 1) * 330 + row * 66 + cL] = r1;
            in_s[(ci0 + 2) * 330 + row * 66 + cL] = r2;
            in_s[(ci0 + 3) * 330 + row * 66 + cL] = r3;
        }
        if (tid < 8 * 9 * 3) {
            int co = tid % 3, q = tid / 3;   // q = ci*9 + tap
            int ci = q / 9, tap = q - ci * 9;
            w_s[q * 3 + co] = w[(c0 + ci) * 27 + co * 9 + tap];
        }
        __syncthreads();
#pragma unroll
        for (int ci = 0; ci < 8; ci++) {
#pragma unroll
            for (int tt = 0; tt < 4; tt++) {
                if (tt >= ntap) break;
                int ty = tt >> px, tx = tt & px;
                int ky = py ? 2 * ty : 1;
                int kx = px ? 2 * tx : 1;
                int dyv = py ? 1 - ty : 0;
                int dxv = px ? 1 - tx : 0;
                float v = in_s[ci * 330 + (r4 + dyv) * 66 + b + dxv];
                const float* wp = &w_s[(ci * 9 + ky * 3 + kx) * 3];
                acc[0] = fmaf(v, wp[0], acc[0]);
                acc[1] = fmaf(v, wp[1], acc[1]);
                acc[2] = fmaf(v, wp[2], acc[2]);
            }
        }
    }
    int y = 2 * (a0 + r4) + py, xcol = 2 * b + px;
#pragma unroll
    for (int co = 0; co < 3; co++)
        out[(n * 3 + co) * 16384 + y * 128 + xcol] = tanhf(acc[co]);
}

// ---------------- launch ----------------
extern "C" void kernel_launch(void* const* d_in, const int* in_sizes, int n_in,
                              void* d_out, int out_size, void* d_ws, size_t ws_size,
                              hipStream_t stream) {
    const float* x       = (const float*)d_in[0];
    const float* enc1_w  = (const float*)d_in[1];
    const float* enc1_b  = (const float*)d_in[2];
    const float* bn1_g   = (const float*)d_in[3];
    const float* bn1_b   = (const float*)d_in[4];
    const float* enc2_w  = (const float*)d_in[5];
    const float* enc2_b  = (const float*)d_in[6];
    const float* pre_w   = (const float*)d_in[7];
    const float* pre_b   = (const float*)d_in[8];
    const float* codebook= (const float*)d_in[9];
    const float* post_w  = (const float*)d_in[10];
    const float* post_b  = (const float*)d_in[11];
    const float* dec1_w  = (const float*)d_in[12];
    const float* dec1_b  = (const float*)d_in[13];
    const float* dbn1_g  = (const float*)d_in[14];
    const float* dbn1_b  = (const float*)d_in[15];
    const float* dec2_w  = (const float*)d_in[16];
    const float* dec2_b  = (const float*)d_in[17];
    float* out = (float*)d_out;
    float* ws  = (float*)d_ws;

    hipMemsetAsync(ws, 0, 4096, stream);                      // loss accumulator etc.
    hipMemsetAsync(ws + WS_BN2S8, 0, 2 * 8 * 256 * 4, stream);// BN2 + BN1 shadow sums (contiguous)

    k_wt<<<2384, 256, 0, stream>>>(dec1_w, enc2_w, pre_w, enc1_w, ws);
    k_F<<<512, 256, 0, stream>>>(codebook, post_w, post_b, ws);
    k_enc1<<<2048, 256, 0, stream>>>(x, enc1_b, ws);
    k_bnfin8<<<1, 128, 0, stream>>>(ws + WS_BN1S8, bn1_g, bn1_b,
                                    ws + WS_BN1SC, ws + WS_BN1SH);
    k_enc2<<<1024, 256, 0, stream>>>(enc2_b, ws);
    k_pre<<<512, 256, 0, stream>>>(pre_b, ws);
    k_vq<<<256, 256, 0, stream>>>(codebook, out, ws);
    k_loss<<<1, 64, 0, stream>>>(out, ws);
    k_gather<<<1024, 256, 0, stream>>>(ws);
    k_dec1<<<2048, 256, 0, stream>>>(dec1_b, ws);
    k_bnfin8<<<1, 128, 0, stream>>>(ws + WS_BN2S8, dbn1_g, dbn1_b,
                                    ws + WS_BN2SC, ws + WS_BN2SH);
    k_dec2<<<dim3(16, 64), 1024, 0, stream>>>(dec2_w, dec2_b, out, ws);
}

// Round 8
// 695.889 us; speedup vs baseline: 3.6389x; 1.2311x over previous
//
#include <hip/hip_runtime.h>

#define EPS 1e-5f

typedef __attribute__((ext_vector_type(8))) short short8;
typedef __attribute__((ext_vector_type(4))) float f32x4;
typedef _Float16 half8v __attribute__((ext_vector_type(8)));

__device__ inline ushort f2bf(float f) {
    uint u = __float_as_uint(f);
    u += 0x7FFFu + ((u >> 16) & 1u);
    return (ushort)(u >> 16);
}
__device__ inline float bf2f(ushort h) { return __uint_as_float(((uint)h) << 16); }
__device__ inline ushort hbits(_Float16 h) { return __builtin_bit_cast(ushort, h); }

// ---------------- ws layout (float offsets) ----------------
#define WS_LOSS     512       // 1
#define WS_BN1SC    1024      // 128
#define WS_BN1SH    1152      // 128
#define WS_BN2SC    1280      // 128
#define WS_BN2SH    1408      // 128
#define WS_CC       1536      // 512 code norms
#define WS_IDX      2048      // 65536 ints
#define WS_WT3      67584     // 16384  pre_w^T  [ci][co]
#define WS_WT1      83968     // 294912 floats = 589824 ushorts: dec1_w split-bf16 [tap][co][ci] hi|lo
#define WS_WT2      378880    // 294912 floats = 589824 ushorts: enc2_w split-fp16 [(tap*256+co)*128+ci] hi|lo(x2048)
#define WS_F        673792    // 131072 fused post table [k][co]
#define WS_BN2S8    804864    // 8 shadow copies x 256
#define WS_BN1S8    806912    // 8 shadow copies x 256
#define WS_WTE1     808960    // 4096 FLOATS = 8192 ushorts: enc1_w split-fp16 [co][32] hi|lo(x2048)
                              // (round-7 bug: comment said 1024 floats -> CBS at 812032 OVERLAPPED [812032,813056))
#define WS_CBS      819200    // 32768 floats = 65536 ushorts: codebook split-fp16 [code][dim] hi then lo(x2048)
#define WS_A        1048576   // h1raw -> z_pix (aliased) -> h3 (NHWC)
#define WS_B        34603008  // h2 -> d_pix [p][256] fp32
#define WS_Z        WS_A

#define OUT_LOSS_E  3145728
#define OUT_LOSS_C  3145729
#define OUT_IDX     3145730

// ---------------- weight pre-transpose / split ----------------
__global__ __launch_bounds__(256) void k_wt(const float* __restrict__ dec1_w,
                                            const float* __restrict__ enc2_w,
                                            const float* __restrict__ pre_w,
                                            const float* __restrict__ enc1_w,
                                            const float* __restrict__ codebook,
                                            float* __restrict__ ws) {
    int g = blockIdx.x * 256 + threadIdx.x;
    if (g < 294912) {
        // dec1: wB[(tap*128+co)*256+ci] split hi/lo bf16 <- dec1_w[ci][co][tap]
        int ci = g & 255, co = (g >> 8) & 127, tap = g >> 15;
        float v = dec1_w[ci * 1152 + co * 9 + tap];
        ushort hi = f2bf(v);
        ushort lo = f2bf(v - bf2f(hi));
        ushort* u16 = (ushort*)(ws + WS_WT1);
        u16[g] = hi;
        u16[294912 + g] = lo;
    } else if (g < 2 * 294912) {
        // enc2: wt2s[(tap*256+co)*128+ci] split hi/lo fp16, lo scaled x2048
        int h = g - 294912;
        int ci = h & 127, rest = h >> 7;
        int co = rest & 255, tap = rest >> 8;
        float v = enc2_w[co * 1152 + ci * 9 + tap];
        _Float16 hi = (_Float16)v;
        _Float16 lo = (_Float16)((v - (float)hi) * 2048.0f);
        ushort* u16 = (ushort*)(ws + WS_WT2);
        u16[h] = hbits(hi);
        u16[294912 + h] = hbits(lo);
    } else if (g < 2 * 294912 + 16384) {    // wt3[ci*64+co] <- pre_w[co][ci]
        int h = g - 2 * 294912;
        int co = h & 63, ci = h >> 6;
        ws[WS_WT3 + h] = pre_w[co * 256 + ci];
    } else if (g < 2 * 294912 + 16384 + 4096) {
        // enc1: we1[co][k] split hi/lo fp16 (lo x2048); k>=27 zero-padded
        int h = g - (2 * 294912 + 16384);
        int k = h & 31, co = h >> 5;
        float v = (k < 27) ? enc1_w[co * 27 + k] : 0.f;
        _Float16 hi = (_Float16)v;
        _Float16 lo = (_Float16)((v - (float)hi) * 2048.0f);
        ushort* u16 = (ushort*)(ws + WS_WTE1);
        u16[h] = hbits(hi);
        u16[4096 + h] = hbits(lo);
    } else if (g < 2 * 294912 + 16384 + 4096 + 32768) {
        // VQ codebook: cbs[code*64+dim] split hi/lo fp16 (lo x2048), natural [n][k] layout
        int h = g - (2 * 294912 + 16384 + 4096);
        float v = codebook[h];
        _Float16 hi = (_Float16)v;
        _Float16 lo = (_Float16)((v - (float)hi) * 2048.0f);
        ushort* u16 = (ushort*)(ws + WS_CBS);
        u16[h] = hbits(hi);
        u16[32768 + h] = hbits(lo);
    }
}

// ---------------- fused post table F = codebook @ post_w^T + post_b; code norms ----------------
__global__ __launch_bounds__(256) void k_F(const float* __restrict__ codebook,
                                           const float* __restrict__ post_w,
                                           const float* __restrict__ post_b,
                                           float* __restrict__ ws) {
    __shared__ __align__(16) float cbr[64];
    int k = blockIdx.x, co = threadIdx.x;
    if (co < 64) cbr[co] = codebook[k * 64 + co];
    __syncthreads();
    float acc = post_b[co];
#pragma unroll
    for (int i = 0; i < 64; i += 4) {
        float4 w4 = *(const float4*)&post_w[co * 64 + i];
        acc = fmaf(cbr[i], w4.x, acc);
        acc = fmaf(cbr[i + 1], w4.y, acc);
        acc = fmaf(cbr[i + 2], w4.z, acc);
        acc = fmaf(cbr[i + 3], w4.w, acc);
    }
    ws[WS_F + k * 256 + co] = acc;
    if (co == 0) {
        float s = 0.f;
        for (int i = 0; i < 64; i++) s += cbr[i] * cbr[i];
        ws[WS_CC + k] = s;
    }
}

// ---------------- enc1: 3x3 s2 p1, 3->128 via split-fp16 MFMA ----------------
__global__ __launch_bounds__(256, 2) void k_enc1(const float* __restrict__ x,
                                                 const float* __restrict__ bias,
                                                 float* __restrict__ ws) {
    __shared__ __align__(16) float raw_s[1950];              // [3 ci][5 rr][130 c]
    __shared__ __align__(16) ushort As_h[5120], As_l[5120];  // [128 m][40]
    int b = blockIdx.x;
    int n = b >> 5, oy0 = (b & 31) * 2;
    int tid = threadIdx.x, lane = tid & 63, wid = tid >> 6;
    int wy = wid >> 1, wx = wid & 1;
    int l15 = lane & 15, quad = lane >> 4;
    int co0 = wx * 64;
    const ushort* we1h = (const ushort*)(ws + WS_WTE1);
    const ushort* we1l = we1h + 4096;

    half8v Bh[4], Bl[4];
#pragma unroll
    for (int nt = 0; nt < 4; nt++) {
        int src = (co0 + nt * 16 + l15) * 32 + quad * 8;
        Bh[nt] = *(const half8v*)&we1h[src];
        Bl[nt] = *(const half8v*)&we1l[src];
    }

    for (int i = tid; i < 1950; i += 256) {
        int c = i % 130, rest = i / 130;
        int rr = rest % 5, ci = rest / 5;
        int iy = 2 * oy0 - 1 + rr, ix = c - 1;
        float v = 0.f;
        if ((unsigned)iy < 128u && (unsigned)ix < 128u)
            v = x[(n * 3 + ci) * 16384 + iy * 128 + ix];
        raw_s[i] = v;
    }
    __syncthreads();

    for (int i = tid; i < 4096; i += 256) {
        int m = i >> 5, k = i & 31;
        float v = 0.f;
        if (k < 27) {
            int ci = k / 9, t9 = k - ci * 9;
            int ky = t9 / 3, kx = t9 - ky * 3;
            int r = m >> 6, xx = m & 63;
            v = raw_s[(ci * 5 + 2 * r + ky) * 130 + 2 * xx + kx];
        }
        _Float16 hi = (_Float16)v;
        _Float16 lo = (_Float16)((v - (float)hi) * 2048.f);
        As_h[m * 40 + k] = hbits(hi);
        As_l[m * 40 + k] = hbits(lo);
    }
    __syncthreads();

    f32x4 acc1[4][4], acc2[4][4];
#pragma unroll
    for (int nt = 0; nt < 4; nt++) {
        float bv = bias[co0 + nt * 16 + l15];
#pragma unroll
        for (int mt = 0; mt < 4; mt++) {
            acc1[mt][nt] = (f32x4){bv, bv, bv, bv};
            acc2[mt][nt] = (f32x4){0.f, 0.f, 0.f, 0.f};
        }
    }

    half8v Ah[4], Al[4];
#pragma unroll
    for (int mt = 0; mt < 4; mt++) {
        int aoff = (wy * 64 + mt * 16 + l15) * 40 + quad * 8;
        Ah[mt] = *(const half8v*)&As_h[aoff];
        Al[mt] = *(const half8v*)&As_l[aoff];
    }
#pragma unroll
    for (int nt = 0; nt < 4; nt++)
#pragma unroll
        for (int mt = 0; mt < 4; mt++) {
            acc2[mt][nt] = __builtin_amdgcn_mfma_f32_16x16x32_f16(Ah[mt], Bl[nt], acc2[mt][nt], 0, 0, 0);
            acc2[mt][nt] = __builtin_amdgcn_mfma_f32_16x16x32_f16(Al[mt], Bh[nt], acc2[mt][nt], 0, 0, 0);
            acc1[mt][nt] = __builtin_amdgcn_mfma_f32_16x16x32_f16(Ah[mt], Bh[nt], acc1[mt][nt], 0, 0, 0);
        }

    float* h1 = ws + WS_A;
    const float ls = 1.f / 2048.f;
    int oy = oy0 + wy;
#pragma unroll
    for (int mt = 0; mt < 4; mt++) {
        int x0 = mt * 16 + quad * 4;
#pragma unroll
        for (int nt = 0; nt < 4; nt++) {
            int co = co0 + nt * 16 + l15;
            *(float4*)&h1[((n * 128 + co) * 64 + oy) * 64 + x0] =
                make_float4(fmaf(acc2[mt][nt][0], ls, acc1[mt][nt][0]),
                            fmaf(acc2[mt][nt][1], ls, acc1[mt][nt][1]),
                            fmaf(acc2[mt][nt][2], ls, acc1[mt][nt][2]),
                            fmaf(acc2[mt][nt][3], ls, acc1[mt][nt][3]));
        }
    }
    int shadow = (b & 7) * 256;
#pragma unroll
    for (int nt = 0; nt < 4; nt++) {
        float s1 = 0.f, s2 = 0.f;
#pragma unroll
        for (int mt = 0; mt < 4; mt++)
#pragma unroll
            for (int r = 0; r < 4; r++) {
                float v = fmaf(acc2[mt][nt][r], ls, acc1[mt][nt][r]);
                s1 += v; s2 += v * v;
            }
        s1 += __shfl_xor(s1, 16); s1 += __shfl_xor(s1, 32);
        s2 += __shfl_xor(s2, 16); s2 += __shfl_xor(s2, 32);
        if (quad == 0) {
            int co = co0 + nt * 16 + l15;
            atomicAdd(&ws[WS_BN1S8 + shadow + co], s1);
            atomicAdd(&ws[WS_BN1S8 + shadow + 128 + co], s2);
        }
    }
}

// ---------------- BN finalize from 8 shadow copies ----------------
__global__ __launch_bounds__(128) void k_bnfin8(const float* __restrict__ sums8,
                                                const float* __restrict__ g,
                                                const float* __restrict__ b,
                                                float* __restrict__ scale,
                                                float* __restrict__ shift) {
    int c = threadIdx.x;
    float s1 = 0.f, s2 = 0.f;
    for (int k = 0; k < 8; k++) {
        s1 += sums8[k * 256 + c];
        s2 += sums8[k * 256 + 128 + c];
    }
    float mean = s1 * (1.f / 262144.f);
    float var = s2 * (1.f / 262144.f) - mean * mean;
    float sc = g[c] * rsqrtf(var + EPS);
    scale[c] = sc;
    shift[c] = b[c] - mean * sc;
}

// ---------------- enc2: 3x3 s2 p1, 128->256 via split-fp16 MFMA ----------------
__global__ __launch_bounds__(256, 2) void k_enc2(const float* __restrict__ bias,
                                                 float* __restrict__ ws) {
    __shared__ __align__(16) uint As_h[6500], As_l[6500];   // [5 row][65 col][32 ci], 52 KB
    __shared__ float scs[128], shs[128];
    int b = blockIdx.x;
    int n = b >> 4, y0 = (b & 15) * 2;
    int tid = threadIdx.x, lane = tid & 63, wid = tid >> 6;
    int l15 = lane & 15, quad = lane >> 4;
    int co0 = wid * 64;
    const float* h1 = ws + WS_A;
    const ushort* w2h = (const ushort*)(ws + WS_WT2);
    const ushort* w2l = w2h + 294912;

    if (tid < 128) { scs[tid] = ws[WS_BN1SC + tid]; shs[tid] = ws[WS_BN1SH + tid]; }

    int Abase[4];
#pragma unroll
    for (int mt = 0; mt < 4; mt++) {
        int m = mt * 16 + l15;
        Abase[mt] = (2 * (m >> 5)) * 2600 + (2 * (m & 31)) * 40 + quad * 8;
    }

    f32x4 acc1[4][4], acc2[4][4];
#pragma unroll
    for (int nt = 0; nt < 4; nt++) {
        float bv = bias[co0 + nt * 16 + l15];
#pragma unroll
        for (int mt = 0; mt < 4; mt++) {
            acc1[mt][nt] = (f32x4){bv, bv, bv, bv};
            acc2[mt][nt] = (f32x4){0.f, 0.f, 0.f, 0.f};
        }
    }

    for (int c0 = 0; c0 < 128; c0 += 32) {
        __syncthreads();
        if (tid < 80) {
            int p = tid & 15, row = tid >> 4;
            As_h[row * 1300 + p] = 0;
            As_l[row * 1300 + p] = 0;
        }
        for (int i = tid; i < 1280; i += 256) {
            int p = i & 15, g = i >> 4;
            int row = g >> 4, colg = g & 15;
            int in_y = 2 * y0 - 1 + row;
            int ci0 = c0 + 2 * p;
            float av[4] = {0.f, 0.f, 0.f, 0.f}, bv[4] = {0.f, 0.f, 0.f, 0.f};
            if ((unsigned)in_y < 64u) {
                const float* bp = h1 + (n * 128 + ci0) * 4096 + in_y * 64 + colg * 4;
                float4 va = *(const float4*)bp;
                float4 vb = *(const float4*)(bp + 4096);
                float sa = scs[ci0], ta = shs[ci0];
                float sb = scs[ci0 + 1], tb = shs[ci0 + 1];
                av[0] = fmaxf(fmaf(va.x, sa, ta), 0.f); av[1] = fmaxf(fmaf(va.y, sa, ta), 0.f);
                av[2] = fmaxf(fmaf(va.z, sa, ta), 0.f); av[3] = fmaxf(fmaf(va.w, sa, ta), 0.f);
                bv[0] = fmaxf(fmaf(vb.x, sb, tb), 0.f); bv[1] = fmaxf(fmaf(vb.y, sb, tb), 0.f);
                bv[2] = fmaxf(fmaf(vb.z, sb, tb), 0.f); bv[3] = fmaxf(fmaf(vb.w, sb, tb), 0.f);
            }
            int wbase = row * 1300 + (colg * 4 + 1) * 20 + p;
#pragma unroll
            for (int j = 0; j < 4; j++) {
                _Float16 ah = (_Float16)av[j], bh = (_Float16)bv[j];
                _Float16 al = (_Float16)((av[j] - (float)ah) * 2048.f);
                _Float16 bl = (_Float16)((bv[j] - (float)bh) * 2048.f);
                As_h[wbase + j * 20] = (uint)hbits(ah) | ((uint)hbits(bh) << 16);
                As_l[wbase + j * 20] = (uint)hbits(al) | ((uint)hbits(bl) << 16);
            }
        }
        __syncthreads();
        const ushort* ah16 = (const ushort*)As_h;
        const ushort* al16 = (const ushort*)As_l;
#pragma unroll
        for (int tap = 0; tap < 9; tap++) {
            int ky = tap / 3, kx = tap - ky * 3;
            int toff = ky * 2600 + kx * 40;
            half8v Bh[4], Bl[4];
#pragma unroll
            for (int nt = 0; nt < 4; nt++) {
                int src = (tap * 256 + co0 + nt * 16 + l15) * 128 + c0 + quad * 8;
                Bh[nt] = *(const half8v*)&w2h[src];
                Bl[nt] = *(const half8v*)&w2l[src];
            }
            half8v Ah[4], Al[4];
#pragma unroll
            for (int mt = 0; mt < 4; mt++) {
                Ah[mt] = *(const half8v*)&ah16[Abase[mt] + toff];
                Al[mt] = *(const half8v*)&al16[Abase[mt] + toff];
            }
#pragma unroll
            for (int nt = 0; nt < 4; nt++)
#pragma unroll
                for (int mt = 0; mt < 4; mt++) {
                    acc2[mt][nt] = __builtin_amdgcn_mfma_f32_16x16x32_f16(Ah[mt], Bl[nt], acc2[mt][nt], 0, 0, 0);
                    acc2[mt][nt] = __builtin_amdgcn_mfma_f32_16x16x32_f16(Al[mt], Bh[nt], acc2[mt][nt], 0, 0, 0);
                    acc1[mt][nt] = __builtin_amdgcn_mfma_f32_16x16x32_f16(Ah[mt], Bh[nt], acc1[mt][nt], 0, 0, 0);
                }
        }
    }

    float* h2 = ws + WS_B;
    const float ls = 1.f / 2048.f;
#pragma unroll
    for (int mt = 0; mt < 4; mt++) {
        int mloc = mt * 16 + quad * 4;
        int y = y0 + (mloc >> 5), x = mloc & 31;
#pragma unroll
        for (int nt = 0; nt < 4; nt++) {
            int co = co0 + nt * 16 + l15;
            *(float4*)&h2[(n * 256 + co) * 1024 + y * 32 + x] =
                make_float4(fmaf(acc2[mt][nt][0], ls, acc1[mt][nt][0]),
                            fmaf(acc2[mt][nt][1], ls, acc1[mt][nt][1]),
                            fmaf(acc2[mt][nt][2], ls, acc1[mt][nt][2]),
                            fmaf(acc2[mt][nt][3], ls, acc1[mt][nt][3]));
        }
    }
}

// ---------------- pre: 1x1, 256->64, out NHWC z_pix[p][c] ----------------
__global__ __launch_bounds__(256) void k_pre(const float* __restrict__ bias,
                                             float* __restrict__ ws) {
    __shared__ __align__(16) float a_s[8 * 128];
    __shared__ __align__(16) float b_s[8 * 64];
    int p0 = blockIdx.x * 128;
    int n = p0 >> 10, sp0 = p0 & 1023;
    int tid = threadIdx.x;
    int px4 = tid & 31, cg = tid >> 5;
    int co8 = cg * 8;
    const float* h2 = ws + WS_B;
    const float* wt3 = ws + WS_WT3;

    float acc[4][8];
#pragma unroll
    for (int r = 0; r < 4; r++)
#pragma unroll
        for (int j = 0; j < 8; j++) acc[r][j] = bias[co8 + j];

    for (int c0 = 0; c0 < 256; c0 += 8) {
        __syncthreads();
#pragma unroll
        for (int it = 0; it < 4; it++) {
            int t = tid + it * 256;
            a_s[t] = h2[n * 262144 + (c0 + (t >> 7)) * 1024 + sp0 + (t & 127)];
        }
#pragma unroll
        for (int it = 0; it < 2; it++) {
            int t = tid + it * 256;
            b_s[t] = wt3[(c0 + (t >> 6)) * 64 + (t & 63)];
        }
        __syncthreads();
#pragma unroll
        for (int ci = 0; ci < 8; ci++) {
            float4 av = *(const float4*)&a_s[ci * 128 + px4 * 4];
            float4 w0 = *(const float4*)&b_s[ci * 64 + co8];
            float4 w1 = *(const float4*)&b_s[ci * 64 + co8 + 4];
            float wv[8] = {w0.x, w0.y, w0.z, w0.w, w1.x, w1.y, w1.z, w1.w};
            float a[4] = {av.x, av.y, av.z, av.w};
#pragma unroll
            for (int j = 0; j < 8; j++)
#pragma unroll
                for (int r = 0; r < 4; r++) acc[r][j] = fmaf(a[r], wv[j], acc[r][j]);
        }
    }
    float* z = ws + WS_Z;
#pragma unroll
    for (int r = 0; r < 4; r++) {
        int p = p0 + px4 * 4 + r;
        *(float4*)&z[p * 64 + co8] = make_float4(acc[r][0], acc[r][1], acc[r][2], acc[r][3]);
        *(float4*)&z[p * 64 + co8 + 4] = make_float4(acc[r][4], acc[r][5], acc[r][6], acc[r][7]);
    }
}

// ---------------- VQ via split-fp16 MFMA ----------------
// Distance GEMM: M=65536 px, N=512 codes, K=64. argmin over s = cc - 2*dot
// (zz is per-pixel constant -> drops out of ordering); loss e = zz + s_best.
// Block = 64 px x all 512 codes; 4 waves x 128 codes; 2 passes of 4 n-tiles.
// B register-direct from 128 KB L2-resident split table.
__global__ __launch_bounds__(256, 2) void k_vq(float* __restrict__ out,
                                               float* __restrict__ ws) {
    __shared__ __align__(16) ushort Ash[64 * 72], Asl[64 * 72];
    __shared__ float zz_s[64];
    __shared__ float red_s[256];
    __shared__ int red_i[256];
    int p0 = blockIdx.x * 64;
    int tid = threadIdx.x, lane = tid & 63, wid = tid >> 6;
    int l15 = lane & 15, quad = lane >> 4;
    const float* z = ws + WS_Z;
    const ushort* cbh = (const ushort*)(ws + WS_CBS);
    const ushort* cbl = cbh + 32768;

    // stage + split z (64 px x 64 dims)
    for (int i = tid; i < 1024; i += 256) {
        int m = i >> 4, k4 = (i & 15) * 4;
        float4 v = *(const float4*)&z[(p0 + m) * 64 + k4];
        _Float16 h0 = (_Float16)v.x, h1 = (_Float16)v.y, h2 = (_Float16)v.z, h3 = (_Float16)v.w;
        _Float16 l0 = (_Float16)((v.x - (float)h0) * 2048.f);
        _Float16 l1 = (_Float16)((v.y - (float)h1) * 2048.f);
        _Float16 l2 = (_Float16)((v.z - (float)h2) * 2048.f);
        _Float16 l3 = (_Float16)((v.w - (float)h3) * 2048.f);
        int d = m * 72 + k4;
        *(uint*)&Ash[d]     = (uint)hbits(h0) | ((uint)hbits(h1) << 16);
        *(uint*)&Ash[d + 2] = (uint)hbits(h2) | ((uint)hbits(h3) << 16);
        *(uint*)&Asl[d]     = (uint)hbits(l0) | ((uint)hbits(l1) << 16);
        *(uint*)&Asl[d + 2] = (uint)hbits(l2) | ((uint)hbits(l3) << 16);
    }
    if (tid < 64) {
        const float* zp = &z[(p0 + tid) * 64];
        float s = 0.f;
#pragma unroll
        for (int k = 0; k < 64; k += 4) {
            float4 v = *(const float4*)&zp[k];
            s += v.x * v.x + v.y * v.y + v.z * v.z + v.w * v.w;
        }
        zz_s[tid] = s;
    }
    __syncthreads();

    float best_s[4][4];
    int best_i[4][4];
#pragma unroll
    for (int mt = 0; mt < 4; mt++)
#pragma unroll
        for (int r = 0; r < 4; r++) { best_s[mt][r] = 3.4e38f; best_i[mt][r] = 0; }

    const float ls = 1.f / 2048.f;
    for (int pass = 0; pass < 2; pass++) {
        f32x4 acc1[4][4], acc2[4][4];
#pragma unroll
        for (int mt = 0; mt < 4; mt++)
#pragma unroll
            for (int nt = 0; nt < 4; nt++) {
                acc1[mt][nt] = (f32x4){0.f, 0.f, 0.f, 0.f};
                acc2[mt][nt] = (f32x4){0.f, 0.f, 0.f, 0.f};
            }
#pragma unroll
        for (int kc = 0; kc < 2; kc++) {
            half8v Ah[4], Al[4];
#pragma unroll
            for (int mt = 0; mt < 4; mt++) {
                int aoff = (mt * 16 + l15) * 72 + kc * 32 + quad * 8;
                Ah[mt] = *(const half8v*)&Ash[aoff];
                Al[mt] = *(const half8v*)&Asl[aoff];
            }
#pragma unroll
            for (int nt = 0; nt < 4; nt++) {
                int code = wid * 128 + pass * 64 + nt * 16 + l15;
                int src = code * 64 + kc * 32 + quad * 8;
                half8v Bh = *(const half8v*)&cbh[src];
                half8v Bl = *(const half8v*)&cbl[src];
#pragma unroll
                for (int mt = 0; mt < 4; mt++) {
                    acc2[mt][nt] = __builtin_amdgcn_mfma_f32_16x16x32_f16(Ah[mt], Bl, acc2[mt][nt], 0, 0, 0);
                    acc2[mt][nt] = __builtin_amdgcn_mfma_f32_16x16x32_f16(Al[mt], Bh, acc2[mt][nt], 0, 0, 0);
                    acc1[mt][nt] = __builtin_amdgcn_mfma_f32_16x16x32_f16(Ah[mt], Bh, acc1[mt][nt], 0, 0, 0);
                }
            }
        }
        // fold distances into running argmin (s = cc - 2*dot)
#pragma unroll
        for (int nt = 0; nt < 4; nt++) {
            int code = wid * 128 + pass * 64 + nt * 16 + l15;
            float cc = ws[WS_CC + code];
#pragma unroll
            for (int mt = 0; mt < 4; mt++)
#pragma unroll
                for (int r = 0; r < 4; r++) {
                    float dot = fmaf(acc2[mt][nt][r], ls, acc1[mt][nt][r]);
                    float s = fmaf(-2.f, dot, cc);
                    if (s < best_s[mt][r] || (s == best_s[mt][r] && code < best_i[mt][r])) {
                        best_s[mt][r] = s; best_i[mt][r] = code;
                    }
                }
        }
    }

    // reduce across l15 lanes (same pixel rows, different codes)
#pragma unroll
    for (int mt = 0; mt < 4; mt++)
#pragma unroll
        for (int r = 0; r < 4; r++) {
            float s = best_s[mt][r];
            int ix = best_i[mt][r];
#pragma unroll
            for (int off = 1; off < 16; off <<= 1) {
                float so = __shfl_xor(s, off);
                int io = __shfl_xor(ix, off);
                if (so < s || (so == s && io < ix)) { s = so; ix = io; }
            }
            if (l15 == 0) {
                int px = mt * 16 + quad * 4 + r;
                red_s[wid * 64 + px] = s;
                red_i[wid * 64 + px] = ix;
            }
        }
    __syncthreads();
    if (tid < 64) {
        float s = red_s[tid];
        int ix = red_i[tid];
#pragma unroll
        for (int w = 1; w < 4; w++) {
            float so = red_s[w * 64 + tid];
            int io = red_i[w * 64 + tid];
            if (so < s || (so == s && io < ix)) { s = so; ix = io; }
        }
        out[OUT_IDX + p0 + tid] = (float)ix;
        ((int*)(ws + WS_IDX))[p0 + tid] = ix;
        float e = fmaxf(zz_s[tid] + s, 0.f);   // ||z - c_best||^2
#pragma unroll
        for (int off = 32; off; off >>= 1) e += __shfl_down(e, off);
        if (tid == 0) atomicAdd(&ws[WS_LOSS], e);
    }
}

__global__ void k_loss(float* __restrict__ out, const float* __restrict__ ws) {
    if (threadIdx.x == 0) {
        float v = ws[WS_LOSS] * (1.f / (65536.f * 64.f));
        out[OUT_LOSS_E] = v;
        out[OUT_LOSS_C] = v;
    }
}

// ---------------- gather fused-post rows: d_pix[p][:] = F[idx[p]][:] ----------------
__global__ __launch_bounds__(256) void k_gather(float* __restrict__ ws) {
    int tid = threadIdx.x;
    const int* idx = (const int*)(ws + WS_IDX);
    const float* F = ws + WS_F;
    float* dpx = ws + WS_B;
    int base = blockIdx.x * 64;
    for (int i = 0; i < 64; i++) {
        int row = idx[base + i];
        dpx[(base + i) * 256 + tid] = F[row * 256 + tid];
    }
}

// ---------------- dec1: conv_transpose 3x3 s2 p1 op1, 256->128 via split-bf16 MFMA ----------------
__global__ __launch_bounds__(256, 2) void k_dec1(const float* __restrict__ bias,
                                                 float* __restrict__ ws) {
    __shared__ __align__(16) short As_h[5280], As_l[5280];   // [5 row][33 col][32 ci]
    __shared__ __align__(16) short Bs_h[4096], Bs_l[4096];   // [128 co][32 ci]
    int bx = blockIdx.x;
    int tile = bx & 511, phase = bx >> 9;
    int py = phase >> 1, px = phase & 1;
    int n_img = tile >> 3, a0 = (tile & 7) * 4;
    int tid = threadIdx.x, lane = tid & 63, wid = tid >> 6;
    int wy = wid >> 1, wx = wid & 1;
    int l15 = lane & 15, quad = lane >> 4;

    int ntY = py + 1, ntX = px + 1, ntap = ntY * ntX;
    int tap_off[4], tap_w[4];
    {
        int ti = 0;
        for (int ty = 0; ty < ntY; ty++)
            for (int tx = 0; tx < ntX; tx++) {
                int dy = py ? 1 - ty : 0, ky = py ? 2 * ty : 1;
                int dx = px ? 1 - tx : 0, kx = px ? 2 * tx : 1;
                tap_off[ti] = (dy * 33 + dx) * 32;
                tap_w[ti] = ky * 3 + kx;
                ti++;
            }
    }

    int Aoff[4];
#pragma unroll
    for (int mt = 0; mt < 4; mt++) {
        int m_loc = wy * 64 + mt * 16 + l15;
        Aoff[mt] = ((m_loc >> 5) * 33 + (m_loc & 31)) * 32 + quad * 8;
    }
    int Boff[4];
#pragma unroll
    for (int nt = 0; nt < 4; nt++)
        Boff[nt] = (wx * 64 + nt * 16 + l15) * 32 + quad * 8;

    f32x4 acc[4][4];
#pragma unroll
    for (int nt = 0; nt < 4; nt++) {
        float bv = bias[wx * 64 + nt * 16 + l15];
#pragma unroll
        for (int mt = 0; mt < 4; mt++) acc[mt][nt] = (f32x4){bv, bv, bv, bv};
    }

    const float* dpx = ws + WS_B;
    const ushort* wbh = (const ushort*)(ws + WS_WT1);
    const ushort* wbl = wbh + 294912;

    for (int c0 = 0; c0 < 256; c0 += 32) {
        __syncthreads();
        for (int i = tid; i < 1320; i += 256) {
            int p5 = i >> 3, q = i & 7;
            int rr = p5 / 33, cc = p5 - rr * 33;
            int a_in = a0 + rr;
            float4 v = make_float4(0.f, 0.f, 0.f, 0.f);
            if (a_in < 32 && cc < 32)
                v = *(const float4*)&dpx[(n_img * 1024 + a_in * 32 + cc) * 256 + c0 + q * 4];
            ushort h0 = f2bf(v.x), h1 = f2bf(v.y), h2 = f2bf(v.z), h3v = f2bf(v.w);
            ushort l0 = f2bf(v.x - bf2f(h0)), l1 = f2bf(v.y - bf2f(h1));
            ushort l2 = f2bf(v.z - bf2f(h2)), l3 = f2bf(v.w - bf2f(h3v));
            int d = p5 * 32 + q * 4;
            *(uint*)&As_h[d]     = (uint)h0 | ((uint)h1 << 16);
            *(uint*)&As_h[d + 2] = (uint)h2 | ((uint)h3v << 16);
            *(uint*)&As_l[d]     = (uint)l0 | ((uint)l1 << 16);
            *(uint*)&As_l[d + 2] = (uint)l2 | ((uint)l3 << 16);
        }
        for (int t = 0; t < ntap; t++) {
            if (t) __syncthreads();
            int tw = tap_w[t];
            for (int i = tid; i < 512; i += 256) {
                int co = i >> 2, q = i & 3;
                int src = (tw * 128 + co) * 256 + c0 + q * 8;
                *(uint4*)&Bs_h[co * 32 + q * 8] = *(const uint4*)&wbh[src];
                *(uint4*)&Bs_l[co * 32 + q * 8] = *(const uint4*)&wbl[src];
            }
            __syncthreads();
            int ao = tap_off[t];
            short8 Ah[4], Al[4];
#pragma unroll
            for (int mt = 0; mt < 4; mt++) {
                Ah[mt] = *(const short8*)&As_h[Aoff[mt] + ao];
                Al[mt] = *(const short8*)&As_l[Aoff[mt] + ao];
            }
#pragma unroll
            for (int nt = 0; nt < 4; nt++) {
                short8 Bh = *(const short8*)&Bs_h[Boff[nt]];
                short8 Bl = *(const short8*)&Bs_l[Boff[nt]];
#pragma unroll
                for (int mt = 0; mt < 4; mt++) {
                    acc[mt][nt] = __builtin_amdgcn_mfma_f32_16x16x32_bf16(Ah[mt], Bh, acc[mt][nt], 0, 0, 0);
                    acc[mt][nt] = __builtin_amdgcn_mfma_f32_16x16x32_bf16(Ah[mt], Bl, acc[mt][nt], 0, 0, 0);
                    acc[mt][nt] = __builtin_amdgcn_mfma_f32_16x16x32_bf16(Al[mt], Bh, acc[mt][nt], 0, 0, 0);
                }
            }
        }
    }

    float* h3n = ws + WS_A;
#pragma unroll
    for (int mt = 0; mt < 4; mt++) {
#pragma unroll
        for (int r = 0; r < 4; r++) {
            int m_glob = tile * 128 + wy * 64 + mt * 16 + quad * 4 + r;
            int a = (m_glob >> 5) & 31, bb = m_glob & 31;
            int y = 2 * a + py, x = 2 * bb + px;
            float* rowp = &h3n[(((m_glob >> 10) * 64 + y) * 64 + x) * 128 + wx * 64];
#pragma unroll
            for (int nt = 0; nt < 4; nt++) rowp[nt * 16 + l15] = acc[mt][nt][r];
        }
    }
    int shadow = (bx & 7) * 256;
#pragma unroll
    for (int nt = 0; nt < 4; nt++) {
        float s1 = 0.f, s2 = 0.f;
#pragma unroll
        for (int mt = 0; mt < 4; mt++)
#pragma unroll
            for (int r = 0; r < 4; r++) {
                float v = acc[mt][nt][r];
                s1 += v; s2 += v * v;
            }
        s1 += __shfl_xor(s1, 16); s1 += __shfl_xor(s1, 32);
        s2 += __shfl_xor(s2, 16); s2 += __shfl_xor(s2, 32);
        if (quad == 0) {
            int co = wx * 64 + nt * 16 + l15;
            atomicAdd(&ws[WS_BN2S8 + shadow + co], s1);
            atomicAdd(&ws[WS_BN2S8 + shadow + 128 + co], s2);
        }
    }
}

// ---------------- dec2: conv_transpose 3x3 s2 p1 op1, 128->3, BN2+ReLU on load, tanh ----------------
__global__ __launch_bounds__(1024, 2) void k_dec2(const float* __restrict__ w,
                                                  const float* __restrict__ bias,
                                                  float* __restrict__ out,
                                                  float* __restrict__ ws) {
    __shared__ __align__(16) float in_s[8 * 5 * 66];
    __shared__ __align__(16) float w_s[8 * 9 * 3];
    __shared__ float scs[128], shs[128];
    int n = blockIdx.y;
    int atile = blockIdx.x;
    int a0 = atile * 4;
    int tid = threadIdx.x;
    int phase = tid >> 8;
    int py = phase >> 1, px = phase & 1;
    int tidl = tid & 255;
    int b = tidl & 63, r4 = tidl >> 6;
    int ntsh = py + px;
    int ntap = 1 << ntsh;
    const float* h3n = ws + WS_A;

    if (tid < 128) { scs[tid] = ws[WS_BN2SC + tid]; shs[tid] = ws[WS_BN2SH + tid]; }

    float acc[3] = {bias[0], bias[1], bias[2]};
    for (int c0 = 0; c0 < 128; c0 += 8) {
        __syncthreads();
        if (tid < 660) {
            int ciq = tid & 1, s = tid >> 1;
            int cL = s % 66, row = s / 66;
            int iy = a0 + row;
            float r0 = 0.f, r1 = 0.f, r2 = 0.f, r3 = 0.f;
            if (iy < 64 && cL < 64) {
                float4 v = *(const float4*)&h3n[((n * 64 + iy) * 64 + cL) * 128 + c0 + ciq * 4];
                int cb = c0 + ciq * 4;
                r0 = fmaxf(fmaf(v.x, scs[cb], shs[cb]), 0.f);
                r1 = fmaxf(fmaf(v.y, scs[cb + 1], shs[cb + 1]), 0.f);
                r2 = fmaxf(fmaf(v.z, scs[cb + 2], shs[cb + 2]), 0.f);
                r3 = fmaxf(fmaf(v.w, scs[cb + 3], shs[cb + 3]), 0.f);
            }
            int ci0 = ciq * 4;
            in_s[(ci0 + 0) * 330 + row * 66 + cL] = r0;
            in_s[(ci0 + 1) * 330 + row * 66 + cL] = r1;
            in_s[(ci0 + 2) * 330 + row * 66 + cL] = r2;
            in_s[(ci0 + 3) * 330 + row * 66 + cL] = r3;
        }
        if (tid < 8 * 9 * 3) {
            int co = tid % 3, q = tid / 3;
            int ci = q / 9, tap = q - ci * 9;
            w_s[q * 3 + co] = w[(c0 + ci) * 27 + co * 9 + tap];
        }
        __syncthreads();
#pragma unroll
        for (int ci = 0; ci < 8; ci++) {
#pragma unroll
            for (int tt = 0; tt < 4; tt++) {
                if (tt >= ntap) break;
                int ty = tt >> px, tx = tt & px;
                int ky = py ? 2 * ty : 1;
                int kx = px ? 2 * tx : 1;
                int dyv = py ? 1 - ty : 0;
                int dxv = px ? 1 - tx : 0;
                float v = in_s[ci * 330 + (r4 + dyv) * 66 + b + dxv];
                const float* wp = &w_s[(ci * 9 + ky * 3 + kx) * 3];
                acc[0] = fmaf(v, wp[0], acc[0]);
                acc[1] = fmaf(v, wp[1], acc[1]);
                acc[2] = fmaf(v, wp[2], acc[2]);
            }
        }
    }
    int y = 2 * (a0 + r4) + py, xcol = 2 * b + px;
#pragma unroll
    for (int co = 0; co < 3; co++)
        out[(n * 3 + co) * 16384 + y * 128 + xcol] = tanhf(acc[co]);
}

// ---------------- launch ----------------
extern "C" void kernel_launch(void* const* d_in, const int* in_sizes, int n_in,
                              void* d_out, int out_size, void* d_ws, size_t ws_size,
                              hipStream_t stream) {
    const float* x       = (const float*)d_in[0];
    const float* enc1_w  = (const float*)d_in[1];
    const float* enc1_b  = (const float*)d_in[2];
    const float* bn1_g   = (const float*)d_in[3];
    const float* bn1_b   = (const float*)d_in[4];
    const float* enc2_w  = (const float*)d_in[5];
    const float* enc2_b  = (const float*)d_in[6];
    const float* pre_w   = (const float*)d_in[7];
    const float* pre_b   = (const float*)d_in[8];
    const float* codebook= (const float*)d_in[9];
    const float* post_w  = (const float*)d_in[10];
    const float* post_b  = (const float*)d_in[11];
    const float* dec1_w  = (const float*)d_in[12];
    const float* dec1_b  = (const float*)d_in[13];
    const float* dbn1_g  = (const float*)d_in[14];
    const float* dbn1_b  = (const float*)d_in[15];
    const float* dec2_w  = (const float*)d_in[16];
    const float* dec2_b  = (const float*)d_in[17];
    float* out = (float*)d_out;
    float* ws  = (float*)d_ws;

    hipMemsetAsync(ws, 0, 4096, stream);                      // loss accumulator etc.
    hipMemsetAsync(ws + WS_BN2S8, 0, 2 * 8 * 256 * 4, stream);// BN2 + BN1 shadow sums

    k_wt<<<2512, 256, 0, stream>>>(dec1_w, enc2_w, pre_w, enc1_w, codebook, ws);
    k_F<<<512, 256, 0, stream>>>(codebook, post_w, post_b, ws);
    k_enc1<<<2048, 256, 0, stream>>>(x, enc1_b, ws);
    k_bnfin8<<<1, 128, 0, stream>>>(ws + WS_BN1S8, bn1_g, bn1_b,
                                    ws + WS_BN1SC, ws + WS_BN1SH);
    k_enc2<<<1024, 256, 0, stream>>>(enc2_b, ws);
    k_pre<<<512, 256, 0, stream>>>(pre_b, ws);
    k_vq<<<1024, 256, 0, stream>>>(out, ws);
    k_loss<<<1, 64, 0, stream>>>(out, ws);
    k_gather<<<1024, 256, 0, stream>>>(ws);
    k_dec1<<<2048, 256, 0, stream>>>(dec1_b, ws);
    k_bnfin8<<<1, 128, 0, stream>>>(ws + WS_BN2S8, dbn1_g, dbn1_b,
                                    ws + WS_BN2SC, ws + WS_BN2SH);
    k_dec2<<<dim3(16, 64), 1024, 0, stream>>>(dec2_w, dec2_b, out, ws);
}